// Round 5
// baseline (408.282 us; speedup 1.0000x reference)
//
#include <hip/hip_runtime.h>

#define B_   8
#define N_   1024
#define F0_  56
#define D_   70
#define DK_  96      // bf16 K-padded row stride (3 x 32)
#define DFC_ 128
#define LST  76      // LDS row stride (words): %8==4 -> conflict-light b128

typedef __attribute__((ext_vector_type(8))) short bf16x8;
typedef __attribute__((ext_vector_type(4))) float f32x4;
typedef unsigned short ushortT;

__device__ __forceinline__ short f2bf(float x) {
  unsigned u = __builtin_bit_cast(unsigned, x);
  u += 0x7FFF + ((u >> 16) & 1);
  return (short)(u >> 16);
}
__device__ __forceinline__ float bfdec(unsigned u16bits) {
  unsigned v = u16bits << 16;
  return __builtin_bit_cast(float, v);
}
__device__ __forceinline__ float dot4(float4 a, float4 b) {
  return a.x * b.x + a.y * b.y + a.z * b.z + a.w * b.w;
}

// ---------------------------------------------- A^T precompute (tiny, once)
__global__ __launch_bounds__(256) void prep_w(const float* __restrict__ gA,
                                              float* __restrict__ At)
{
  const int k = blockIdx.x;
  for (int idx = threadIdx.x; idx < D_ * D_; idx += 256) {
    const int d = idx / D_, m = idx - d * D_;
    At[(size_t)k * D_ * D_ + idx] = gA[(size_t)k * D_ * D_ + m * D_ + d];
  }
}

// ------------------------------------- adjacency pack + bitmasks (fused)
// u16: bits[15:1] = bf16(rbf+A1) mantissa-LSB-dropped, bit0 = (A1>0)
__global__ __launch_bounds__(256) void prep_adj_mask(
    const float* __restrict__ A1, const float* __restrict__ A2,
    const float* __restrict__ mup, const float* __restrict__ devp,
    ushortT* __restrict__ adjp, unsigned* __restrict__ m1b, unsigned* __restrict__ m2b)
{
  const int row = blockIdx.x;             // b*N + i
  const int t = threadIdx.x;
  __shared__ unsigned w1s[32], w2s[32];
  if (t < 32) { w1s[t] = 0; w2s[t] = 0; }
  __syncthreads();
  const size_t base = (size_t)row * N_ + t * 4;
  const float4 a1 = *(const float4*)(A1 + base);
  const float4 a2 = *(const float4*)(A2 + base);
  const float mu = mup[0], idev = 1.0f / devp[0];
  const float a1v[4] = {a1.x, a1.y, a1.z, a1.w};
  const float a2v[4] = {a2.x, a2.y, a2.z, a2.w};
  ushortT out[4];
  unsigned b1 = 0, b2 = 0;
#pragma unroll
  for (int k = 0; k < 4; k++) {
    const float rbf = (a2v[k] <= 10.f) ? __expf(-(a2v[k] - mu) * (a2v[k] - mu) * idev) : 0.f;
    const float adj1 = rbf + a1v[k];
    ushortT u = ((ushortT)f2bf(adj1)) & 0xFFFE;
    if (a1v[k] > 0.f) u |= 1;
    out[k] = u;
    b1 |= ((u & 0xFFFEu) ? 1u : 0u) << k;
    b2 |= (u & 1u) << k;
  }
  *(uint2*)(adjp + base) = *(uint2*)out;
  atomicOr(&w1s[t >> 3], b1 << ((t & 7) * 4));
  atomicOr(&w2s[t >> 3], b2 << ((t & 7) * 4));
  __syncthreads();
  if (t < 32) {
    m1b[(size_t)row * 32 + t] = w1s[t];
    m2b[(size_t)row * 32 + t] = w2s[t];
  }
}

// ---------------- fused [combine|featem] + h + hA + hT  (16 rows/block)
// MODE 0: x = H @ few^T (layer 0).  MODE 1: combine prev layer -> x.
#define GROWS 16
template<int MODE>
__global__ __launch_bounds__(256) void gatmm_fused(
    float* __restrict__ x, const float* __restrict__ H, const float* __restrict__ few,
    const ushortT* __restrict__ hp1p, const ushortT* __restrict__ hp2p, int JC,
    const float* __restrict__ g1, const float* __restrict__ g2w, const float* __restrict__ g2b,
    const float* __restrict__ W, const float* __restrict__ At,
    short* __restrict__ hb16, short* __restrict__ hAb16, short* __restrict__ hT)
{
  __shared__ float sW[D_][LST];
  __shared__ float sAt[D_][LST];
  __shared__ float sx[GROWS][LST];
  __shared__ float sh[GROWS][LST];
  const int tid = threadIdx.x;
  const int r0 = blockIdx.x * GROWS;
  const int b = r0 >> 10, n0 = r0 & (N_ - 1);

  // stage W
  for (int idx = tid; idx < D_ * LST; idx += 256) {
    const int d = idx / LST, m = idx - d * LST;
    sW[d][m] = (m < D_) ? W[d * D_ + m] : 0.f;
  }
  if (MODE == 0) {
    // featem: sAt <- few, sh <- H rows
    for (int idx = tid; idx < D_ * LST; idx += 256) {
      const int d = idx / LST, m = idx - d * LST;
      sAt[d][m] = (m < F0_) ? few[d * F0_ + m] : 0.f;
    }
    for (int idx = tid; idx < GROWS * LST; idx += 256) {
      const int rr = idx / LST, m = idx - rr * LST;
      sh[rr][m] = (m < F0_) ? H[(size_t)(r0 + rr) * F0_ + m] : 0.f;
    }
    __syncthreads();
    for (int idx = tid; idx < GROWS * LST; idx += 256) {
      const int rr = idx / LST, d = idx - rr * LST;
      float a = 0.f;
      if (d < D_) {
        const float4* hr = (const float4*)&sh[rr][0];
        const float4* wr = (const float4*)&sAt[d][0];
#pragma unroll
        for (int m4 = 0; m4 < F0_ / 4; m4++) a += dot4(hr[m4], wr[m4]);
        x[(size_t)(r0 + rr) * D_ + d] = a;
      }
      sx[rr][d] = a;
    }
    __syncthreads();
    // reload sAt with A^T for gemm2
    for (int idx = tid; idx < D_ * LST; idx += 256) {
      const int d = idx / LST, m = idx - d * LST;
      sAt[d][m] = (m < D_) ? At[d * D_ + m] : 0.f;
    }
  } else {
    for (int idx = tid; idx < D_ * LST; idx += 256) {
      const int d = idx / LST, m = idx - d * LST;
      sAt[d][m] = (m < D_) ? At[d * D_ + m] : 0.f;
    }
    // ---- combine (gating) for this block's 16 rows
    const int rr = tid >> 4, lt = tid & 15;
    const int grow = r0 + rr;
    float s1[5], s2[5], xv[5];
#pragma unroll
    for (int q = 0; q < 5; q++) { s1[q] = 0.f; s2[q] = 0.f; xv[q] = 0.f; }
    for (int jc = 0; jc < JC; jc++) {
      const size_t basep = ((size_t)jc * (B_ * N_) + grow) * 80 + lt;
#pragma unroll
      for (int q = 0; q < 5; q++) {
        const int d = lt + 16 * q;
        if (d < D_) {
          s1[q] += bfdec(hp1p[basep + 16 * q]);
          s2[q] += bfdec(hp2p[basep + 16 * q]);
        }
      }
    }
    float d1 = 0.f, d2 = 0.f, d3 = 0.f;
#pragma unroll
    for (int q = 0; q < 5; q++) {
      const int d = lt + 16 * q;
      if (d < D_) {
        s1[q] = fmaxf(s1[q], 0.f);
        s2[q] = fmaxf(s2[q], 0.f);
        xv[q] = x[(size_t)grow * D_ + d];
        d1 += xv[q] * g1[d];
        d2 += s1[q] * g2w[d];
        d3 += s2[q] * g2w[d];
      }
    }
#pragma unroll
    for (int off = 1; off < 16; off <<= 1) {
      d1 += __shfl_xor(d1, off);
      d2 += __shfl_xor(d2, off);
      d3 += __shfl_xor(d3, off);
    }
    const float bb = g2b[0];
    const float c1 = 1.f / (1.f + __expf(-(d1 + d2 + bb)));
    const float c2 = 1.f / (1.f + __expf(-(d1 + d3 + bb)));
#pragma unroll
    for (int q = 0; q < 5; q++) {
      const int d = lt + 16 * q;
      if (d < D_) {
        const float xn = (c1 * xv[q] + (1.f - c1) * s1[q]) - (c2 * xv[q] + (1.f - c2) * s2[q]);
        sx[rr][d] = xn;
        x[(size_t)grow * D_ + d] = xn;
      } else if (d < LST) {
        sx[rr][d] = 0.f;
      }
    }
  }
  __syncthreads();
  // gemm1: sh = sx @ W^T
  for (int idx = tid; idx < GROWS * LST; idx += 256) {
    const int rr = idx / LST, d = idx - rr * LST;
    float a = 0.f;
    if (d < D_) {
      const float4* xr = (const float4*)&sx[rr][0];
      const float4* wr = (const float4*)&sW[d][0];
#pragma unroll
      for (int m4 = 0; m4 < LST / 4; m4++) a += dot4(xr[m4], wr[m4]);
    }
    sh[rr][d] = a;
  }
  __syncthreads();
  // h row-major store (coalesced)
  for (int idx = tid; idx < GROWS * DK_; idx += 256) {
    const int rr = idx / DK_, d = idx - rr * DK_;
    hb16[(size_t)(r0 + rr) * DK_ + d] = f2bf((d < LST) ? sh[rr][d] : 0.f);
  }
  // hT store, nn-major (32B segments)
  for (int idx = tid; idx < DK_ * GROWS; idx += 256) {
    const int d = idx >> 4, nn = idx & 15;
    hT[((size_t)b * DK_ + d) * N_ + n0 + nn] = f2bf((d < LST) ? sh[nn][d] : 0.f);
  }
  // gemm2: hA = sh @ A  (via A^T rows)
  for (int idx = tid; idx < GROWS * DK_; idx += 256) {
    const int rr = idx / DK_, d = idx - rr * DK_;
    float a = 0.f;
    if (d < D_) {
      const float4* hr = (const float4*)&sh[rr][0];
      const float4* ar = (const float4*)&sAt[d][0];
#pragma unroll
      for (int m4 = 0; m4 < LST / 4; m4++) a += dot4(hr[m4], ar[m4]);
    }
    hAb16[(size_t)(r0 + rr) * DK_ + d] = f2bf(a);
  }
}

// ------------------------- pass1: E sweep + deferred masked softmax stats
// grid (32 j-tiles, 8 i-chunks of 128, B), 256 thr
__global__ __launch_bounds__(256) void pass1_mfma(
    const unsigned* __restrict__ m1b, const unsigned* __restrict__ m2b,
    const short* __restrict__ hb16, const short* __restrict__ hAb16,
    float* __restrict__ M1p, float* __restrict__ S1p,
    float* __restrict__ M2p, float* __restrict__ S2p)
{
  const int jt = blockIdx.x, ic = blockIdx.y, b = blockIdx.z;
  const int tid = threadIdx.x, w = tid >> 6, lane = tid & 63;
  const int lr = lane & 15, kg = lane >> 4;
  const int ih = w >> 1, jh = w & 1;
  const int j0 = jt * 32;
  const short* hb  = hb16  + (size_t)b * N_ * DK_;
  const short* hAb = hAb16 + (size_t)b * N_ * DK_;

  bf16x8 b_h[3], b_hA[3];
  {
    const short* p = hb  + (size_t)(j0 + jh * 16 + lr) * DK_ + kg * 8;
    const short* q = hAb + (size_t)(j0 + jh * 16 + lr) * DK_ + kg * 8;
#pragma unroll
    for (int ks = 0; ks < 3; ks++) {
      b_h[ks]  = *(const bf16x8*)(p + ks * 32);
      b_hA[ks] = *(const bf16x8*)(q + ks * 32);
    }
  }
  const int bitp = jh * 16 + lr;
  const int i0base = ic * 128;
  float Ev[16];
  unsigned g1m = 0, g2m = 0;

#pragma unroll
  for (int iter = 0; iter < 4; iter++) {
    const int i0 = i0base + iter * 32 + ih * 16;
    const short* pa = hAb + (size_t)(i0 + lr) * DK_ + kg * 8;
    const short* ph = hb  + (size_t)(i0 + lr) * DK_ + kg * 8;
    bf16x8 a_hA[3], a_h[3];
#pragma unroll
    for (int ks = 0; ks < 3; ks++) {
      a_hA[ks] = *(const bf16x8*)(pa + ks * 32);
      a_h[ks]  = *(const bf16x8*)(ph + ks * 32);
    }
    const unsigned* W1p = m1b + ((size_t)b * N_ + i0 + kg * 4) * 32 + jt;
    const unsigned* W2p = m2b + ((size_t)b * N_ + i0 + kg * 4) * 32 + jt;
    unsigned mw1[4], mw2[4];
#pragma unroll
    for (int r = 0; r < 4; r++) { mw1[r] = W1p[(size_t)r * 32]; mw2[r] = W2p[(size_t)r * 32]; }
    f32x4 E = {0.f, 0.f, 0.f, 0.f};
#pragma unroll
    for (int ks = 0; ks < 3; ks++)
      E = __builtin_amdgcn_mfma_f32_16x16x32_bf16(a_hA[ks], b_h[ks], E, 0, 0, 0);
#pragma unroll
    for (int ks = 0; ks < 3; ks++)
      E = __builtin_amdgcn_mfma_f32_16x16x32_bf16(a_h[ks], b_hA[ks], E, 0, 0, 0);
#pragma unroll
    for (int r = 0; r < 4; r++) {
      Ev[iter * 4 + r] = E[r];
      g1m |= ((mw1[r] >> bitp) & 1u) << (iter * 4 + r);
      g2m |= ((mw2[r] >> bitp) & 1u) << (iter * 4 + r);
    }
  }
  // deferred masked max + exp-sum
  float M1r = -3.0e38f, M2r = -3.0e38f;
#pragma unroll
  for (int k = 0; k < 16; k++) {
    M1r = ((g1m >> k) & 1u) ? fmaxf(M1r, Ev[k]) : M1r;
    M2r = ((g2m >> k) & 1u) ? fmaxf(M2r, Ev[k]) : M2r;
  }
  float S1r = 0.f, S2r = 0.f;
#pragma unroll
  for (int k = 0; k < 16; k++) {
    S1r += ((g1m >> k) & 1u) ? __expf(Ev[k] - M1r) : 0.f;
    S2r += ((g2m >> k) & 1u) ? __expf(Ev[k] - M2r) : 0.f;
  }
  // merge across kg lane-groups (i direction)
#pragma unroll
  for (int off = 16; off <= 32; off <<= 1) {
    float Mo = __shfl_xor(M1r, off), So = __shfl_xor(S1r, off);
    float nM = fmaxf(M1r, Mo);
    S1r = S1r * __expf(M1r - nM) + So * __expf(Mo - nM); M1r = nM;
    Mo = __shfl_xor(M2r, off); So = __shfl_xor(S2r, off);
    nM = fmaxf(M2r, Mo);
    S2r = S2r * __expf(M2r - nM) + So * __expf(Mo - nM); M2r = nM;
  }
  __shared__ float sM[2][4][16], sS[2][4][16];
  if (lane < 16) {
    sM[0][w][lr] = M1r; sS[0][w][lr] = S1r;
    sM[1][w][lr] = M2r; sS[1][w][lr] = S2r;
  }
  __syncthreads();
  if (tid < 32) {
    const int jhh = tid >> 4, l2 = tid & 15;
    const size_t o = ((size_t)b * 8 + ic) * N_ + j0 + jhh * 16 + l2;
    {
      float Ma = sM[0][jhh][l2], Sa = sS[0][jhh][l2];
      float Mb = sM[0][2 + jhh][l2], Sb = sS[0][2 + jhh][l2];
      float nM = fmaxf(Ma, Mb);
      M1p[o] = nM; S1p[o] = Sa * __expf(Ma - nM) + Sb * __expf(Mb - nM);
    }
    {
      float Ma = sM[1][jhh][l2], Sa = sS[1][jhh][l2];
      float Mb = sM[1][2 + jhh][l2], Sb = sS[1][2 + jhh][l2];
      float nM = fmaxf(Ma, Mb);
      M2p[o] = nM; S2p[o] = Sa * __expf(Ma - nM) + Sb * __expf(Mb - nM);
    }
  }
}

// merge the 8 i-chunk partials
__global__ __launch_bounds__(256) void finalize_kernel(
    const float* __restrict__ M1p, const float* __restrict__ S1p,
    const float* __restrict__ M2p, const float* __restrict__ S2p,
    float* __restrict__ M1, float* __restrict__ S1,
    float* __restrict__ M2, float* __restrict__ S2)
{
  int idx = blockIdx.x * 256 + threadIdx.x;
  if (idx >= B_ * N_) return;
  int b = idx >> 10, k = idx & (N_ - 1);
  {
    float M = -3.0e38f, S = 0.f;
#pragma unroll
    for (int q = 0; q < 8; q++) {
      float m = M1p[((size_t)b * 8 + q) * N_ + k], s = S1p[((size_t)b * 8 + q) * N_ + k];
      float nM = fmaxf(M, m);
      S = S * __expf(M - nM) + s * __expf(m - nM); M = nM;
    }
    M1[idx] = M; S1[idx] = S;
  }
  {
    float M = -3.0e38f, S = 0.f;
#pragma unroll
    for (int q = 0; q < 8; q++) {
      float m = M2p[((size_t)b * 8 + q) * N_ + k], s = S2p[((size_t)b * 8 + q) * N_ + k];
      float nM = fmaxf(M, m);
      S = S * __expf(M - nM) + s * __expf(m - nM); M = nM;
    }
    M2[idx] = M; S2[idx] = S;
  }
}

// ------------------------------------------- pass2: E + PV via MFMA
__global__ __launch_bounds__(256) void pass2_mfma(
    const ushortT* __restrict__ adjp,
    const short* __restrict__ hb16, const short* __restrict__ hAb16,
    const short* __restrict__ hT16,
    const float* __restrict__ M1, const float* __restrict__ S1,
    const float* __restrict__ M2, const float* __restrict__ S2,
    ushortT* __restrict__ hp1p, ushortT* __restrict__ hp2p, int njt)
{
  const int it = blockIdx.x, jc = blockIdx.y, b = blockIdx.z;
  const int tid = threadIdx.x, w = tid >> 6, lane = tid & 63;
  const int lr = lane & 15, kg = lane >> 4;
  const int ih = w >> 1, jh = w & 1;
  const int i0 = it * 32;
  const int dbase = (w & 1) * 3;

  const short* hb  = hb16  + (size_t)b * N_ * DK_;
  const short* hAb = hAb16 + (size_t)b * N_ * DK_;
  const short* hTb = hT16  + (size_t)b * DK_ * N_;

  bf16x8 a_hA[3], a_h[3];
  {
    const short* pa = hAb + (size_t)(i0 + ih * 16 + lr) * DK_ + kg * 8;
    const short* ph = hb  + (size_t)(i0 + ih * 16 + lr) * DK_ + kg * 8;
#pragma unroll
    for (int ks = 0; ks < 3; ks++) {
      a_hA[ks] = *(const bf16x8*)(pa + ks * 32);
      a_h[ks]  = *(const bf16x8*)(ph + ks * 32);
    }
  }
  f32x4 acc[2][3];
#pragma unroll
  for (int m = 0; m < 2; m++)
#pragma unroll
    for (int q = 0; q < 3; q++) acc[m][q] = (f32x4){0.f, 0.f, 0.f, 0.f};

  __shared__ short wlds[2][2][32][40];   // [parity][matrix][i][j], stride 40
  const int j0base = jc * njt * 32;

  for (int t = 0; t < njt; ++t) {
    const int j0 = j0base + t * 32;
    const int jcol = j0 + jh * 16 + lr;
    const int par = t & 1;
    bf16x8 b_h[3], b_hA[3], bt[3];
    {
      const short* p = hb  + (size_t)(j0 + jh * 16 + lr) * DK_ + kg * 8;
      const short* q = hAb + (size_t)(j0 + jh * 16 + lr) * DK_ + kg * 8;
#pragma unroll
      for (int ks = 0; ks < 3; ks++) {
        b_h[ks]  = *(const bf16x8*)(p + ks * 32);
        b_hA[ks] = *(const bf16x8*)(q + ks * 32);
      }
    }
#pragma unroll
    for (int q = 0; q < 3; q++)
      bt[q] = *(const bf16x8*)(hTb + (size_t)((dbase + q) * 16 + lr) * N_ + j0 + kg * 8);

    float adj1v[4]; bool gon1[4], gon2[4];
    {
      const ushortT* Ap = adjp + ((size_t)b * N_ + jcol) * N_ + i0 + ih * 16 + kg * 4;
      ushortT uu[4];
      *(uint2*)uu = *(const uint2*)Ap;
#pragma unroll
      for (int r = 0; r < 4; r++) {
        adj1v[r] = bfdec(uu[r] & 0xFFFEu);
        gon1[r] = (uu[r] & 0xFFFEu) != 0; gon2[r] = (uu[r] & 1u) != 0;
      }
    }
    const float M1j = M1[(size_t)b * N_ + jcol];
    const float is1 = 1.0f / S1[(size_t)b * N_ + jcol];
    const float M2j = M2[(size_t)b * N_ + jcol];
    const float is2 = 1.0f / S2[(size_t)b * N_ + jcol];

    f32x4 E = {0.f, 0.f, 0.f, 0.f};
#pragma unroll
    for (int ks = 0; ks < 3; ks++)
      E = __builtin_amdgcn_mfma_f32_16x16x32_bf16(a_hA[ks], b_h[ks], E, 0, 0, 0);
#pragma unroll
    for (int ks = 0; ks < 3; ks++)
      E = __builtin_amdgcn_mfma_f32_16x16x32_bf16(a_h[ks], b_hA[ks], E, 0, 0, 0);

    short w1v[4], w2v[4];
#pragma unroll
    for (int r = 0; r < 4; r++) {
      const float e = E[r];
      w1v[r] = f2bf(gon1[r] ? __expf(e - M1j) * adj1v[r] * is1 : 0.f);
      w2v[r] = f2bf(gon2[r] ? __expf(e - M2j) * is2 : 0.f);
    }
#pragma unroll
    for (int r = 0; r < 4; r++) {
      wlds[par][0][ih * 16 + kg * 4 + r][jh * 16 + lr] = w1v[r];
      wlds[par][1][ih * 16 + kg * 4 + r][jh * 16 + lr] = w2v[r];
    }
    __syncthreads();
#pragma unroll
    for (int m = 0; m < 2; m++) {
      bf16x8 af = *(const bf16x8*)&wlds[par][m][ih * 16 + lr][kg * 8];
#pragma unroll
      for (int q = 0; q < 3; q++)
        acc[m][q] = __builtin_amdgcn_mfma_f32_16x16x32_bf16(af, bt[q], acc[m][q], 0, 0, 0);
    }
  }
#pragma unroll
  for (int m = 0; m < 2; m++) {
#pragma unroll
    for (int q = 0; q < 3; q++) {
      const int dt = dbase + q;
      if (dt < 5) {
        ushortT* dst = (m ? hp2p : hp1p) +
            (((size_t)jc * B_ + b) * N_ + i0 + ih * 16 + kg * 4) * 80 + dt * 16 + lr;
#pragma unroll
        for (int r = 0; r < 4; r++) dst[(size_t)r * 80] = (ushortT)f2bf(acc[m][q][r]);
      }
    }
  }
}

// ---------------------- final-layer combine (in-place x)
__global__ __launch_bounds__(256) void combine_kernel(
    float* __restrict__ x,
    const ushortT* __restrict__ hp1p, const ushortT* __restrict__ hp2p, int JC,
    const float* __restrict__ g1, const float* __restrict__ g2w,
    const float* __restrict__ g2b)
{
  const int r = blockIdx.x * 4 + (threadIdx.x >> 6);
  const int t = threadIdx.x & 63;
  float s1a = 0.f, s2a = 0.f, s1b = 0.f, s2b = 0.f;
  for (int q = 0; q < JC; q++) {
    const size_t base = ((size_t)q * (B_ * N_) + r) * 80;
    s1a += bfdec(hp1p[base + t]);
    s2a += bfdec(hp2p[base + t]);
    if (t < D_ - 64) {
      s1b += bfdec(hp1p[base + 64 + t]);
      s2b += bfdec(hp2p[base + 64 + t]);
    }
  }
  const float a0 = fmaxf(s1a, 0.f), b0 = fmaxf(s2a, 0.f);
  const float a1v = fmaxf(s1b, 0.f), b1v = fmaxf(s2b, 0.f);
  float* xr = x + (size_t)r * D_;
  const float x0 = xr[t];
  float d1 = x0 * g1[t], d2 = a0 * g2w[t], d3 = b0 * g2w[t];
  float x1 = 0.f;
  if (t < D_ - 64) {
    x1 = xr[64 + t];
    d1 += x1 * g1[64 + t]; d2 += a1v * g2w[64 + t]; d3 += b1v * g2w[64 + t];
  }
#pragma unroll
  for (int off = 1; off < 64; off <<= 1) {
    d1 += __shfl_xor(d1, off);
    d2 += __shfl_xor(d2, off);
    d3 += __shfl_xor(d3, off);
  }
  const float bb = g2b[0];
  const float c1 = 1.f / (1.f + __expf(-(d1 + d2 + bb)));
  const float c2 = 1.f / (1.f + __expf(-(d1 + d3 + bb)));
  xr[t] = (c1 * x0 + (1.f - c1) * a0) - (c2 * x0 + (1.f - c2) * b0);
  if (t < D_ - 64)
    xr[64 + t] = (c1 * x1 + (1.f - c1) * a1v) - (c2 * x1 + (1.f - c2) * b1v);
}

// ------------------------------------------- masked sum pool over N
__global__ __launch_bounds__(256) void pool_kernel(
    const float* __restrict__ x, const float* __restrict__ V, float* __restrict__ pooled)
{
  const int d = blockIdx.x, b = blockIdx.y, t = threadIdx.x;
  const float* xb = x + (size_t)b * N_ * D_;
  const float* Vb = V + (size_t)b * N_;
  float s = 0.f;
  for (int n = t; n < N_; n += 256) s += xb[(size_t)n * D_ + d] * Vb[n];
#pragma unroll
  for (int off = 32; off >= 1; off >>= 1) s += __shfl_down(s, off);
  __shared__ float red[4];
  if ((t & 63) == 0) red[t >> 6] = s;
  __syncthreads();
  if (t == 0) pooled[b * D_ + d] = red[0] + red[1] + red[2] + red[3];
}

// ------------------------------------------- MLP head (single block, 1024 thr)
__global__ __launch_bounds__(1024) void fc_kernel(
    const float* __restrict__ pooled,
    const float* __restrict__ w0, const float* __restrict__ b0,
    const float* __restrict__ w1, const float* __restrict__ b1,
    const float* __restrict__ w2, const float* __restrict__ b2,
    const float* __restrict__ w3, const float* __restrict__ b3,
    float* __restrict__ out)
{
  __shared__ float pin[B_][D_];
  __shared__ float bufA[B_][DFC_], bufB[B_][DFC_];
  const int t = threadIdx.x;
  if (t < B_ * D_) pin[t / D_][t % D_] = pooled[t];
  __syncthreads();
  const int r = t >> 7, o = t & 127;
  {
    float a = b0[o];
    const float2* wr = (const float2*)(w0 + o * D_);
#pragma unroll
    for (int m2 = 0; m2 < D_ / 2; m2++) {
      const float2 wv = wr[m2];
      a += pin[r][m2 * 2] * wv.x + pin[r][m2 * 2 + 1] * wv.y;
    }
    bufA[r][o] = fmaxf(a, 0.f);
  }
  __syncthreads();
  {
    float a = b1[o];
    const float4* wr = (const float4*)(w1 + o * DFC_);
    const float4* br = (const float4*)&bufA[r][0];
#pragma unroll
    for (int m4 = 0; m4 < DFC_ / 4; m4++) a += dot4(br[m4], wr[m4]);
    bufB[r][o] = fmaxf(a, 0.f);
  }
  __syncthreads();
  {
    float a = b2[o];
    const float4* wr = (const float4*)(w2 + o * DFC_);
    const float4* br = (const float4*)&bufB[r][0];
#pragma unroll
    for (int m4 = 0; m4 < DFC_ / 4; m4++) a += dot4(br[m4], wr[m4]);
    bufA[r][o] = fmaxf(a, 0.f);
  }
  __syncthreads();
  if (t < 64) {
    const int rr = t >> 3, l8 = t & 7;
    const float4* wr = (const float4*)(w3 + l8 * 16);
    const float4* br = (const float4*)&bufA[rr][l8 * 16];
    float a = 0.f;
#pragma unroll
    for (int m4 = 0; m4 < 4; m4++) a += dot4(br[m4], wr[m4]);
    a += __shfl_xor(a, 1); a += __shfl_xor(a, 2); a += __shfl_xor(a, 4);
    if (l8 == 0) out[rr] = 1.f / (1.f + __expf(-(a + b3[0])));
  }
}

// ----------------------------------------------------------------------
extern "C" void kernel_launch(void* const* d_in, const int* in_sizes, int n_in,
                              void* d_out, int out_size, void* d_ws, size_t ws_size,
                              hipStream_t stream)
{
  const float* H     = (const float*)d_in[0];
  const float* A1    = (const float*)d_in[1];
  const float* A2    = (const float*)d_in[2];
  const float* V     = (const float*)d_in[3];
  const float* few   = (const float*)d_in[4];
  const float* mup   = (const float*)d_in[5];
  const float* devp  = (const float*)d_in[6];
  const float* gW    = (const float*)d_in[7];
  const float* gA    = (const float*)d_in[8];
  const float* g1    = (const float*)d_in[9];
  const float* g2w   = (const float*)d_in[10];
  const float* g2b   = (const float*)d_in[11];
  const float* w0 = (const float*)d_in[12]; const float* b0 = (const float*)d_in[13];
  const float* w1 = (const float*)d_in[14]; const float* b1 = (const float*)d_in[15];
  const float* w2 = (const float*)d_in[16]; const float* b2 = (const float*)d_in[17];
  const float* w3 = (const float*)d_in[18]; const float* b3 = (const float*)d_in[19];
  float* outp = (float*)d_out;

  float* ws = (float*)d_ws;
  // fixed layout (float offsets)
  float*   x     = ws;                         // 573440
  short*   hb16  = (short*)(ws + 573440);      // B*N*96 bf16
  short*   hAb16 = (short*)(ws + 966656);
  short*   hT16  = (short*)(ws + 1359872);     // B*96*N bf16
  float*   At    = ws + 1753088;               // 4*70*70
  float*   M1    = ws + 1772688;
  float*   S1    = ws + 1780880;
  float*   M2    = ws + 1789072;
  float*   S2    = ws + 1797264;
  float*   M1p   = ws + 1805456;               // 8*B*N
  float*   S1p   = ws + 1870992;
  float*   M2p   = ws + 1936528;
  float*   S2p   = ws + 2002064;
  float*   pooled= ws + 2067600;               // 576
  ushortT* adjp  = (ushortT*)(ws + 2068176);   // B*N*N u16
  unsigned* m1b  = (unsigned*)(ws + 6262480);  // B*N*32 u32
  unsigned* m2b  = (unsigned*)(ws + 6524624);

  auto need = [](int jc) -> size_t {
    return (size_t)(6786768u + (size_t)jc * 655360u) * 4u;
  };
  int JC;
  if      (need(4) <= ws_size) JC = 4;
  else if (need(2) <= ws_size) JC = 2;
  else if (need(1) <= ws_size) JC = 1;
  else return;
  ushortT* hp1p = (ushortT*)(ws + 6786768u);
  ushortT* hp2p = hp1p + (size_t)JC * 655360u;
  const int njt = (N_ / 32) / JC;
  const int ROWS = B_ * N_;

  prep_w<<<4, 256, 0, stream>>>(gA, At);
  prep_adj_mask<<<ROWS, 256, 0, stream>>>(A1, A2, mup, devp, adjp, m1b, m2b);

  for (int k = 0; k < 4; k++) {
    const float* Wk  = gW + (size_t)k * D_ * D_;
    const float* Atk = At + (size_t)k * D_ * D_;
    if (k == 0)
      gatmm_fused<0><<<ROWS / GROWS, 256, 0, stream>>>(
          x, H, few, nullptr, nullptr, 0, nullptr, nullptr, nullptr,
          Wk, Atk, hb16, hAb16, hT16);
    else
      gatmm_fused<1><<<ROWS / GROWS, 256, 0, stream>>>(
          x, nullptr, nullptr, hp1p, hp2p, JC,
          g1 + (size_t)(k - 1) * D_, g2w + (size_t)(k - 1) * D_, g2b + (k - 1),
          Wk, Atk, hb16, hAb16, hT16);
    pass1_mfma<<<dim3(32, 8, B_), 256, 0, stream>>>(m1b, m2b, hb16, hAb16,
                                                    M1p, S1p, M2p, S2p);
    finalize_kernel<<<(B_ * N_ + 255) / 256, 256, 0, stream>>>(M1p, S1p, M2p, S2p,
                                                               M1, S1, M2, S2);
    pass2_mfma<<<dim3(32, JC, B_), 256, 0, stream>>>(adjp, hb16, hAb16, hT16,
                                                     M1, S1, M2, S2, hp1p, hp2p, njt);
  }
  combine_kernel<<<ROWS / 4, 256, 0, stream>>>(x, hp1p, hp2p, JC,
                                               g1 + 3 * D_, g2w + 3 * D_, g2b + 3);
  pool_kernel<<<dim3(D_, B_), 256, 0, stream>>>(x, V, pooled);
  fc_kernel<<<1, 1024, 0, stream>>>(pooled, w0, b0, w1, b1, w2, b2, w3, b3, outp);
}

// Round 6
// 356.412 us; speedup vs baseline: 1.1455x; 1.1455x over previous
//
#include <hip/hip_runtime.h>

#define B_   8
#define N_   1024
#define F0_  56
#define D_   70
#define DK_  96      // bf16 K-padded row stride (3 x 32)
#define DFC_ 128
#define NEG_BIG (-9e15f)

typedef __attribute__((ext_vector_type(8))) short bf16x8;
typedef __attribute__((ext_vector_type(4))) float f32x4;
typedef unsigned short ushortT;

__device__ __forceinline__ short f2bf(float x) {
  unsigned u = __builtin_bit_cast(unsigned, x);
  u += 0x7FFF + ((u >> 16) & 1);
  return (short)(u >> 16);
}
__device__ __forceinline__ float bfdec(unsigned u16bits) {
  unsigned v = u16bits << 16;
  return __builtin_bit_cast(float, v);
}
__device__ __forceinline__ float dot4(float4 a, float4 b) {
  return a.x * b.x + a.y * b.y + a.z * b.z + a.w * b.w;
}

// ------------------------------------ weights -> bf16 padded; hT pad-zero
// blocks 0-3: Wb16[k][80][96]; 4-7: Atb16[k][80][96] (= gA^T); 8-15: hT rows 80..95 = 0
__global__ __launch_bounds__(256) void prep_wb(
    const float* __restrict__ gW, const float* __restrict__ gA,
    short* __restrict__ Wb16, short* __restrict__ Atb16, short* __restrict__ hT)
{
  const int blk = blockIdx.x;
  if (blk < 8) {
    const int k = blk & 3;
    const bool isW = blk < 4;
    short* dst = (isW ? Wb16 : Atb16) + (size_t)k * 80 * 96;
    const float* src = (isW ? gW : gA) + (size_t)k * D_ * D_;
    for (int i = threadIdx.x; i < 80 * 96; i += 256) {
      const int d = i / 96, m = i - (i / 96) * 96;
      float v = 0.f;
      if (d < D_ && m < D_) v = isW ? src[d * D_ + m] : src[m * D_ + d];
      dst[i] = f2bf(v);
    }
  } else {
    const int b = blk - 8;
    uint2* p = (uint2*)(hT + ((size_t)(b * 96 + 80)) * N_);
    for (int i = threadIdx.x; i < 16 * N_ / 4; i += 256) p[i] = (uint2){0, 0};
  }
}

// ---------------------------------------------------------------- featem
__global__ __launch_bounds__(128) void featem_kernel(
    const float* __restrict__ H, const float* __restrict__ W, float* __restrict__ x)
{
  const int r = blockIdx.x, t = threadIdx.x;
  __shared__ float row[F0_];
  if (t < F0_) row[t] = H[(size_t)r * F0_ + t];
  __syncthreads();
  if (t < D_) {
    float a = 0.f;
#pragma unroll 8
    for (int m = 0; m < F0_; m++) a += row[m] * W[t * F0_ + m];
    x[(size_t)r * D_ + t] = a;
  }
}

// ------------------------------------- adjacency pack + bitmasks (fused)
__global__ __launch_bounds__(256) void prep_adj_mask(
    const float* __restrict__ A1, const float* __restrict__ A2,
    const float* __restrict__ mup, const float* __restrict__ devp,
    ushortT* __restrict__ adjp, unsigned* __restrict__ m1b, unsigned* __restrict__ m2b)
{
  const int row = blockIdx.x;             // b*N + i
  const int t = threadIdx.x;
  __shared__ unsigned w1s[32], w2s[32];
  if (t < 32) { w1s[t] = 0; w2s[t] = 0; }
  __syncthreads();
  const size_t base = (size_t)row * N_ + t * 4;
  const float4 a1 = *(const float4*)(A1 + base);
  const float4 a2 = *(const float4*)(A2 + base);
  const float mu = mup[0], idev = 1.0f / devp[0];
  const float a1v[4] = {a1.x, a1.y, a1.z, a1.w};
  const float a2v[4] = {a2.x, a2.y, a2.z, a2.w};
  ushortT out[4];
  unsigned b1 = 0, b2 = 0;
#pragma unroll
  for (int k = 0; k < 4; k++) {
    const float rbf = (a2v[k] <= 10.f) ? __expf(-(a2v[k] - mu) * (a2v[k] - mu) * idev) : 0.f;
    const float adj1 = rbf + a1v[k];
    ushortT u = ((ushortT)f2bf(adj1)) & 0xFFFE;
    if (a1v[k] > 0.f) u |= 1;
    out[k] = u;
    b1 |= ((u & 0xFFFEu) ? 1u : 0u) << k;
    b2 |= (u & 1u) << k;
  }
  *(uint2*)(adjp + base) = *(uint2*)out;
  atomicOr(&w1s[t >> 3], b1 << ((t & 7) * 4));
  atomicOr(&w2s[t >> 3], b2 << ((t & 7) * 4));
  __syncthreads();
  if (t < 32) {
    m1b[(size_t)row * 32 + t] = w1s[t];
    m2b[(size_t)row * 32 + t] = w2s[t];
  }
}

// ---------------- fused [combine] + h + hA + hT via MFMA (32 rows, 2 waves)
// MODE 0: read x (from featem). MODE 1: combine prev layer into x first.
template<int MODE>
__global__ __launch_bounds__(128) void gatmm_mfma(
    float* __restrict__ x,
    const ushortT* __restrict__ hp1p, const ushortT* __restrict__ hp2p, int JC,
    const float* __restrict__ g1, const float* __restrict__ g2w, const float* __restrict__ g2b,
    const short* __restrict__ Wb, const short* __restrict__ Atb,
    short* __restrict__ hb16, short* __restrict__ hAb16, short* __restrict__ hT)
{
  const int tid = threadIdx.x;
  const int w = tid >> 6, lane = tid & 63;
  const int lr = lane & 15, kg = lane >> 4;
  const int r0 = blockIdx.x * 32;
  const int b = r0 >> 10, n0 = r0 & (N_ - 1);

  __shared__ __align__(16) short sxb[32][104];  // row stride 208B (13x16)
  __shared__ __align__(16) short shl[32][104];

  // zero pad cols 64..103 of both buffers
  for (int i = tid; i < 320; i += 128) {
    const int r = i / 10, c = i - (i / 10) * 10;
    *(uint2*)&sxb[r][64 + c * 4] = (uint2){0, 0};
    *(uint2*)&shl[r][64 + c * 4] = (uint2){0, 0};
  }

  if (MODE == 0) {
    for (int i = tid; i < 32 * D_; i += 128) {
      const int r = i / D_;
      sxb[r][i - r * D_] = f2bf(x[(size_t)r0 * D_ + i]);
    }
  } else {
    const int lt = tid & 15, gg = tid >> 4;   // 8 groups x 16 lanes
#pragma unroll
    for (int rg = 0; rg < 4; rg++) {
      const int row = gg * 4 + rg;
      const int grow = r0 + row;
      float s1[5], s2[5], xv[5];
#pragma unroll
      for (int q = 0; q < 5; q++) { s1[q] = 0.f; s2[q] = 0.f; xv[q] = 0.f; }
      for (int jc = 0; jc < JC; jc++) {
        const size_t bp = ((size_t)jc * (B_ * N_) + grow) * 80 + lt;
#pragma unroll
        for (int q = 0; q < 5; q++) {
          s1[q] += bfdec(hp1p[bp + 16 * q]);
          s2[q] += bfdec(hp2p[bp + 16 * q]);
        }
      }
      float d1 = 0.f, d2 = 0.f, d3 = 0.f;
#pragma unroll
      for (int q = 0; q < 5; q++) {
        const int d = lt + 16 * q;
        if (d < D_) {
          s1[q] = fmaxf(s1[q], 0.f); s2[q] = fmaxf(s2[q], 0.f);
          xv[q] = x[(size_t)grow * D_ + d];
          d1 += xv[q] * g1[d]; d2 += s1[q] * g2w[d]; d3 += s2[q] * g2w[d];
        }
      }
#pragma unroll
      for (int off = 1; off < 16; off <<= 1) {
        d1 += __shfl_xor(d1, off); d2 += __shfl_xor(d2, off); d3 += __shfl_xor(d3, off);
      }
      const float bb = g2b[0];
      const float c1 = 1.f / (1.f + __expf(-(d1 + d2 + bb)));
      const float c2 = 1.f / (1.f + __expf(-(d1 + d3 + bb)));
#pragma unroll
      for (int q = 0; q < 5; q++) {
        const int d = lt + 16 * q;
        if (d < D_) {
          const float xn = (c1 * xv[q] + (1.f - c1) * s1[q]) - (c2 * xv[q] + (1.f - c2) * s2[q]);
          x[(size_t)grow * D_ + d] = xn;
          sxb[row][d] = f2bf(xn);
        }
      }
    }
  }
  __syncthreads();

  // GEMM1: h = x @ W^T  (wave w -> rows w*16..w*16+15)
  bf16x8 af[3];
#pragma unroll
  for (int ks = 0; ks < 3; ks++)
    af[ks] = *(const bf16x8*)&sxb[w * 16 + lr][ks * 32 + kg * 8];
  f32x4 acc[5];
#pragma unroll
  for (int nt = 0; nt < 5; nt++) acc[nt] = (f32x4){0.f, 0.f, 0.f, 0.f};
#pragma unroll
  for (int nt = 0; nt < 5; nt++) {
#pragma unroll
    for (int ks = 0; ks < 3; ks++) {
      bf16x8 bw = *(const bf16x8*)(Wb + (size_t)(nt * 16 + lr) * 96 + ks * 32 + kg * 8);
      acc[nt] = __builtin_amdgcn_mfma_f32_16x16x32_bf16(af[ks], bw, acc[nt], 0, 0, 0);
    }
  }
#pragma unroll
  for (int nt = 0; nt < 5; nt++)
#pragma unroll
    for (int r = 0; r < 4; r++)
      shl[w * 16 + kg * 4 + r][nt * 16 + lr] = f2bf(acc[nt][r]);
  __syncthreads();

  // h row-major store
  for (int i = tid; i < 32 * 12; i += 128) {
    const int r = i / 12, seg = i - (i / 12) * 12;
    *(bf16x8*)(hb16 + (size_t)(r0 + r) * DK_ + seg * 8) = *(const bf16x8*)&shl[r][seg * 8];
  }
  // hT store (d-major rows, 16B segments in n)
  for (int i = tid; i < 80 * 4; i += 128) {
    const int d = i >> 2, ng = i & 3;
    short tmp[8];
#pragma unroll
    for (int k = 0; k < 8; k++) tmp[k] = shl[ng * 8 + k][d];
    *(bf16x8*)(hT + ((size_t)(b * 96 + d)) * N_ + n0 + ng * 8) = *(bf16x8*)tmp;
  }

  // GEMM2: hA = h @ A  (B-frags from A^T)
  bf16x8 ah[3];
#pragma unroll
  for (int ks = 0; ks < 3; ks++)
    ah[ks] = *(const bf16x8*)&shl[w * 16 + lr][ks * 32 + kg * 8];
  f32x4 acc2[5];
#pragma unroll
  for (int nt = 0; nt < 5; nt++) acc2[nt] = (f32x4){0.f, 0.f, 0.f, 0.f};
#pragma unroll
  for (int nt = 0; nt < 5; nt++) {
#pragma unroll
    for (int ks = 0; ks < 3; ks++) {
      bf16x8 bw = *(const bf16x8*)(Atb + (size_t)(nt * 16 + lr) * 96 + ks * 32 + kg * 8);
      acc2[nt] = __builtin_amdgcn_mfma_f32_16x16x32_bf16(ah[ks], bw, acc2[nt], 0, 0, 0);
    }
  }
#pragma unroll
  for (int nt = 0; nt < 5; nt++)
#pragma unroll
    for (int r = 0; r < 4; r++)
      sxb[w * 16 + kg * 4 + r][nt * 16 + lr] = f2bf(acc2[nt][r]);
  __syncthreads();
  for (int i = tid; i < 32 * 12; i += 128) {
    const int r = i / 12, seg = i - (i / 12) * 12;
    *(bf16x8*)(hAb16 + (size_t)(r0 + r) * DK_ + seg * 8) = *(const bf16x8*)&sxb[r][seg * 8];
  }
}

// ------------------------- pass1: E sweep + deferred masked softmax stats
__global__ __launch_bounds__(256) void pass1_mfma(
    const unsigned* __restrict__ m1b, const unsigned* __restrict__ m2b,
    const short* __restrict__ hb16, const short* __restrict__ hAb16,
    float* __restrict__ M1p, float* __restrict__ S1p,
    float* __restrict__ M2p, float* __restrict__ S2p)
{
  const int jt = blockIdx.x, ic = blockIdx.y, b = blockIdx.z;
  const int tid = threadIdx.x, w = tid >> 6, lane = tid & 63;
  const int lr = lane & 15, kg = lane >> 4;
  const int ih = w >> 1, jh = w & 1;
  const int j0 = jt * 32;
  const short* hb  = hb16  + (size_t)b * N_ * DK_;
  const short* hAb = hAb16 + (size_t)b * N_ * DK_;

  bf16x8 b_h[3], b_hA[3];
  {
    const short* p = hb  + (size_t)(j0 + jh * 16 + lr) * DK_ + kg * 8;
    const short* q = hAb + (size_t)(j0 + jh * 16 + lr) * DK_ + kg * 8;
#pragma unroll
    for (int ks = 0; ks < 3; ks++) {
      b_h[ks]  = *(const bf16x8*)(p + ks * 32);
      b_hA[ks] = *(const bf16x8*)(q + ks * 32);
    }
  }
  const int bitp = jh * 16 + lr;
  const int i0base = ic * 128;
  float Ev[16];
  unsigned g1m = 0, g2m = 0;

#pragma unroll
  for (int iter = 0; iter < 4; iter++) {
    const int i0 = i0base + iter * 32 + ih * 16;
    const short* pa = hAb + (size_t)(i0 + lr) * DK_ + kg * 8;
    const short* ph = hb  + (size_t)(i0 + lr) * DK_ + kg * 8;
    bf16x8 a_hA[3], a_h[3];
#pragma unroll
    for (int ks = 0; ks < 3; ks++) {
      a_hA[ks] = *(const bf16x8*)(pa + ks * 32);
      a_h[ks]  = *(const bf16x8*)(ph + ks * 32);
    }
    const unsigned* W1p = m1b + ((size_t)b * N_ + i0 + kg * 4) * 32 + jt;
    const unsigned* W2p = m2b + ((size_t)b * N_ + i0 + kg * 4) * 32 + jt;
    unsigned mw1[4], mw2[4];
#pragma unroll
    for (int r = 0; r < 4; r++) { mw1[r] = W1p[(size_t)r * 32]; mw2[r] = W2p[(size_t)r * 32]; }
    f32x4 E = {0.f, 0.f, 0.f, 0.f};
#pragma unroll
    for (int ks = 0; ks < 3; ks++)
      E = __builtin_amdgcn_mfma_f32_16x16x32_bf16(a_hA[ks], b_h[ks], E, 0, 0, 0);
#pragma unroll
    for (int ks = 0; ks < 3; ks++)
      E = __builtin_amdgcn_mfma_f32_16x16x32_bf16(a_h[ks], b_hA[ks], E, 0, 0, 0);
#pragma unroll
    for (int r = 0; r < 4; r++) {
      Ev[iter * 4 + r] = E[r];
      g1m |= ((mw1[r] >> bitp) & 1u) << (iter * 4 + r);
      g2m |= ((mw2[r] >> bitp) & 1u) << (iter * 4 + r);
    }
  }
  float M1r = -3.0e38f, M2r = -3.0e38f;
#pragma unroll
  for (int k = 0; k < 16; k++) {
    M1r = ((g1m >> k) & 1u) ? fmaxf(M1r, Ev[k]) : M1r;
    M2r = ((g2m >> k) & 1u) ? fmaxf(M2r, Ev[k]) : M2r;
  }
  float S1r = 0.f, S2r = 0.f;
#pragma unroll
  for (int k = 0; k < 16; k++) {
    S1r += ((g1m >> k) & 1u) ? __expf(Ev[k] - M1r) : 0.f;
    S2r += ((g2m >> k) & 1u) ? __expf(Ev[k] - M2r) : 0.f;
  }
#pragma unroll
  for (int off = 16; off <= 32; off <<= 1) {
    float Mo = __shfl_xor(M1r, off), So = __shfl_xor(S1r, off);
    float nM = fmaxf(M1r, Mo);
    S1r = S1r * __expf(M1r - nM) + So * __expf(Mo - nM); M1r = nM;
    Mo = __shfl_xor(M2r, off); So = __shfl_xor(S2r, off);
    nM = fmaxf(M2r, Mo);
    S2r = S2r * __expf(M2r - nM) + So * __expf(Mo - nM); M2r = nM;
  }
  __shared__ float sM[2][4][16], sS[2][4][16];
  if (lane < 16) {
    sM[0][w][lr] = M1r; sS[0][w][lr] = S1r;
    sM[1][w][lr] = M2r; sS[1][w][lr] = S2r;
  }
  __syncthreads();
  if (tid < 32) {
    const int jhh = tid >> 4, l2 = tid & 15;
    const size_t o = ((size_t)b * 8 + ic) * N_ + j0 + jhh * 16 + l2;
    {
      float Ma = sM[0][jhh][l2], Sa = sS[0][jhh][l2];
      float Mb = sM[0][2 + jhh][l2], Sb = sS[0][2 + jhh][l2];
      float nM = fmaxf(Ma, Mb);
      M1p[o] = nM; S1p[o] = Sa * __expf(Ma - nM) + Sb * __expf(Mb - nM);
    }
    {
      float Ma = sM[1][jhh][l2], Sa = sS[1][jhh][l2];
      float Mb = sM[1][2 + jhh][l2], Sb = sS[1][2 + jhh][l2];
      float nM = fmaxf(Ma, Mb);
      M2p[o] = nM; S2p[o] = Sa * __expf(Ma - nM) + Sb * __expf(Mb - nM);
    }
  }
}

// --------------------- pass2: inline finalize + E + PV via MFMA
__global__ __launch_bounds__(256) void pass2_mfma(
    const ushortT* __restrict__ adjp,
    const short* __restrict__ hb16, const short* __restrict__ hAb16,
    const short* __restrict__ hT16,
    const float* __restrict__ M1p, const float* __restrict__ S1p,
    const float* __restrict__ M2p, const float* __restrict__ S2p,
    ushortT* __restrict__ hp1p, ushortT* __restrict__ hp2p, int njt)
{
  const int it = blockIdx.x, jc = blockIdx.y, b = blockIdx.z;
  const int tid = threadIdx.x, w = tid >> 6, lane = tid & 63;
  const int lr = lane & 15, kg = lane >> 4;
  const int ih = w >> 1, jh = w & 1;
  const int i0 = it * 32;
  const int dbase = (w & 1) * 3;
  const int jbase = jc * njt * 32;

  __shared__ float sMS[4][1024];
  for (int idx = tid; idx < njt * 32; idx += 256) {
    const int col = jbase + idx;
    float M = -3.0e38f, S = 0.f;
#pragma unroll
    for (int q = 0; q < 8; q++) {
      const float m = M1p[((size_t)b * 8 + q) * N_ + col];
      const float s = S1p[((size_t)b * 8 + q) * N_ + col];
      const float nM = fmaxf(M, m);
      S = S * __expf(M - nM) + s * __expf(m - nM); M = nM;
    }
    sMS[0][idx] = M; sMS[1][idx] = 1.0f / S;
    M = -3.0e38f; S = 0.f;
#pragma unroll
    for (int q = 0; q < 8; q++) {
      const float m = M2p[((size_t)b * 8 + q) * N_ + col];
      const float s = S2p[((size_t)b * 8 + q) * N_ + col];
      const float nM = fmaxf(M, m);
      S = S * __expf(M - nM) + s * __expf(m - nM); M = nM;
    }
    sMS[2][idx] = M; sMS[3][idx] = 1.0f / S;
  }

  const short* hb  = hb16  + (size_t)b * N_ * DK_;
  const short* hAb = hAb16 + (size_t)b * N_ * DK_;
  const short* hTb = hT16  + (size_t)b * DK_ * N_;

  bf16x8 a_hA[3], a_h[3];
  {
    const short* pa = hAb + (size_t)(i0 + ih * 16 + lr) * DK_ + kg * 8;
    const short* ph = hb  + (size_t)(i0 + ih * 16 + lr) * DK_ + kg * 8;
#pragma unroll
    for (int ks = 0; ks < 3; ks++) {
      a_hA[ks] = *(const bf16x8*)(pa + ks * 32);
      a_h[ks]  = *(const bf16x8*)(ph + ks * 32);
    }
  }
  f32x4 acc[2][3];
#pragma unroll
  for (int m = 0; m < 2; m++)
#pragma unroll
    for (int q = 0; q < 3; q++) acc[m][q] = (f32x4){0.f, 0.f, 0.f, 0.f};

  __shared__ short wlds[2][2][32][40];
  __syncthreads();

  for (int t = 0; t < njt; ++t) {
    const int j0 = jbase + t * 32;
    const int jcol = j0 + jh * 16 + lr;
    const int jrel = jcol - jbase;
    const int par = t & 1;
    bf16x8 b_h[3], b_hA[3], bt[3];
    {
      const short* p = hb  + (size_t)(j0 + jh * 16 + lr) * DK_ + kg * 8;
      const short* q = hAb + (size_t)(j0 + jh * 16 + lr) * DK_ + kg * 8;
#pragma unroll
      for (int ks = 0; ks < 3; ks++) {
        b_h[ks]  = *(const bf16x8*)(p + ks * 32);
        b_hA[ks] = *(const bf16x8*)(q + ks * 32);
      }
    }
#pragma unroll
    for (int q = 0; q < 3; q++)
      bt[q] = *(const bf16x8*)(hTb + (size_t)((dbase + q) * 16 + lr) * N_ + j0 + kg * 8);

    float adj1v[4]; bool gon1[4], gon2[4];
    {
      const ushortT* Ap = adjp + ((size_t)b * N_ + jcol) * N_ + i0 + ih * 16 + kg * 4;
      ushortT uu[4];
      *(uint2*)uu = *(const uint2*)Ap;
#pragma unroll
      for (int r = 0; r < 4; r++) {
        adj1v[r] = bfdec(uu[r] & 0xFFFEu);
        gon1[r] = (uu[r] & 0xFFFEu) != 0; gon2[r] = (uu[r] & 1u) != 0;
      }
    }
    const float M1j = sMS[0][jrel], is1 = sMS[1][jrel];
    const float M2j = sMS[2][jrel], is2 = sMS[3][jrel];

    f32x4 E = {0.f, 0.f, 0.f, 0.f};
#pragma unroll
    for (int ks = 0; ks < 3; ks++)
      E = __builtin_amdgcn_mfma_f32_16x16x32_bf16(a_hA[ks], b_h[ks], E, 0, 0, 0);
#pragma unroll
    for (int ks = 0; ks < 3; ks++)
      E = __builtin_amdgcn_mfma_f32_16x16x32_bf16(a_h[ks], b_hA[ks], E, 0, 0, 0);

    short w1v[4], w2v[4];
#pragma unroll
    for (int r = 0; r < 4; r++) {
      const float e = E[r];
      w1v[r] = f2bf(gon1[r] ? __expf(e - M1j) * adj1v[r] * is1 : 0.f);
      w2v[r] = f2bf(gon2[r] ? __expf(e - M2j) * is2 : 0.f);
    }
#pragma unroll
    for (int r = 0; r < 4; r++) {
      wlds[par][0][ih * 16 + kg * 4 + r][jh * 16 + lr] = w1v[r];
      wlds[par][1][ih * 16 + kg * 4 + r][jh * 16 + lr] = w2v[r];
    }
    __syncthreads();
#pragma unroll
    for (int m = 0; m < 2; m++) {
      bf16x8 af = *(const bf16x8*)&wlds[par][m][ih * 16 + lr][kg * 8];
#pragma unroll
      for (int q = 0; q < 3; q++)
        acc[m][q] = __builtin_amdgcn_mfma_f32_16x16x32_bf16(af, bt[q], acc[m][q], 0, 0, 0);
    }
  }
#pragma unroll
  for (int m = 0; m < 2; m++) {
#pragma unroll
    for (int q = 0; q < 3; q++) {
      const int dt = dbase + q;
      if (dt < 5) {
        ushortT* dst = (m ? hp2p : hp1p) +
            (((size_t)jc * B_ + b) * N_ + i0 + ih * 16 + kg * 4) * 80 + dt * 16 + lr;
#pragma unroll
        for (int r = 0; r < 4; r++) dst[(size_t)r * 80] = (ushortT)f2bf(acc[m][q][r]);
      }
    }
  }
}

// ---------------------- final-layer combine (in-place x)
__global__ __launch_bounds__(256) void combine_kernel(
    float* __restrict__ x,
    const ushortT* __restrict__ hp1p, const ushortT* __restrict__ hp2p, int JC,
    const float* __restrict__ g1, const float* __restrict__ g2w,
    const float* __restrict__ g2b)
{
  const int r = blockIdx.x * 4 + (threadIdx.x >> 6);
  const int t = threadIdx.x & 63;
  float s1a = 0.f, s2a = 0.f, s1b = 0.f, s2b = 0.f;
  for (int q = 0; q < JC; q++) {
    const size_t base = ((size_t)q * (B_ * N_) + r) * 80;
    s1a += bfdec(hp1p[base + t]);
    s2a += bfdec(hp2p[base + t]);
    if (t < D_ - 64) {
      s1b += bfdec(hp1p[base + 64 + t]);
      s2b += bfdec(hp2p[base + 64 + t]);
    }
  }
  const float a0 = fmaxf(s1a, 0.f), b0 = fmaxf(s2a, 0.f);
  const float a1v = fmaxf(s1b, 0.f), b1v = fmaxf(s2b, 0.f);
  float* xr = x + (size_t)r * D_;
  const float x0 = xr[t];
  float d1 = x0 * g1[t], d2 = a0 * g2w[t], d3 = b0 * g2w[t];
  float x1 = 0.f;
  if (t < D_ - 64) {
    x1 = xr[64 + t];
    d1 += x1 * g1[64 + t]; d2 += a1v * g2w[64 + t]; d3 += b1v * g2w[64 + t];
  }
#pragma unroll
  for (int off = 1; off < 64; off <<= 1) {
    d1 += __shfl_xor(d1, off);
    d2 += __shfl_xor(d2, off);
    d3 += __shfl_xor(d3, off);
  }
  const float bb = g2b[0];
  const float c1 = 1.f / (1.f + __expf(-(d1 + d2 + bb)));
  const float c2 = 1.f / (1.f + __expf(-(d1 + d3 + bb)));
  xr[t] = (c1 * x0 + (1.f - c1) * a0) - (c2 * x0 + (1.f - c2) * b0);
  if (t < D_ - 64)
    xr[64 + t] = (c1 * x1 + (1.f - c1) * a1v) - (c2 * x1 + (1.f - c2) * b1v);
}

// ------------------------------------------- masked sum pool over N
__global__ __launch_bounds__(256) void pool_kernel(
    const float* __restrict__ x, const float* __restrict__ V, float* __restrict__ pooled)
{
  const int d = blockIdx.x, b = blockIdx.y, t = threadIdx.x;
  const float* xb = x + (size_t)b * N_ * D_;
  const float* Vb = V + (size_t)b * N_;
  float s = 0.f;
  for (int n = t; n < N_; n += 256) s += xb[(size_t)n * D_ + d] * Vb[n];
#pragma unroll
  for (int off = 32; off >= 1; off >>= 1) s += __shfl_down(s, off);
  __shared__ float red[4];
  if ((t & 63) == 0) red[t >> 6] = s;
  __syncthreads();
  if (t == 0) pooled[b * D_ + d] = red[0] + red[1] + red[2] + red[3];
}

// ------------------------------------------- MLP head (single block, 1024 thr)
__global__ __launch_bounds__(1024) void fc_kernel(
    const float* __restrict__ pooled,
    const float* __restrict__ w0, const float* __restrict__ b0,
    const float* __restrict__ w1, const float* __restrict__ b1,
    const float* __restrict__ w2, const float* __restrict__ b2,
    const float* __restrict__ w3, const float* __restrict__ b3,
    float* __restrict__ out)
{
  __shared__ float pin[B_][D_];
  __shared__ float bufA[B_][DFC_], bufB[B_][DFC_];
  const int t = threadIdx.x;
  if (t < B_ * D_) pin[t / D_][t % D_] = pooled[t];
  __syncthreads();
  const int r = t >> 7, o = t & 127;
  {
    float a = b0[o];
    const float2* wr = (const float2*)(w0 + o * D_);
#pragma unroll
    for (int m2 = 0; m2 < D_ / 2; m2++) {
      const float2 wv = wr[m2];
      a += pin[r][m2 * 2] * wv.x + pin[r][m2 * 2 + 1] * wv.y;
    }
    bufA[r][o] = fmaxf(a, 0.f);
  }
  __syncthreads();
  {
    float a = b1[o];
    const float4* wr = (const float4*)(w1 + o * DFC_);
    const float4* br = (const float4*)&bufA[r][0];
#pragma unroll
    for (int m4 = 0; m4 < DFC_ / 4; m4++) a += dot4(br[m4], wr[m4]);
    bufB[r][o] = fmaxf(a, 0.f);
  }
  __syncthreads();
  {
    float a = b2[o];
    const float4* wr = (const float4*)(w2 + o * DFC_);
    const float4* br = (const float4*)&bufB[r][0];
#pragma unroll
    for (int m4 = 0; m4 < DFC_ / 4; m4++) a += dot4(br[m4], wr[m4]);
    bufA[r][o] = fmaxf(a, 0.f);
  }
  __syncthreads();
  if (t < 64) {
    const int rr = t >> 3, l8 = t & 7;
    const float4* wr = (const float4*)(w3 + l8 * 16);
    const float4* br = (const float4*)&bufA[rr][l8 * 16];
    float a = 0.f;
#pragma unroll
    for (int m4 = 0; m4 < 4; m4++) a += dot4(br[m4], wr[m4]);
    a += __shfl_xor(a, 1); a += __shfl_xor(a, 2); a += __shfl_xor(a, 4);
    if (l8 == 0) out[rr] = 1.f / (1.f + __expf(-(a + b3[0])));
  }
}

// ----------------------------------------------------------------------
extern "C" void kernel_launch(void* const* d_in, const int* in_sizes, int n_in,
                              void* d_out, int out_size, void* d_ws, size_t ws_size,
                              hipStream_t stream)
{
  const float* H     = (const float*)d_in[0];
  const float* A1    = (const float*)d_in[1];
  const float* A2    = (const float*)d_in[2];
  const float* V     = (const float*)d_in[3];
  const float* few   = (const float*)d_in[4];
  const float* mup   = (const float*)d_in[5];
  const float* devp  = (const float*)d_in[6];
  const float* gW    = (const float*)d_in[7];
  const float* gA    = (const float*)d_in[8];
  const float* g1    = (const float*)d_in[9];
  const float* g2w   = (const float*)d_in[10];
  const float* g2b   = (const float*)d_in[11];
  const float* w0 = (const float*)d_in[12]; const float* b0 = (const float*)d_in[13];
  const float* w1 = (const float*)d_in[14]; const float* b1 = (const float*)d_in[15];
  const float* w2 = (const float*)d_in[16]; const float* b2 = (const float*)d_in[17];
  const float* w3 = (const float*)d_in[18]; const float* b3 = (const float*)d_in[19];
  float* outp = (float*)d_out;

  float* ws = (float*)d_ws;
  // fixed layout (float offsets)
  float*   x     = ws;                         // 573440
  short*   hb16  = (short*)(ws + 573440);      // B*N*96 bf16
  short*   hAb16 = (short*)(ws + 966656);
  short*   hT16  = (short*)(ws + 1359872);     // B*96*N bf16
  short*   Wb16  = (short*)(ws + 1753088);     // 4*80*96 bf16
  short*   Atb16 = (short*)(ws + 1768448);
  float*   M1p   = ws + 1783808;               // 8*B*N each
  float*   S1p   = ws + 1849344;
  float*   M2p   = ws + 1914880;
  float*   S2p   = ws + 1980416;
  float*   pooled= ws + 2045952;               // 576 -> 2046528
  ushortT* adjp  = (ushortT*)(ws + 2046528);   // B*N*N u16 -> 6240832
  unsigned* m1b  = (unsigned*)(ws + 6240832);  // B*N*32 u32 -> 6502976
  unsigned* m2b  = (unsigned*)(ws + 6502976);  // -> 6765120

  auto need = [](int jc) -> size_t {
    return (size_t)(6765120u + (size_t)jc * 655360u) * 4u;
  };
  int JC;
  if      (need(4) <= ws_size) JC = 4;
  else if (need(2) <= ws_size) JC = 2;
  else if (need(1) <= ws_size) JC = 1;
  else return;
  ushortT* hp1p = (ushortT*)(ws + 6765120u);
  ushortT* hp2p = hp1p + (size_t)JC * 655360u;
  const int njt = (N_ / 32) / JC;
  const int ROWS = B_ * N_;

  prep_wb<<<16, 256, 0, stream>>>(gW, gA, Wb16, Atb16, hT16);
  featem_kernel<<<ROWS, 128, 0, stream>>>(H, few, x);
  prep_adj_mask<<<ROWS, 256, 0, stream>>>(A1, A2, mup, devp, adjp, m1b, m2b);

  for (int k = 0; k < 4; k++) {
    const short* Wk  = Wb16  + (size_t)k * 80 * 96;
    const short* Atk = Atb16 + (size_t)k * 80 * 96;
    if (k == 0)
      gatmm_mfma<0><<<ROWS / 32, 128, 0, stream>>>(
          x, nullptr, nullptr, 0, nullptr, nullptr, nullptr,
          Wk, Atk, hb16, hAb16, hT16);
    else
      gatmm_mfma<1><<<ROWS / 32, 128, 0, stream>>>(
          x, hp1p, hp2p, JC,
          g1 + (size_t)(k - 1) * D_, g2w + (size_t)(k - 1) * D_, g2b + (k - 1),
          Wk, Atk, hb16, hAb16, hT16);
    pass1_mfma<<<dim3(32, 8, B_), 256, 0, stream>>>(m1b, m2b, hb16, hAb16,
                                                    M1p, S1p, M2p, S2p);
    pass2_mfma<<<dim3(32, JC, B_), 256, 0, stream>>>(adjp, hb16, hAb16, hT16,
        M1p, S1p, M2p, S2p, hp1p, hp2p, njt);
  }
  combine_kernel<<<ROWS / 4, 256, 0, stream>>>(x, hp1p, hp2p, JC,
                                               g1 + 3 * D_, g2w + 3 * D_, g2b + 3);
  pool_kernel<<<dim3(D_, B_), 256, 0, stream>>>(x, V, pooled);
  fc_kernel<<<1, 1024, 0, stream>>>(pooled, w0, b0, w1, b1, w2, b2, w3, b3, outp);
}

// Round 7
// 337.891 us; speedup vs baseline: 1.2083x; 1.0548x over previous
//
#include <hip/hip_runtime.h>

#define B_   8
#define N_   1024
#define F0_  56
#define D_   70
#define DK_  96      // bf16 K-padded row stride (3 x 32)
#define DFC_ 128
#define NEG_BIG (-9e15f)

typedef __attribute__((ext_vector_type(8))) short bf16x8;
typedef __attribute__((ext_vector_type(4))) float f32x4;
typedef unsigned short ushortT;
typedef _Float16 f16T;

__device__ __forceinline__ short f2bf(float x) {
  unsigned u = __builtin_bit_cast(unsigned, x);
  u += 0x7FFF + ((u >> 16) & 1);
  return (short)(u >> 16);
}
__device__ __forceinline__ float bfdec(unsigned u16bits) {
  unsigned v = u16bits << 16;
  return __builtin_bit_cast(float, v);
}
__device__ __forceinline__ ushortT f2h(float x) {
  f16T h = (f16T)x; return __builtin_bit_cast(ushortT, h);
}
__device__ __forceinline__ float h2f(ushortT u) {
  return (float)__builtin_bit_cast(f16T, u);
}
__device__ __forceinline__ float dot4(float4 a, float4 b) {
  return a.x * b.x + a.y * b.y + a.z * b.z + a.w * b.w;
}

// ------------------------------------ weights -> bf16 padded; hT pad-zero
__global__ __launch_bounds__(256) void prep_wb(
    const float* __restrict__ gW, const float* __restrict__ gA,
    short* __restrict__ Wb16, short* __restrict__ Atb16, short* __restrict__ hT)
{
  const int blk = blockIdx.x;
  if (blk < 8) {
    const int k = blk & 3;
    const bool isW = blk < 4;
    short* dst = (isW ? Wb16 : Atb16) + (size_t)k * 80 * 96;
    const float* src = (isW ? gW : gA) + (size_t)k * D_ * D_;
    for (int i = threadIdx.x; i < 80 * 96; i += 256) {
      const int d = i / 96, m = i - (i / 96) * 96;
      float v = 0.f;
      if (d < D_ && m < D_) v = isW ? src[d * D_ + m] : src[m * D_ + d];
      dst[i] = f2bf(v);
    }
  } else {
    const int b = blk - 8;
    uint2* p = (uint2*)(hT + ((size_t)(b * 96 + 80)) * N_);
    for (int i = threadIdx.x; i < 16 * N_ / 4; i += 256) p[i] = (uint2){0, 0};
  }
}

// ---------------------------------------------------------------- featem
__global__ __launch_bounds__(128) void featem_kernel(
    const float* __restrict__ H, const float* __restrict__ W, float* __restrict__ x)
{
  const int r = blockIdx.x, t = threadIdx.x;
  __shared__ float row[F0_];
  if (t < F0_) row[t] = H[(size_t)r * F0_ + t];
  __syncthreads();
  if (t < D_) {
    float a = 0.f;
#pragma unroll 8
    for (int m = 0; m < F0_; m++) a += row[m] * W[t * F0_ + m];
    x[(size_t)r * D_ + t] = a;
  }
}

// -------------------- adjacency: tiled pack [b][jt][it][32j][32i] + bitmasks
__global__ __launch_bounds__(256) void prep_adj_tiled(
    const float* __restrict__ A1, const float* __restrict__ A2,
    const float* __restrict__ mup, const float* __restrict__ devp,
    ushortT* __restrict__ adj_t, unsigned* __restrict__ m1b, unsigned* __restrict__ m2b)
{
  const int it = blockIdx.x, b = blockIdx.y;
  const int i0 = it * 32;
  const int tid = threadIdx.x;
  const int irel = tid >> 3, jq = tid & 7;
  const float mu = mup[0], idev = 1.0f / devp[0];
  __shared__ ushortT tl[32][36];

  for (int jt = 0; jt < 32; jt++) {
    const int j0 = jt * 32;
    const size_t base = ((size_t)b * N_ + i0 + irel) * N_ + j0 + jq * 4;
    const float4 a1 = *(const float4*)(A1 + base);
    const float4 a2 = *(const float4*)(A2 + base);
    const float a1v[4] = {a1.x, a1.y, a1.z, a1.w};
    const float a2v[4] = {a2.x, a2.y, a2.z, a2.w};
    ushortT o[4];
#pragma unroll
    for (int k = 0; k < 4; k++) {
      const float rbf = (a2v[k] <= 10.f) ? __expf(-(a2v[k] - mu) * (a2v[k] - mu) * idev) : 0.f;
      const float adj1 = rbf + a1v[k];
      ushortT u = ((ushortT)f2bf(adj1)) & 0xFFFE;
      if (a1v[k] > 0.f) u |= 1;
      o[k] = u;
    }
    *(uint2*)&tl[irel][jq * 4] = *(uint2*)o;
    __syncthreads();
    // transpose write: adj_t tile row = j, col = i (i fastest)
    {
      const int jrel = tid >> 3, iq = tid & 7;
      ushortT w[4];
#pragma unroll
      for (int k = 0; k < 4; k++) w[k] = tl[iq * 4 + k][jrel];
      ushortT* dst = adj_t + (((size_t)(b * 32 + jt) * 32 + it) * 1024) + jrel * 32 + iq * 4;
      *(uint2*)dst = *(uint2*)w;
    }
    if (tid < 32) {
      unsigned w1 = 0, w2 = 0;
#pragma unroll
      for (int j = 0; j < 32; j++) {
        const unsigned u = tl[tid][j];
        w1 |= ((u & 0xFFFEu) ? 1u : 0u) << j;
        w2 |= (u & 1u) << j;
      }
      m1b[((size_t)b * N_ + i0 + tid) * 32 + jt] = w1;
      m2b[((size_t)b * N_ + i0 + tid) * 32 + jt] = w2;
    }
    __syncthreads();
  }
}

// ---------------- fused [combine] + h + hA + hT via MFMA (32 rows, 2 waves)
template<int MODE>
__global__ __launch_bounds__(128) void gatmm_mfma(
    float* __restrict__ x,
    const ushortT* __restrict__ hp1p, const ushortT* __restrict__ hp2p, int JC,
    const float* __restrict__ g1, const float* __restrict__ g2w, const float* __restrict__ g2b,
    const short* __restrict__ Wb, const short* __restrict__ Atb,
    short* __restrict__ hb16, short* __restrict__ hAb16, short* __restrict__ hT)
{
  const int tid = threadIdx.x;
  const int w = tid >> 6, lane = tid & 63;
  const int lr = lane & 15, kg = lane >> 4;
  const int r0 = blockIdx.x * 32;
  const int b = r0 >> 10, n0 = r0 & (N_ - 1);

  __shared__ __align__(16) short sxb[32][104];
  __shared__ __align__(16) short shl[32][104];

  for (int i = tid; i < 320; i += 128) {
    const int r = i / 10, c = i - (i / 10) * 10;
    *(uint2*)&sxb[r][64 + c * 4] = (uint2){0, 0};
    *(uint2*)&shl[r][64 + c * 4] = (uint2){0, 0};
  }

  if (MODE == 0) {
    for (int i = tid; i < 32 * D_; i += 128) {
      const int r = i / D_;
      sxb[r][i - r * D_] = f2bf(x[(size_t)r0 * D_ + i]);
    }
  } else {
    const int lt = tid & 15, gg = tid >> 4;
#pragma unroll
    for (int rg = 0; rg < 4; rg++) {
      const int row = gg * 4 + rg;
      const int grow = r0 + row;
      float s1[5], s2[5], xv[5];
#pragma unroll
      for (int q = 0; q < 5; q++) { s1[q] = 0.f; s2[q] = 0.f; xv[q] = 0.f; }
      for (int jc = 0; jc < JC; jc++) {
        const size_t bp = ((size_t)jc * (B_ * N_) + grow) * 80 + lt;
#pragma unroll
        for (int q = 0; q < 5; q++) {
          s1[q] += bfdec(hp1p[bp + 16 * q]);
          s2[q] += bfdec(hp2p[bp + 16 * q]);
        }
      }
      float d1 = 0.f, d2 = 0.f, d3 = 0.f;
#pragma unroll
      for (int q = 0; q < 5; q++) {
        const int d = lt + 16 * q;
        if (d < D_) {
          s1[q] = fmaxf(s1[q], 0.f); s2[q] = fmaxf(s2[q], 0.f);
          xv[q] = x[(size_t)grow * D_ + d];
          d1 += xv[q] * g1[d]; d2 += s1[q] * g2w[d]; d3 += s2[q] * g2w[d];
        }
      }
#pragma unroll
      for (int off = 1; off < 16; off <<= 1) {
        d1 += __shfl_xor(d1, off); d2 += __shfl_xor(d2, off); d3 += __shfl_xor(d3, off);
      }
      const float bb = g2b[0];
      const float c1 = 1.f / (1.f + __expf(-(d1 + d2 + bb)));
      const float c2 = 1.f / (1.f + __expf(-(d1 + d3 + bb)));
#pragma unroll
      for (int q = 0; q < 5; q++) {
        const int d = lt + 16 * q;
        if (d < D_) {
          const float xn = (c1 * xv[q] + (1.f - c1) * s1[q]) - (c2 * xv[q] + (1.f - c2) * s2[q]);
          x[(size_t)grow * D_ + d] = xn;
          sxb[row][d] = f2bf(xn);
        }
      }
    }
  }
  __syncthreads();

  // GEMM1: h = x @ W^T
  bf16x8 af[3];
#pragma unroll
  for (int ks = 0; ks < 3; ks++)
    af[ks] = *(const bf16x8*)&sxb[w * 16 + lr][ks * 32 + kg * 8];
  f32x4 acc[5];
#pragma unroll
  for (int nt = 0; nt < 5; nt++) acc[nt] = (f32x4){0.f, 0.f, 0.f, 0.f};
#pragma unroll
  for (int nt = 0; nt < 5; nt++) {
#pragma unroll
    for (int ks = 0; ks < 3; ks++) {
      bf16x8 bw = *(const bf16x8*)(Wb + (size_t)(nt * 16 + lr) * 96 + ks * 32 + kg * 8);
      acc[nt] = __builtin_amdgcn_mfma_f32_16x16x32_bf16(af[ks], bw, acc[nt], 0, 0, 0);
    }
  }
#pragma unroll
  for (int nt = 0; nt < 5; nt++)
#pragma unroll
    for (int r = 0; r < 4; r++)
      shl[w * 16 + kg * 4 + r][nt * 16 + lr] = f2bf(acc[nt][r]);
  __syncthreads();

  for (int i = tid; i < 32 * 12; i += 128) {
    const int r = i / 12, seg = i - (i / 12) * 12;
    *(bf16x8*)(hb16 + (size_t)(r0 + r) * DK_ + seg * 8) = *(const bf16x8*)&shl[r][seg * 8];
  }
  for (int i = tid; i < 80 * 4; i += 128) {
    const int d = i >> 2, ng = i & 3;
    short tmp[8];
#pragma unroll
    for (int k = 0; k < 8; k++) tmp[k] = shl[ng * 8 + k][d];
    *(bf16x8*)(hT + ((size_t)(b * 96 + d)) * N_ + n0 + ng * 8) = *(bf16x8*)tmp;
  }

  // GEMM2: hA = h @ A
  bf16x8 ah[3];
#pragma unroll
  for (int ks = 0; ks < 3; ks++)
    ah[ks] = *(const bf16x8*)&shl[w * 16 + lr][ks * 32 + kg * 8];
  f32x4 acc2[5];
#pragma unroll
  for (int nt = 0; nt < 5; nt++) acc2[nt] = (f32x4){0.f, 0.f, 0.f, 0.f};
#pragma unroll
  for (int nt = 0; nt < 5; nt++) {
#pragma unroll
    for (int ks = 0; ks < 3; ks++) {
      bf16x8 bw = *(const bf16x8*)(Atb + (size_t)(nt * 16 + lr) * 96 + ks * 32 + kg * 8);
      acc2[nt] = __builtin_amdgcn_mfma_f32_16x16x32_bf16(ah[ks], bw, acc2[nt], 0, 0, 0);
    }
  }
#pragma unroll
  for (int nt = 0; nt < 5; nt++)
#pragma unroll
    for (int r = 0; r < 4; r++)
      sxb[w * 16 + kg * 4 + r][nt * 16 + lr] = f2bf(acc2[nt][r]);
  __syncthreads();
  for (int i = tid; i < 32 * 12; i += 128) {
    const int r = i / 12, seg = i - (i / 12) * 12;
    *(bf16x8*)(hAb16 + (size_t)(r0 + r) * DK_ + seg * 8) = *(const bf16x8*)&sxb[r][seg * 8];
  }
}

// ---------------- passE: E tiles (stored fp16, tiled) + masked softmax stats
__global__ __launch_bounds__(256) void passE_mfma(
    const unsigned* __restrict__ m1b, const unsigned* __restrict__ m2b,
    const short* __restrict__ hb16, const short* __restrict__ hAb16,
    ushortT* __restrict__ Et,
    float* __restrict__ M1p, float* __restrict__ S1p,
    float* __restrict__ M2p, float* __restrict__ S2p)
{
  const int jt = blockIdx.x, ic = blockIdx.y, b = blockIdx.z;
  const int tid = threadIdx.x, w = tid >> 6, lane = tid & 63;
  const int lr = lane & 15, kg = lane >> 4;
  const int ih = w >> 1, jh = w & 1;
  const int j0 = jt * 32;
  const short* hb  = hb16  + (size_t)b * N_ * DK_;
  const short* hAb = hAb16 + (size_t)b * N_ * DK_;

  bf16x8 b_h[3], b_hA[3];
  {
    const short* p = hb  + (size_t)(j0 + jh * 16 + lr) * DK_ + kg * 8;
    const short* q = hAb + (size_t)(j0 + jh * 16 + lr) * DK_ + kg * 8;
#pragma unroll
    for (int ks = 0; ks < 3; ks++) {
      b_h[ks]  = *(const bf16x8*)(p + ks * 32);
      b_hA[ks] = *(const bf16x8*)(q + ks * 32);
    }
  }
  const int bitp = jh * 16 + lr;
  const int i0base = ic * 128;
  float Ev[16];
  unsigned g1m = 0, g2m = 0;

#pragma unroll
  for (int iter = 0; iter < 4; iter++) {
    const int i0 = i0base + iter * 32 + ih * 16;
    const short* pa = hAb + (size_t)(i0 + lr) * DK_ + kg * 8;
    const short* ph = hb  + (size_t)(i0 + lr) * DK_ + kg * 8;
    bf16x8 a_hA[3], a_h[3];
#pragma unroll
    for (int ks = 0; ks < 3; ks++) {
      a_hA[ks] = *(const bf16x8*)(pa + ks * 32);
      a_h[ks]  = *(const bf16x8*)(ph + ks * 32);
    }
    const unsigned* W1p = m1b + ((size_t)b * N_ + i0 + kg * 4) * 32 + jt;
    const unsigned* W2p = m2b + ((size_t)b * N_ + i0 + kg * 4) * 32 + jt;
    unsigned mw1[4], mw2[4];
#pragma unroll
    for (int r = 0; r < 4; r++) { mw1[r] = W1p[(size_t)r * 32]; mw2[r] = W2p[(size_t)r * 32]; }
    f32x4 E = {0.f, 0.f, 0.f, 0.f};
#pragma unroll
    for (int ks = 0; ks < 3; ks++)
      E = __builtin_amdgcn_mfma_f32_16x16x32_bf16(a_hA[ks], b_h[ks], E, 0, 0, 0);
#pragma unroll
    for (int ks = 0; ks < 3; ks++)
      E = __builtin_amdgcn_mfma_f32_16x16x32_bf16(a_h[ks], b_hA[ks], E, 0, 0, 0);
    // round to fp16, store tiled [b][jt][itg][jrel][irel]; stats use ROUNDED values
    ushortT ev16[4];
#pragma unroll
    for (int r = 0; r < 4; r++) ev16[r] = f2h(E[r]);
    {
      const int itg = ic * 4 + iter;
      const unsigned lo = (unsigned)ev16[0] | ((unsigned)ev16[1] << 16);
      const unsigned hi = (unsigned)ev16[2] | ((unsigned)ev16[3] << 16);
      ushortT* dst = Et + ((size_t)(b * 32 + jt) * 32 + itg) * 1024 +
                     (jh * 16 + lr) * 32 + (ih * 16 + kg * 4);
      *(uint2*)dst = (uint2){lo, hi};
    }
#pragma unroll
    for (int r = 0; r < 4; r++) {
      Ev[iter * 4 + r] = h2f(ev16[r]);
      g1m |= ((mw1[r] >> bitp) & 1u) << (iter * 4 + r);
      g2m |= ((mw2[r] >> bitp) & 1u) << (iter * 4 + r);
    }
  }
  float M1r = -3.0e38f, M2r = -3.0e38f;
#pragma unroll
  for (int k = 0; k < 16; k++) {
    M1r = ((g1m >> k) & 1u) ? fmaxf(M1r, Ev[k]) : M1r;
    M2r = ((g2m >> k) & 1u) ? fmaxf(M2r, Ev[k]) : M2r;
  }
  float S1r = 0.f, S2r = 0.f;
#pragma unroll
  for (int k = 0; k < 16; k++) {
    S1r += ((g1m >> k) & 1u) ? __expf(Ev[k] - M1r) : 0.f;
    S2r += ((g2m >> k) & 1u) ? __expf(Ev[k] - M2r) : 0.f;
  }
#pragma unroll
  for (int off = 16; off <= 32; off <<= 1) {
    float Mo = __shfl_xor(M1r, off), So = __shfl_xor(S1r, off);
    float nM = fmaxf(M1r, Mo);
    S1r = S1r * __expf(M1r - nM) + So * __expf(Mo - nM); M1r = nM;
    Mo = __shfl_xor(M2r, off); So = __shfl_xor(S2r, off);
    nM = fmaxf(M2r, Mo);
    S2r = S2r * __expf(M2r - nM) + So * __expf(Mo - nM); M2r = nM;
  }
  __shared__ float sM[2][4][16], sS[2][4][16];
  if (lane < 16) {
    sM[0][w][lr] = M1r; sS[0][w][lr] = S1r;
    sM[1][w][lr] = M2r; sS[1][w][lr] = S2r;
  }
  __syncthreads();
  if (tid < 32) {
    const int jhh = tid >> 4, l2 = tid & 15;
    const size_t o = ((size_t)b * 8 + ic) * N_ + j0 + jhh * 16 + l2;
    {
      float Ma = sM[0][jhh][l2], Sa = sS[0][jhh][l2];
      float Mb = sM[0][2 + jhh][l2], Sb = sS[0][2 + jhh][l2];
      float nM = fmaxf(Ma, Mb);
      M1p[o] = nM; S1p[o] = Sa * __expf(Ma - nM) + Sb * __expf(Mb - nM);
    }
    {
      float Ma = sM[1][jhh][l2], Sa = sS[1][jhh][l2];
      float Mb = sM[1][2 + jhh][l2], Sb = sS[1][2 + jhh][l2];
      float nM = fmaxf(Ma, Mb);
      M2p[o] = nM; S2p[o] = Sa * __expf(Ma - nM) + Sb * __expf(Mb - nM);
    }
  }
}

// --------------------- passPV: read E + adj tiles, weights, PV MFMA
__global__ __launch_bounds__(256) void passPV_mfma(
    const ushortT* __restrict__ adj_t, const ushortT* __restrict__ Et,
    const short* __restrict__ hT16,
    const float* __restrict__ M1p, const float* __restrict__ S1p,
    const float* __restrict__ M2p, const float* __restrict__ S2p,
    ushortT* __restrict__ hp1p, ushortT* __restrict__ hp2p, int njt)
{
  const int it = blockIdx.x, jc = blockIdx.y, b = blockIdx.z;
  const int tid = threadIdx.x, w = tid >> 6, lane = tid & 63;
  const int lr = lane & 15, kg = lane >> 4;
  const int ih = w >> 1, jh = w & 1;
  const int dbase = (w & 1) * 3;
  const int jbase = jc * njt * 32;

  __shared__ float sMS[4][256];
  for (int idx = tid; idx < njt * 32; idx += 256) {
    const int col = jbase + idx;
    float M = -3.0e38f, S = 0.f;
#pragma unroll
    for (int q = 0; q < 8; q++) {
      const float m = M1p[((size_t)b * 8 + q) * N_ + col];
      const float s = S1p[((size_t)b * 8 + q) * N_ + col];
      const float nM = fmaxf(M, m);
      S = S * __expf(M - nM) + s * __expf(m - nM); M = nM;
    }
    sMS[0][idx] = M; sMS[1][idx] = 1.0f / S;
    M = -3.0e38f; S = 0.f;
#pragma unroll
    for (int q = 0; q < 8; q++) {
      const float m = M2p[((size_t)b * 8 + q) * N_ + col];
      const float s = S2p[((size_t)b * 8 + q) * N_ + col];
      const float nM = fmaxf(M, m);
      S = S * __expf(M - nM) + s * __expf(m - nM); M = nM;
    }
    sMS[2][idx] = M; sMS[3][idx] = 1.0f / S;
  }

  const short* hTb = hT16 + (size_t)b * DK_ * N_;
  f32x4 acc[2][3];
#pragma unroll
  for (int m = 0; m < 2; m++)
#pragma unroll
    for (int q = 0; q < 3; q++) acc[m][q] = (f32x4){0.f, 0.f, 0.f, 0.f};

  __shared__ short wlds[2][2][32][40];
  __syncthreads();

  for (int t = 0; t < njt; ++t) {
    const int j0 = jbase + t * 32;
    const int jtg = (jbase >> 5) + t;
    const int par = t & 1;
    const size_t tb = ((size_t)(b * 32 + jtg) * 32 + it) * 1024 +
                      (jh * 16 + lr) * 32 + (ih * 16 + kg * 4);
    const uint2 eraw = *(const uint2*)(Et + tb);
    const uint2 araw = *(const uint2*)(adj_t + tb);
    bf16x8 bt[3];
#pragma unroll
    for (int q = 0; q < 3; q++)
      bt[q] = *(const bf16x8*)(hTb + (size_t)((dbase + q) * 16 + lr) * N_ + j0 + kg * 8);

    const ushortT ev[4] = {(ushortT)(eraw.x & 0xFFFF), (ushortT)(eraw.x >> 16),
                           (ushortT)(eraw.y & 0xFFFF), (ushortT)(eraw.y >> 16)};
    const ushortT uu[4] = {(ushortT)(araw.x & 0xFFFF), (ushortT)(araw.x >> 16),
                           (ushortT)(araw.y & 0xFFFF), (ushortT)(araw.y >> 16)};
    const int jrel = t * 32 + jh * 16 + lr;
    const float M1j = sMS[0][jrel], is1 = sMS[1][jrel];
    const float M2j = sMS[2][jrel], is2 = sMS[3][jrel];

    short w1v[4], w2v[4];
#pragma unroll
    for (int r = 0; r < 4; r++) {
      const float e = h2f(ev[r]);
      const float adj1v = bfdec(uu[r] & 0xFFFEu);
      const bool gon1 = (uu[r] & 0xFFFEu) != 0, gon2 = (uu[r] & 1u) != 0;
      w1v[r] = f2bf(gon1 ? __expf(e - M1j) * adj1v * is1 : 0.f);
      w2v[r] = f2bf(gon2 ? __expf(e - M2j) * is2 : 0.f);
    }
#pragma unroll
    for (int r = 0; r < 4; r++) {
      wlds[par][0][ih * 16 + kg * 4 + r][jh * 16 + lr] = w1v[r];
      wlds[par][1][ih * 16 + kg * 4 + r][jh * 16 + lr] = w2v[r];
    }
    __syncthreads();
#pragma unroll
    for (int m = 0; m < 2; m++) {
      bf16x8 af = *(const bf16x8*)&wlds[par][m][ih * 16 + lr][kg * 8];
#pragma unroll
      for (int q = 0; q < 3; q++)
        acc[m][q] = __builtin_amdgcn_mfma_f32_16x16x32_bf16(af, bt[q], acc[m][q], 0, 0, 0);
    }
  }
  const int i0 = it * 32;
#pragma unroll
  for (int m = 0; m < 2; m++) {
#pragma unroll
    for (int q = 0; q < 3; q++) {
      const int dt = dbase + q;
      if (dt < 5) {
        ushortT* dst = (m ? hp2p : hp1p) +
            (((size_t)jc * B_ + b) * N_ + i0 + ih * 16 + kg * 4) * 80 + dt * 16 + lr;
#pragma unroll
        for (int r = 0; r < 4; r++) dst[(size_t)r * 80] = (ushortT)f2bf(acc[m][q][r]);
      }
    }
  }
}

// ---------------------- final-layer combine (in-place x)
__global__ __launch_bounds__(256) void combine_kernel(
    float* __restrict__ x,
    const ushortT* __restrict__ hp1p, const ushortT* __restrict__ hp2p, int JC,
    const float* __restrict__ g1, const float* __restrict__ g2w,
    const float* __restrict__ g2b)
{
  const int r = blockIdx.x * 4 + (threadIdx.x >> 6);
  const int t = threadIdx.x & 63;
  float s1a = 0.f, s2a = 0.f, s1b = 0.f, s2b = 0.f;
  for (int q = 0; q < JC; q++) {
    const size_t base = ((size_t)q * (B_ * N_) + r) * 80;
    s1a += bfdec(hp1p[base + t]);
    s2a += bfdec(hp2p[base + t]);
    if (t < D_ - 64) {
      s1b += bfdec(hp1p[base + 64 + t]);
      s2b += bfdec(hp2p[base + 64 + t]);
    }
  }
  const float a0 = fmaxf(s1a, 0.f), b0 = fmaxf(s2a, 0.f);
  const float a1v = fmaxf(s1b, 0.f), b1v = fmaxf(s2b, 0.f);
  float* xr = x + (size_t)r * D_;
  const float x0 = xr[t];
  float d1 = x0 * g1[t], d2 = a0 * g2w[t], d3 = b0 * g2w[t];
  float x1 = 0.f;
  if (t < D_ - 64) {
    x1 = xr[64 + t];
    d1 += x1 * g1[64 + t]; d2 += a1v * g2w[64 + t]; d3 += b1v * g2w[64 + t];
  }
#pragma unroll
  for (int off = 1; off < 64; off <<= 1) {
    d1 += __shfl_xor(d1, off);
    d2 += __shfl_xor(d2, off);
    d3 += __shfl_xor(d3, off);
  }
  const float bb = g2b[0];
  const float c1 = 1.f / (1.f + __expf(-(d1 + d2 + bb)));
  const float c2 = 1.f / (1.f + __expf(-(d1 + d3 + bb)));
  xr[t] = (c1 * x0 + (1.f - c1) * a0) - (c2 * x0 + (1.f - c2) * b0);
  if (t < D_ - 64)
    xr[64 + t] = (c1 * x1 + (1.f - c1) * a1v) - (c2 * x1 + (1.f - c2) * b1v);
}

// ------------------------------------------- masked sum pool over N
__global__ __launch_bounds__(256) void pool_kernel(
    const float* __restrict__ x, const float* __restrict__ V, float* __restrict__ pooled)
{
  const int d = blockIdx.x, b = blockIdx.y, t = threadIdx.x;
  const float* xb = x + (size_t)b * N_ * D_;
  const float* Vb = V + (size_t)b * N_;
  float s = 0.f;
  for (int n = t; n < N_; n += 256) s += xb[(size_t)n * D_ + d] * Vb[n];
#pragma unroll
  for (int off = 32; off >= 1; off >>= 1) s += __shfl_down(s, off);
  __shared__ float red[4];
  if ((t & 63) == 0) red[t >> 6] = s;
  __syncthreads();
  if (t == 0) pooled[b * D_ + d] = red[0] + red[1] + red[2] + red[3];
}

// ------------------------------------------- MLP head (single block, 1024 thr)
__global__ __launch_bounds__(1024) void fc_kernel(
    const float* __restrict__ pooled,
    const float* __restrict__ w0, const float* __restrict__ b0,
    const float* __restrict__ w1, const float* __restrict__ b1,
    const float* __restrict__ w2, const float* __restrict__ b2,
    const float* __restrict__ w3, const float* __restrict__ b3,
    float* __restrict__ out)
{
  __shared__ float pin[B_][D_];
  __shared__ float bufA[B_][DFC_], bufB[B_][DFC_];
  const int t = threadIdx.x;
  if (t < B_ * D_) pin[t / D_][t % D_] = pooled[t];
  __syncthreads();
  const int r = t >> 7, o = t & 127;
  {
    float a = b0[o];
    const float2* wr = (const float2*)(w0 + o * D_);
#pragma unroll
    for (int m2 = 0; m2 < D_ / 2; m2++) {
      const float2 wv = wr[m2];
      a += pin[r][m2 * 2] * wv.x + pin[r][m2 * 2 + 1] * wv.y;
    }
    bufA[r][o] = fmaxf(a, 0.f);
  }
  __syncthreads();
  {
    float a = b1[o];
    const float4* wr = (const float4*)(w1 + o * DFC_);
    const float4* br = (const float4*)&bufA[r][0];
#pragma unroll
    for (int m4 = 0; m4 < DFC_ / 4; m4++) a += dot4(br[m4], wr[m4]);
    bufB[r][o] = fmaxf(a, 0.f);
  }
  __syncthreads();
  {
    float a = b2[o];
    const float4* wr = (const float4*)(w2 + o * DFC_);
    const float4* br = (const float4*)&bufB[r][0];
#pragma unroll
    for (int m4 = 0; m4 < DFC_ / 4; m4++) a += dot4(br[m4], wr[m4]);
    bufA[r][o] = fmaxf(a, 0.f);
  }
  __syncthreads();
  if (t < 64) {
    const int rr = t >> 3, l8 = t & 7;
    const float4* wr = (const float4*)(w3 + l8 * 16);
    const float4* br = (const float4*)&bufA[rr][l8 * 16];
    float a = 0.f;
#pragma unroll
    for (int m4 = 0; m4 < 4; m4++) a += dot4(br[m4], wr[m4]);
    a += __shfl_xor(a, 1); a += __shfl_xor(a, 2); a += __shfl_xor(a, 4);
    if (l8 == 0) out[rr] = 1.f / (1.f + __expf(-(a + b3[0])));
  }
}

// ----------------------------------------------------------------------
extern "C" void kernel_launch(void* const* d_in, const int* in_sizes, int n_in,
                              void* d_out, int out_size, void* d_ws, size_t ws_size,
                              hipStream_t stream)
{
  const float* H     = (const float*)d_in[0];
  const float* A1    = (const float*)d_in[1];
  const float* A2    = (const float*)d_in[2];
  const float* V     = (const float*)d_in[3];
  const float* few   = (const float*)d_in[4];
  const float* mup   = (const float*)d_in[5];
  const float* devp  = (const float*)d_in[6];
  const float* gW    = (const float*)d_in[7];
  const float* gA    = (const float*)d_in[8];
  const float* g1    = (const float*)d_in[9];
  const float* g2w   = (const float*)d_in[10];
  const float* g2b   = (const float*)d_in[11];
  const float* w0 = (const float*)d_in[12]; const float* b0 = (const float*)d_in[13];
  const float* w1 = (const float*)d_in[14]; const float* b1 = (const float*)d_in[15];
  const float* w2 = (const float*)d_in[16]; const float* b2 = (const float*)d_in[17];
  const float* w3 = (const float*)d_in[18]; const float* b3 = (const float*)d_in[19];
  float* outp = (float*)d_out;

  float* ws = (float*)d_ws;
  // fixed layout (float offsets)
  float*   x     = ws;                         // 573440
  short*   hb16  = (short*)(ws + 573440);
  short*   hAb16 = (short*)(ws + 966656);
  short*   hT16  = (short*)(ws + 1359872);
  short*   Wb16  = (short*)(ws + 1753088);
  short*   Atb16 = (short*)(ws + 1768448);
  float*   M1p   = ws + 1783808;               // 8*B*N each
  float*   S1p   = ws + 1849344;
  float*   M2p   = ws + 1914880;
  float*   S2p   = ws + 1980416;
  float*   pooled= ws + 2045952;               // -> 2046528
  ushortT* adj_t = (ushortT*)(ws + 2046528);   // 8M u16 -> 6240832
  unsigned* m1b  = (unsigned*)(ws + 6240832);  // -> 6502976
  unsigned* m2b  = (unsigned*)(ws + 6502976);  // -> 6765120
  ushortT* Et    = (ushortT*)(ws + 6765120);   // 8M u16 -> 10959424
  const int JC = 4;
  ushortT* hp1p  = (ushortT*)(ws + 10959424);
  ushortT* hp2p  = hp1p + (size_t)JC * 655360u;
  const size_t need = (size_t)(10959424u + (size_t)JC * 655360u) * 4u;
  if (ws_size < need) return;
  const int njt = (N_ / 32) / JC;
  const int ROWS = B_ * N_;

  prep_wb<<<16, 256, 0, stream>>>(gW, gA, Wb16, Atb16, hT16);
  featem_kernel<<<ROWS, 128, 0, stream>>>(H, few, x);
  prep_adj_tiled<<<dim3(32, B_), 256, 0, stream>>>(A1, A2, mup, devp, adj_t, m1b, m2b);

  for (int k = 0; k < 4; k++) {
    const short* Wk  = Wb16  + (size_t)k * 80 * 96;
    const short* Atk = Atb16 + (size_t)k * 80 * 96;
    if (k == 0)
      gatmm_mfma<0><<<ROWS / 32, 128, 0, stream>>>(
          x, nullptr, nullptr, 0, nullptr, nullptr, nullptr,
          Wk, Atk, hb16, hAb16, hT16);
    else
      gatmm_mfma<1><<<ROWS / 32, 128, 0, stream>>>(
          x, hp1p, hp2p, JC,
          g1 + (size_t)(k - 1) * D_, g2w + (size_t)(k - 1) * D_, g2b + (k - 1),
          Wk, Atk, hb16, hAb16, hT16);
    passE_mfma<<<dim3(32, 8, B_), 256, 0, stream>>>(m1b, m2b, hb16, hAb16, Et,
                                                    M1p, S1p, M2p, S2p);
    passPV_mfma<<<dim3(32, JC, B_), 256, 0, stream>>>(adj_t, Et, hT16,
        M1p, S1p, M2p, S2p, hp1p, hp2p, njt);
  }
  combine_kernel<<<ROWS / 4, 256, 0, stream>>>(x, hp1p, hp2p, JC,
                                               g1 + 3 * D_, g2w + 3 * D_, g2b + 3);
  pool_kernel<<<dim3(D_, B_), 256, 0, stream>>>(x, V, pooled);
  fc_kernel<<<1, 1024, 0, stream>>>(pooled, w0, b0, w1, b1, w2, b2, w3, b3, outp);
}

// Round 8
// 316.968 us; speedup vs baseline: 1.2881x; 1.0660x over previous
//
#include <hip/hip_runtime.h>

#define B_   8
#define N_   1024
#define F0_  56
#define D_   70
#define DK_  96      // bf16 K-padded row stride (3 x 32)
#define DFC_ 128
#define NEG_BIG (-9e15f)

typedef __attribute__((ext_vector_type(8))) short bf16x8;
typedef __attribute__((ext_vector_type(4))) float f32x4;
typedef unsigned short ushortT;
typedef _Float16 f16T;

__device__ __forceinline__ short f2bf(float x) {
  unsigned u = __builtin_bit_cast(unsigned, x);
  u += 0x7FFF + ((u >> 16) & 1);
  return (short)(u >> 16);
}
__device__ __forceinline__ float bfdec(unsigned u16bits) {
  unsigned v = u16bits << 16;
  return __builtin_bit_cast(float, v);
}
__device__ __forceinline__ ushortT f2h(float x) {
  f16T h = (f16T)x; return __builtin_bit_cast(ushortT, h);
}
__device__ __forceinline__ float h2f(ushortT u) {
  return (float)__builtin_bit_cast(f16T, u);
}
__device__ __forceinline__ float dot4(float4 a, float4 b) {
  return a.x * b.x + a.y * b.y + a.z * b.z + a.w * b.w;
}

// ------------------------------------ weights -> bf16 padded; hT pad-zero
__global__ __launch_bounds__(256) void prep_wb(
    const float* __restrict__ gW, const float* __restrict__ gA,
    short* __restrict__ Wb16, short* __restrict__ Atb16, short* __restrict__ hT)
{
  const int blk = blockIdx.x;
  if (blk < 8) {
    const int k = blk & 3;
    const bool isW = blk < 4;
    short* dst = (isW ? Wb16 : Atb16) + (size_t)k * 80 * 96;
    const float* src = (isW ? gW : gA) + (size_t)k * D_ * D_;
    for (int i = threadIdx.x; i < 80 * 96; i += 256) {
      const int d = i / 96, m = i - (i / 96) * 96;
      float v = 0.f;
      if (d < D_ && m < D_) v = isW ? src[d * D_ + m] : src[m * D_ + d];
      dst[i] = f2bf(v);
    }
  } else {
    const int b = blk - 8;
    uint2* p = (uint2*)(hT + ((size_t)(b * 96 + 80)) * N_);
    for (int i = threadIdx.x; i < 16 * N_ / 4; i += 256) p[i] = (uint2){0, 0};
  }
}

// ---------------------------------------------------------------- featem
__global__ __launch_bounds__(128) void featem_kernel(
    const float* __restrict__ H, const float* __restrict__ W, float* __restrict__ x)
{
  const int r = blockIdx.x, t = threadIdx.x;
  __shared__ float row[F0_];
  if (t < F0_) row[t] = H[(size_t)r * F0_ + t];
  __syncthreads();
  if (t < D_) {
    float a = 0.f;
#pragma unroll 8
    for (int m = 0; m < F0_; m++) a += row[m] * W[t * F0_ + m];
    x[(size_t)r * D_ + t] = a;
  }
}

// -------------------- adjacency: tiled pack [b][jt][it][32j][32i] + bitmasks
// One block per 32x32 tile. adj symmetric -> the "transposed" tile is a
// DIRECT read of rows (j0+jrel) at cols (i0..): fully coalesced, no LDS xpose.
__global__ __launch_bounds__(256) void prep_adj_tiled(
    const float* __restrict__ A1, const float* __restrict__ A2,
    const float* __restrict__ mup, const float* __restrict__ devp,
    ushortT* __restrict__ adj_t, unsigned* __restrict__ m1b, unsigned* __restrict__ m2b)
{
  const int it = blockIdx.x, jt = blockIdx.y, b = blockIdx.z;
  const int i0 = it * 32, j0 = jt * 32;
  const int tid = threadIdx.x;
  const int jrel = tid >> 3, iq = tid & 7;
  __shared__ unsigned m1s[32], m2s[32];
  if (tid < 32) { m1s[tid] = 0; m2s[tid] = 0; }
  __syncthreads();
  const float mu = mup[0], idev = 1.0f / devp[0];
  const size_t base = ((size_t)b * N_ + j0 + jrel) * N_ + i0 + iq * 4;
  const float4 a1 = *(const float4*)(A1 + base);
  const float4 a2 = *(const float4*)(A2 + base);
  const float a1v[4] = {a1.x, a1.y, a1.z, a1.w};
  const float a2v[4] = {a2.x, a2.y, a2.z, a2.w};
  ushortT o[4];
#pragma unroll
  for (int k = 0; k < 4; k++) {
    const float rbf = (a2v[k] <= 10.f) ? __expf(-(a2v[k] - mu) * (a2v[k] - mu) * idev) : 0.f;
    const float adj1 = rbf + a1v[k];
    ushortT u = ((ushortT)f2bf(adj1)) & 0xFFFE;
    if (a1v[k] > 0.f) u |= 1;
    o[k] = u;
  }
  *(uint2*)(adj_t + ((size_t)(b * 32 + jt) * 32 + it) * 1024 + jrel * 32 + iq * 4) =
      *(uint2*)o;
  // masks: bit jrel of word (row i0+iq*4+k, word jt). value at (j0+jrel, i0+iq*4+k)
  // equals adj[i0+iq*4+k][j0+jrel] by symmetry.
  const unsigned bit = 1u << jrel;
#pragma unroll
  for (int k = 0; k < 4; k++) {
    if (o[k] & 0xFFFEu) atomicOr(&m1s[iq * 4 + k], bit);
    if (o[k] & 1u)      atomicOr(&m2s[iq * 4 + k], bit);
  }
  __syncthreads();
  if (tid < 32) {
    m1b[((size_t)b * N_ + i0 + tid) * 32 + jt] = m1s[tid];
    m2b[((size_t)b * N_ + i0 + tid) * 32 + jt] = m2s[tid];
  }
}

// ---------------- fused [combine] + h + hA + hT via MFMA (32 rows, 2 waves)
template<int MODE>
__global__ __launch_bounds__(128) void gatmm_mfma(
    float* __restrict__ x,
    const ushortT* __restrict__ hp1p, const ushortT* __restrict__ hp2p, int JC,
    const float* __restrict__ g1, const float* __restrict__ g2w, const float* __restrict__ g2b,
    const short* __restrict__ Wb, const short* __restrict__ Atb,
    short* __restrict__ hb16, short* __restrict__ hAb16, short* __restrict__ hT)
{
  const int tid = threadIdx.x;
  const int w = tid >> 6, lane = tid & 63;
  const int lr = lane & 15, kg = lane >> 4;
  const int r0 = blockIdx.x * 32;
  const int b = r0 >> 10, n0 = r0 & (N_ - 1);

  __shared__ __align__(16) short sxb[32][104];
  __shared__ __align__(16) short shl[32][104];

  for (int i = tid; i < 320; i += 128) {
    const int r = i / 10, c = i - (i / 10) * 10;
    *(uint2*)&sxb[r][64 + c * 4] = (uint2){0, 0};
    *(uint2*)&shl[r][64 + c * 4] = (uint2){0, 0};
  }

  if (MODE == 0) {
    for (int i = tid; i < 32 * D_; i += 128) {
      const int r = i / D_;
      sxb[r][i - r * D_] = f2bf(x[(size_t)r0 * D_ + i]);
    }
  } else {
    const int lt = tid & 15, gg = tid >> 4;
#pragma unroll
    for (int rg = 0; rg < 4; rg++) {
      const int row = gg * 4 + rg;
      const int grow = r0 + row;
      float s1[5], s2[5], xv[5];
#pragma unroll
      for (int q = 0; q < 5; q++) { s1[q] = 0.f; s2[q] = 0.f; xv[q] = 0.f; }
      for (int jc = 0; jc < JC; jc++) {
        const size_t bp = ((size_t)jc * (B_ * N_) + grow) * 80 + lt;
#pragma unroll
        for (int q = 0; q < 5; q++) {
          s1[q] += bfdec(hp1p[bp + 16 * q]);
          s2[q] += bfdec(hp2p[bp + 16 * q]);
        }
      }
      float d1 = 0.f, d2 = 0.f, d3 = 0.f;
#pragma unroll
      for (int q = 0; q < 5; q++) {
        const int d = lt + 16 * q;
        if (d < D_) {
          s1[q] = fmaxf(s1[q], 0.f); s2[q] = fmaxf(s2[q], 0.f);
          xv[q] = x[(size_t)grow * D_ + d];
          d1 += xv[q] * g1[d]; d2 += s1[q] * g2w[d]; d3 += s2[q] * g2w[d];
        }
      }
#pragma unroll
      for (int off = 1; off < 16; off <<= 1) {
        d1 += __shfl_xor(d1, off); d2 += __shfl_xor(d2, off); d3 += __shfl_xor(d3, off);
      }
      const float bb = g2b[0];
      const float c1 = 1.f / (1.f + __expf(-(d1 + d2 + bb)));
      const float c2 = 1.f / (1.f + __expf(-(d1 + d3 + bb)));
#pragma unroll
      for (int q = 0; q < 5; q++) {
        const int d = lt + 16 * q;
        if (d < D_) {
          const float xn = (c1 * xv[q] + (1.f - c1) * s1[q]) - (c2 * xv[q] + (1.f - c2) * s2[q]);
          x[(size_t)grow * D_ + d] = xn;
          sxb[row][d] = f2bf(xn);
        }
      }
    }
  }
  __syncthreads();

  // GEMM1: h = x @ W^T
  bf16x8 af[3];
#pragma unroll
  for (int ks = 0; ks < 3; ks++)
    af[ks] = *(const bf16x8*)&sxb[w * 16 + lr][ks * 32 + kg * 8];
  f32x4 acc[5];
#pragma unroll
  for (int nt = 0; nt < 5; nt++) acc[nt] = (f32x4){0.f, 0.f, 0.f, 0.f};
#pragma unroll
  for (int nt = 0; nt < 5; nt++) {
#pragma unroll
    for (int ks = 0; ks < 3; ks++) {
      bf16x8 bw = *(const bf16x8*)(Wb + (size_t)(nt * 16 + lr) * 96 + ks * 32 + kg * 8);
      acc[nt] = __builtin_amdgcn_mfma_f32_16x16x32_bf16(af[ks], bw, acc[nt], 0, 0, 0);
    }
  }
#pragma unroll
  for (int nt = 0; nt < 5; nt++)
#pragma unroll
    for (int r = 0; r < 4; r++)
      shl[w * 16 + kg * 4 + r][nt * 16 + lr] = f2bf(acc[nt][r]);
  __syncthreads();

  for (int i = tid; i < 32 * 12; i += 128) {
    const int r = i / 12, seg = i - (i / 12) * 12;
    *(bf16x8*)(hb16 + (size_t)(r0 + r) * DK_ + seg * 8) = *(const bf16x8*)&shl[r][seg * 8];
  }
  for (int i = tid; i < 80 * 4; i += 128) {
    const int d = i >> 2, ng = i & 3;
    short tmp[8];
#pragma unroll
    for (int k = 0; k < 8; k++) tmp[k] = shl[ng * 8 + k][d];
    *(bf16x8*)(hT + ((size_t)(b * 96 + d)) * N_ + n0 + ng * 8) = *(bf16x8*)tmp;
  }

  // GEMM2: hA = h @ A
  bf16x8 ah[3];
#pragma unroll
  for (int ks = 0; ks < 3; ks++)
    ah[ks] = *(const bf16x8*)&shl[w * 16 + lr][ks * 32 + kg * 8];
  f32x4 acc2[5];
#pragma unroll
  for (int nt = 0; nt < 5; nt++) acc2[nt] = (f32x4){0.f, 0.f, 0.f, 0.f};
#pragma unroll
  for (int nt = 0; nt < 5; nt++) {
#pragma unroll
    for (int ks = 0; ks < 3; ks++) {
      bf16x8 bw = *(const bf16x8*)(Atb + (size_t)(nt * 16 + lr) * 96 + ks * 32 + kg * 8);
      acc2[nt] = __builtin_amdgcn_mfma_f32_16x16x32_bf16(ah[ks], bw, acc2[nt], 0, 0, 0);
    }
  }
#pragma unroll
  for (int nt = 0; nt < 5; nt++)
#pragma unroll
    for (int r = 0; r < 4; r++)
      sxb[w * 16 + kg * 4 + r][nt * 16 + lr] = f2bf(acc2[nt][r]);
  __syncthreads();
  for (int i = tid; i < 32 * 12; i += 128) {
    const int r = i / 12, seg = i - (i / 12) * 12;
    *(bf16x8*)(hAb16 + (size_t)(r0 + r) * DK_ + seg * 8) = *(const bf16x8*)&sxb[r][seg * 8];
  }
}

// ---------------- passE: E tiles (stored fp16, tiled) + masked softmax stats
__global__ __launch_bounds__(256) void passE_mfma(
    const unsigned* __restrict__ m1b, const unsigned* __restrict__ m2b,
    const short* __restrict__ hb16, const short* __restrict__ hAb16,
    ushortT* __restrict__ Et,
    float* __restrict__ M1p, float* __restrict__ S1p,
    float* __restrict__ M2p, float* __restrict__ S2p)
{
  const int jt = blockIdx.x, ic = blockIdx.y, b = blockIdx.z;
  const int tid = threadIdx.x, w = tid >> 6, lane = tid & 63;
  const int lr = lane & 15, kg = lane >> 4;
  const int ih = w >> 1, jh = w & 1;
  const int j0 = jt * 32;
  const short* hb  = hb16  + (size_t)b * N_ * DK_;
  const short* hAb = hAb16 + (size_t)b * N_ * DK_;

  bf16x8 b_h[3], b_hA[3];
  {
    const short* p = hb  + (size_t)(j0 + jh * 16 + lr) * DK_ + kg * 8;
    const short* q = hAb + (size_t)(j0 + jh * 16 + lr) * DK_ + kg * 8;
#pragma unroll
    for (int ks = 0; ks < 3; ks++) {
      b_h[ks]  = *(const bf16x8*)(p + ks * 32);
      b_hA[ks] = *(const bf16x8*)(q + ks * 32);
    }
  }
  const int bitp = jh * 16 + lr;
  const int i0base = ic * 128;
  float Ev[16];
  unsigned g1m = 0, g2m = 0;

#pragma unroll
  for (int iter = 0; iter < 4; iter++) {
    const int i0 = i0base + iter * 32 + ih * 16;
    const short* pa = hAb + (size_t)(i0 + lr) * DK_ + kg * 8;
    const short* ph = hb  + (size_t)(i0 + lr) * DK_ + kg * 8;
    bf16x8 a_hA[3], a_h[3];
#pragma unroll
    for (int ks = 0; ks < 3; ks++) {
      a_hA[ks] = *(const bf16x8*)(pa + ks * 32);
      a_h[ks]  = *(const bf16x8*)(ph + ks * 32);
    }
    const unsigned* W1p = m1b + ((size_t)b * N_ + i0 + kg * 4) * 32 + jt;
    const unsigned* W2p = m2b + ((size_t)b * N_ + i0 + kg * 4) * 32 + jt;
    unsigned mw1[4], mw2[4];
#pragma unroll
    for (int r = 0; r < 4; r++) { mw1[r] = W1p[(size_t)r * 32]; mw2[r] = W2p[(size_t)r * 32]; }
    f32x4 E = {0.f, 0.f, 0.f, 0.f};
#pragma unroll
    for (int ks = 0; ks < 3; ks++)
      E = __builtin_amdgcn_mfma_f32_16x16x32_bf16(a_hA[ks], b_h[ks], E, 0, 0, 0);
#pragma unroll
    for (int ks = 0; ks < 3; ks++)
      E = __builtin_amdgcn_mfma_f32_16x16x32_bf16(a_h[ks], b_hA[ks], E, 0, 0, 0);
    ushortT ev16[4];
#pragma unroll
    for (int r = 0; r < 4; r++) ev16[r] = f2h(E[r]);
    {
      const int itg = ic * 4 + iter;
      const unsigned lo = (unsigned)ev16[0] | ((unsigned)ev16[1] << 16);
      const unsigned hi = (unsigned)ev16[2] | ((unsigned)ev16[3] << 16);
      ushortT* dst = Et + ((size_t)(b * 32 + jt) * 32 + itg) * 1024 +
                     (jh * 16 + lr) * 32 + (ih * 16 + kg * 4);
      *(uint2*)dst = (uint2){lo, hi};
    }
#pragma unroll
    for (int r = 0; r < 4; r++) {
      Ev[iter * 4 + r] = h2f(ev16[r]);
      g1m |= ((mw1[r] >> bitp) & 1u) << (iter * 4 + r);
      g2m |= ((mw2[r] >> bitp) & 1u) << (iter * 4 + r);
    }
  }
  float M1r = -3.0e38f, M2r = -3.0e38f;
#pragma unroll
  for (int k = 0; k < 16; k++) {
    M1r = ((g1m >> k) & 1u) ? fmaxf(M1r, Ev[k]) : M1r;
    M2r = ((g2m >> k) & 1u) ? fmaxf(M2r, Ev[k]) : M2r;
  }
  float S1r = 0.f, S2r = 0.f;
#pragma unroll
  for (int k = 0; k < 16; k++) {
    S1r += ((g1m >> k) & 1u) ? __expf(Ev[k] - M1r) : 0.f;
    S2r += ((g2m >> k) & 1u) ? __expf(Ev[k] - M2r) : 0.f;
  }
#pragma unroll
  for (int off = 16; off <= 32; off <<= 1) {
    float Mo = __shfl_xor(M1r, off), So = __shfl_xor(S1r, off);
    float nM = fmaxf(M1r, Mo);
    S1r = S1r * __expf(M1r - nM) + So * __expf(Mo - nM); M1r = nM;
    Mo = __shfl_xor(M2r, off); So = __shfl_xor(S2r, off);
    nM = fmaxf(M2r, Mo);
    S2r = S2r * __expf(M2r - nM) + So * __expf(Mo - nM); M2r = nM;
  }
  __shared__ float sM[2][4][16], sS[2][4][16];
  if (lane < 16) {
    sM[0][w][lr] = M1r; sS[0][w][lr] = S1r;
    sM[1][w][lr] = M2r; sS[1][w][lr] = S2r;
  }
  __syncthreads();
  if (tid < 32) {
    const int jhh = tid >> 4, l2 = tid & 15;
    const size_t o = ((size_t)b * 8 + ic) * N_ + j0 + jhh * 16 + l2;
    {
      float Ma = sM[0][jhh][l2], Sa = sS[0][jhh][l2];
      float Mb = sM[0][2 + jhh][l2], Sb = sS[0][2 + jhh][l2];
      float nM = fmaxf(Ma, Mb);
      M1p[o] = nM; S1p[o] = Sa * __expf(Ma - nM) + Sb * __expf(Mb - nM);
    }
    {
      float Ma = sM[1][jhh][l2], Sa = sS[1][jhh][l2];
      float Mb = sM[1][2 + jhh][l2], Sb = sS[1][2 + jhh][l2];
      float nM = fmaxf(Ma, Mb);
      M2p[o] = nM; S2p[o] = Sa * __expf(Ma - nM) + Sb * __expf(Mb - nM);
    }
  }
}

// --------------------- passPV: read E + adj tiles, weights, PV MFMA
__global__ __launch_bounds__(256) void passPV_mfma(
    const ushortT* __restrict__ adj_t, const ushortT* __restrict__ Et,
    const short* __restrict__ hT16,
    const float* __restrict__ M1p, const float* __restrict__ S1p,
    const float* __restrict__ M2p, const float* __restrict__ S2p,
    ushortT* __restrict__ hp1p, ushortT* __restrict__ hp2p, int njt)
{
  const int it = blockIdx.x, jc = blockIdx.y, b = blockIdx.z;
  const int tid = threadIdx.x, w = tid >> 6, lane = tid & 63;
  const int lr = lane & 15, kg = lane >> 4;
  const int ih = w >> 1, jh = w & 1;
  const int dbase = (w & 1) * 3;
  const int jbase = jc * njt * 32;

  __shared__ float sMS[4][256];
  for (int idx = tid; idx < njt * 32; idx += 256) {
    const int col = jbase + idx;
    float M = -3.0e38f, S = 0.f;
#pragma unroll
    for (int q = 0; q < 8; q++) {
      const float m = M1p[((size_t)b * 8 + q) * N_ + col];
      const float s = S1p[((size_t)b * 8 + q) * N_ + col];
      const float nM = fmaxf(M, m);
      S = S * __expf(M - nM) + s * __expf(m - nM); M = nM;
    }
    sMS[0][idx] = M; sMS[1][idx] = 1.0f / S;
    M = -3.0e38f; S = 0.f;
#pragma unroll
    for (int q = 0; q < 8; q++) {
      const float m = M2p[((size_t)b * 8 + q) * N_ + col];
      const float s = S2p[((size_t)b * 8 + q) * N_ + col];
      const float nM = fmaxf(M, m);
      S = S * __expf(M - nM) + s * __expf(m - nM); M = nM;
    }
    sMS[2][idx] = M; sMS[3][idx] = 1.0f / S;
  }

  const short* hTb = hT16 + (size_t)b * DK_ * N_;
  f32x4 acc[2][3];
#pragma unroll
  for (int m = 0; m < 2; m++)
#pragma unroll
    for (int q = 0; q < 3; q++) acc[m][q] = (f32x4){0.f, 0.f, 0.f, 0.f};

  __shared__ short wlds[2][2][32][40];
  __syncthreads();

  for (int t = 0; t < njt; ++t) {
    const int j0 = jbase + t * 32;
    const int jtg = (jbase >> 5) + t;
    const int par = t & 1;
    const size_t tb = ((size_t)(b * 32 + jtg) * 32 + it) * 1024 +
                      (jh * 16 + lr) * 32 + (ih * 16 + kg * 4);
    const uint2 eraw = *(const uint2*)(Et + tb);
    const uint2 araw = *(const uint2*)(adj_t + tb);
    bf16x8 bt[3];
#pragma unroll
    for (int q = 0; q < 3; q++)
      bt[q] = *(const bf16x8*)(hTb + (size_t)((dbase + q) * 16 + lr) * N_ + j0 + kg * 8);

    const ushortT ev[4] = {(ushortT)(eraw.x & 0xFFFF), (ushortT)(eraw.x >> 16),
                           (ushortT)(eraw.y & 0xFFFF), (ushortT)(eraw.y >> 16)};
    const ushortT uu[4] = {(ushortT)(araw.x & 0xFFFF), (ushortT)(araw.x >> 16),
                           (ushortT)(araw.y & 0xFFFF), (ushortT)(araw.y >> 16)};
    const int jrel = t * 32 + jh * 16 + lr;
    const float M1j = sMS[0][jrel], is1 = sMS[1][jrel];
    const float M2j = sMS[2][jrel], is2 = sMS[3][jrel];

    short w1v[4], w2v[4];
#pragma unroll
    for (int r = 0; r < 4; r++) {
      const float e = h2f(ev[r]);
      const float adj1v = bfdec(uu[r] & 0xFFFEu);
      const bool gon1 = (uu[r] & 0xFFFEu) != 0, gon2 = (uu[r] & 1u) != 0;
      w1v[r] = f2bf(gon1 ? __expf(e - M1j) * adj1v * is1 : 0.f);
      w2v[r] = f2bf(gon2 ? __expf(e - M2j) * is2 : 0.f);
    }
#pragma unroll
    for (int r = 0; r < 4; r++) {
      wlds[par][0][ih * 16 + kg * 4 + r][jh * 16 + lr] = w1v[r];
      wlds[par][1][ih * 16 + kg * 4 + r][jh * 16 + lr] = w2v[r];
    }
    __syncthreads();
#pragma unroll
    for (int m = 0; m < 2; m++) {
      bf16x8 af = *(const bf16x8*)&wlds[par][m][ih * 16 + lr][kg * 8];
#pragma unroll
      for (int q = 0; q < 3; q++)
        acc[m][q] = __builtin_amdgcn_mfma_f32_16x16x32_bf16(af, bt[q], acc[m][q], 0, 0, 0);
    }
  }
  const int i0 = it * 32;
#pragma unroll
  for (int m = 0; m < 2; m++) {
#pragma unroll
    for (int q = 0; q < 3; q++) {
      const int dt = dbase + q;
      if (dt < 5) {
        ushortT* dst = (m ? hp2p : hp1p) +
            (((size_t)jc * B_ + b) * N_ + i0 + ih * 16 + kg * 4) * 80 + dt * 16 + lr;
#pragma unroll
        for (int r = 0; r < 4; r++) dst[(size_t)r * 80] = (ushortT)f2bf(acc[m][q][r]);
      }
    }
  }
}

// ---------------------- final-layer combine (in-place x)
__global__ __launch_bounds__(256) void combine_kernel(
    float* __restrict__ x,
    const ushortT* __restrict__ hp1p, const ushortT* __restrict__ hp2p, int JC,
    const float* __restrict__ g1, const float* __restrict__ g2w,
    const float* __restrict__ g2b)
{
  const int r = blockIdx.x * 4 + (threadIdx.x >> 6);
  const int t = threadIdx.x & 63;
  float s1a = 0.f, s2a = 0.f, s1b = 0.f, s2b = 0.f;
  for (int q = 0; q < JC; q++) {
    const size_t base = ((size_t)q * (B_ * N_) + r) * 80;
    s1a += bfdec(hp1p[base + t]);
    s2a += bfdec(hp2p[base + t]);
    if (t < D_ - 64) {
      s1b += bfdec(hp1p[base + 64 + t]);
      s2b += bfdec(hp2p[base + 64 + t]);
    }
  }
  const float a0 = fmaxf(s1a, 0.f), b0 = fmaxf(s2a, 0.f);
  const float a1v = fmaxf(s1b, 0.f), b1v = fmaxf(s2b, 0.f);
  float* xr = x + (size_t)r * D_;
  const float x0 = xr[t];
  float d1 = x0 * g1[t], d2 = a0 * g2w[t], d3 = b0 * g2w[t];
  float x1 = 0.f;
  if (t < D_ - 64) {
    x1 = xr[64 + t];
    d1 += x1 * g1[64 + t]; d2 += a1v * g2w[64 + t]; d3 += b1v * g2w[64 + t];
  }
#pragma unroll
  for (int off = 1; off < 64; off <<= 1) {
    d1 += __shfl_xor(d1, off);
    d2 += __shfl_xor(d2, off);
    d3 += __shfl_xor(d3, off);
  }
  const float bb = g2b[0];
  const float c1 = 1.f / (1.f + __expf(-(d1 + d2 + bb)));
  const float c2 = 1.f / (1.f + __expf(-(d1 + d3 + bb)));
  xr[t] = (c1 * x0 + (1.f - c1) * a0) - (c2 * x0 + (1.f - c2) * b0);
  if (t < D_ - 64)
    xr[64 + t] = (c1 * x1 + (1.f - c1) * a1v) - (c2 * x1 + (1.f - c2) * b1v);
}

// ------------------------------------------- masked sum pool over N
__global__ __launch_bounds__(256) void pool_kernel(
    const float* __restrict__ x, const float* __restrict__ V, float* __restrict__ pooled)
{
  const int d = blockIdx.x, b = blockIdx.y, t = threadIdx.x;
  const float* xb = x + (size_t)b * N_ * D_;
  const float* Vb = V + (size_t)b * N_;
  float s = 0.f;
  for (int n = t; n < N_; n += 256) s += xb[(size_t)n * D_ + d] * Vb[n];
#pragma unroll
  for (int off = 32; off >= 1; off >>= 1) s += __shfl_down(s, off);
  __shared__ float red[4];
  if ((t & 63) == 0) red[t >> 6] = s;
  __syncthreads();
  if (t == 0) pooled[b * D_ + d] = red[0] + red[1] + red[2] + red[3];
}

// ------------------------------------------- MLP head (single block, 1024 thr)
__global__ __launch_bounds__(1024) void fc_kernel(
    const float* __restrict__ pooled,
    const float* __restrict__ w0, const float* __restrict__ b0,
    const float* __restrict__ w1, const float* __restrict__ b1,
    const float* __restrict__ w2, const float* __restrict__ b2,
    const float* __restrict__ w3, const float* __restrict__ b3,
    float* __restrict__ out)
{
  __shared__ float pin[B_][D_];
  __shared__ float bufA[B_][DFC_], bufB[B_][DFC_];
  const int t = threadIdx.x;
  if (t < B_ * D_) pin[t / D_][t % D_] = pooled[t];
  __syncthreads();
  const int r = t >> 7, o = t & 127;
  {
    float a = b0[o];
    const float2* wr = (const float2*)(w0 + o * D_);
#pragma unroll
    for (int m2 = 0; m2 < D_ / 2; m2++) {
      const float2 wv = wr[m2];
      a += pin[r][m2 * 2] * wv.x + pin[r][m2 * 2 + 1] * wv.y;
    }
    bufA[r][o] = fmaxf(a, 0.f);
  }
  __syncthreads();
  {
    float a = b1[o];
    const float4* wr = (const float4*)(w1 + o * DFC_);
    const float4* br = (const float4*)&bufA[r][0];
#pragma unroll
    for (int m4 = 0; m4 < DFC_ / 4; m4++) a += dot4(br[m4], wr[m4]);
    bufB[r][o] = fmaxf(a, 0.f);
  }
  __syncthreads();
  {
    float a = b2[o];
    const float4* wr = (const float4*)(w2 + o * DFC_);
    const float4* br = (const float4*)&bufB[r][0];
#pragma unroll
    for (int m4 = 0; m4 < DFC_ / 4; m4++) a += dot4(br[m4], wr[m4]);
    bufA[r][o] = fmaxf(a, 0.f);
  }
  __syncthreads();
  if (t < 64) {
    const int rr = t >> 3, l8 = t & 7;
    const float4* wr = (const float4*)(w3 + l8 * 16);
    const float4* br = (const float4*)&bufA[rr][l8 * 16];
    float a = 0.f;
#pragma unroll
    for (int m4 = 0; m4 < 4; m4++) a += dot4(br[m4], wr[m4]);
    a += __shfl_xor(a, 1); a += __shfl_xor(a, 2); a += __shfl_xor(a, 4);
    if (l8 == 0) out[rr] = 1.f / (1.f + __expf(-(a + b3[0])));
  }
}

// ----------------------------------------------------------------------
extern "C" void kernel_launch(void* const* d_in, const int* in_sizes, int n_in,
                              void* d_out, int out_size, void* d_ws, size_t ws_size,
                              hipStream_t stream)
{
  const float* H     = (const float*)d_in[0];
  const float* A1    = (const float*)d_in[1];
  const float* A2    = (const float*)d_in[2];
  const float* V     = (const float*)d_in[3];
  const float* few   = (const float*)d_in[4];
  const float* mup   = (const float*)d_in[5];
  const float* devp  = (const float*)d_in[6];
  const float* gW    = (const float*)d_in[7];
  const float* gA    = (const float*)d_in[8];
  const float* g1    = (const float*)d_in[9];
  const float* g2w   = (const float*)d_in[10];
  const float* g2b   = (const float*)d_in[11];
  const float* w0 = (const float*)d_in[12]; const float* b0 = (const float*)d_in[13];
  const float* w1 = (const float*)d_in[14]; const float* b1 = (const float*)d_in[15];
  const float* w2 = (const float*)d_in[16]; const float* b2 = (const float*)d_in[17];
  const float* w3 = (const float*)d_in[18]; const float* b3 = (const float*)d_in[19];
  float* outp = (float*)d_out;

  float* ws = (float*)d_ws;
  // fixed layout (float offsets)
  float*   x     = ws;                         // 573440
  short*   hb16  = (short*)(ws + 573440);
  short*   hAb16 = (short*)(ws + 966656);
  short*   hT16  = (short*)(ws + 1359872);
  short*   Wb16  = (short*)(ws + 1753088);
  short*   Atb16 = (short*)(ws + 1768448);
  float*   M1p   = ws + 1783808;               // 8*B*N each
  float*   S1p   = ws + 1849344;
  float*   M2p   = ws + 1914880;
  float*   S2p   = ws + 1980416;
  float*   pooled= ws + 2045952;               // -> 2046528
  ushortT* adj_t = (ushortT*)(ws + 2046528);   // 8M u16 -> 6240832
  unsigned* m1b  = (unsigned*)(ws + 6240832);  // -> 6502976
  unsigned* m2b  = (unsigned*)(ws + 6502976);  // -> 6765120
  ushortT* Et    = (ushortT*)(ws + 6765120);   // 8M u16 -> 10959424
  const int JC = 4;
  ushortT* hp1p  = (ushortT*)(ws + 10959424);
  ushortT* hp2p  = hp1p + (size_t)JC * 655360u;
  const size_t need = (size_t)(10959424u + (size_t)JC * 655360u) * 4u;
  if (ws_size < need) return;
  const int njt = (N_ / 32) / JC;
  const int ROWS = B_ * N_;

  prep_wb<<<16, 256, 0, stream>>>(gW, gA, Wb16, Atb16, hT16);
  featem_kernel<<<ROWS, 128, 0, stream>>>(H, few, x);
  prep_adj_tiled<<<dim3(32, 32, B_), 256, 0, stream>>>(A1, A2, mup, devp, adj_t, m1b, m2b);

  for (int k = 0; k < 4; k++) {
    const short* Wk  = Wb16  + (size_t)k * 80 * 96;
    const short* Atk = Atb16 + (size_t)k * 80 * 96;
    if (k == 0)
      gatmm_mfma<0><<<ROWS / 32, 128, 0, stream>>>(
          x, nullptr, nullptr, 0, nullptr, nullptr, nullptr,
          Wk, Atk, hb16, hAb16, hT16);
    else
      gatmm_mfma<1><<<ROWS / 32, 128, 0, stream>>>(
          x, hp1p, hp2p, JC,
          g1 + (size_t)(k - 1) * D_, g2w + (size_t)(k - 1) * D_, g2b + (k - 1),
          Wk, Atk, hb16, hAb16, hT16);
    passE_mfma<<<dim3(32, 8, B_), 256, 0, stream>>>(m1b, m2b, hb16, hAb16, Et,
                                                    M1p, S1p, M2p, S2p);
    passPV_mfma<<<dim3(32, JC, B_), 256, 0, stream>>>(adj_t, Et, hT16,
        M1p, S1p, M2p, S2p, hp1p, hp2p, njt);
  }
  combine_kernel<<<ROWS / 4, 256, 0, stream>>>(x, hp1p, hp2p, JC,
                                               g1 + 3 * D_, g2w + 3 * D_, g2b + 3);
  pool_kernel<<<dim3(D_, B_), 256, 0, stream>>>(x, V, pooled);
  fc_kernel<<<1, 1024, 0, stream>>>(pooled, w0, b0, w1, b1, w2, b2, w3, b3, outp);
}

// Round 9
// 312.174 us; speedup vs baseline: 1.3079x; 1.0154x over previous
//
#include <hip/hip_runtime.h>

#define B_   8
#define N_   1024
#define F0_  56
#define D_   70
#define DK_  96      // bf16 K-padded row stride (3 x 32)
#define DFC_ 128

typedef __attribute__((ext_vector_type(8))) short bf16x8;
typedef __attribute__((ext_vector_type(4))) float f32x4;
typedef unsigned short ushortT;
typedef _Float16 f16T;

__device__ __forceinline__ short f2bf(float x) {
  unsigned u = __builtin_bit_cast(unsigned, x);
  u += 0x7FFF + ((u >> 16) & 1);
  return (short)(u >> 16);
}
__device__ __forceinline__ float bfdec(unsigned u16bits) {
  unsigned v = u16bits << 16;
  return __builtin_bit_cast(float, v);
}
__device__ __forceinline__ ushortT f2h(float x) {
  f16T h = (f16T)x; return __builtin_bit_cast(ushortT, h);
}
__device__ __forceinline__ float h2f(ushortT u) {
  return (float)__builtin_bit_cast(f16T, u);
}
__device__ __forceinline__ float dot4(float4 a, float4 b) {
  return a.x * b.x + a.y * b.y + a.z * b.z + a.w * b.w;
}

// ---- prep_all: adj tiles+masks (8192 blocks) | weights | hT pad | few | pooled=0
__global__ __launch_bounds__(256) void prep_all(
    const float* __restrict__ A1, const float* __restrict__ A2,
    const float* __restrict__ mup, const float* __restrict__ devp,
    const float* __restrict__ gW, const float* __restrict__ gA,
    const float* __restrict__ few,
    ushortT* __restrict__ adj_t, unsigned* __restrict__ m1b, unsigned* __restrict__ m2b,
    short* __restrict__ Wb16, short* __restrict__ Atb16, short* __restrict__ fewb16,
    short* __restrict__ hT, float* __restrict__ pooled)
{
  const int bid = blockIdx.x;
  const int tid = threadIdx.x;
  if (bid >= 32 * 32 * B_) {
    const int e = bid - 32 * 32 * B_;
    if (e < 8) {
      const int k = e & 3;
      const bool isW = e < 4;
      short* dst = (isW ? Wb16 : Atb16) + (size_t)k * 80 * 96;
      const float* src = (isW ? gW : gA) + (size_t)k * D_ * D_;
      for (int i = tid; i < 80 * 96; i += 256) {
        const int d = i / 96, m = i - (i / 96) * 96;
        float v = 0.f;
        if (d < D_ && m < D_) v = isW ? src[d * D_ + m] : src[m * D_ + d];
        dst[i] = f2bf(v);
      }
    } else if (e < 16) {
      const int b = e - 8;
      uint2* p = (uint2*)(hT + ((size_t)(b * 96 + 80)) * N_);
      for (int i = tid; i < 16 * N_ / 4; i += 256) p[i] = (uint2){0, 0};
    } else {
      for (int i = tid; i < 80 * 64; i += 256) {
        const int d = i >> 6, m = i & 63;
        fewb16[i] = f2bf((d < D_ && m < F0_) ? few[d * F0_ + m] : 0.f);
      }
      for (int i = tid; i < B_ * D_; i += 256) pooled[i] = 0.f;
    }
    return;
  }
  const int it = bid & 31, jt = (bid >> 5) & 31, b = bid >> 10;
  const int i0 = it * 32, j0 = jt * 32;
  const int jrel = tid >> 3, iq = tid & 7;
  __shared__ unsigned m1s[32], m2s[32];
  if (tid < 32) { m1s[tid] = 0; m2s[tid] = 0; }
  __syncthreads();
  const float mu = mup[0], idev = 1.0f / devp[0];
  const size_t base = ((size_t)b * N_ + j0 + jrel) * N_ + i0 + iq * 4;
  const float4 a1 = *(const float4*)(A1 + base);
  const float4 a2 = *(const float4*)(A2 + base);
  const float a1v[4] = {a1.x, a1.y, a1.z, a1.w};
  const float a2v[4] = {a2.x, a2.y, a2.z, a2.w};
  ushortT o[4];
#pragma unroll
  for (int k = 0; k < 4; k++) {
    const float rbf = (a2v[k] <= 10.f) ? __expf(-(a2v[k] - mu) * (a2v[k] - mu) * idev) : 0.f;
    const float adj1 = rbf + a1v[k];
    ushortT u = ((ushortT)f2bf(adj1)) & 0xFFFE;
    if (a1v[k] > 0.f) u |= 1;
    o[k] = u;
  }
  *(uint2*)(adj_t + ((size_t)(b * 32 + jt) * 32 + it) * 1024 + jrel * 32 + iq * 4) =
      *(uint2*)o;
  const unsigned bit = 1u << jrel;
#pragma unroll
  for (int k = 0; k < 4; k++) {
    if (o[k] & 0xFFFEu) atomicOr(&m1s[iq * 4 + k], bit);
    if (o[k] & 1u)      atomicOr(&m2s[iq * 4 + k], bit);
  }
  __syncthreads();
  if (tid < 32) {
    m1b[((size_t)b * N_ + i0 + tid) * 32 + jt] = m1s[tid];
    m2b[((size_t)b * N_ + i0 + tid) * 32 + jt] = m2s[tid];
  }
}

// -- fused [featem|combine] + h + hA + hT via MFMA (32 rows, 2 waves)
// MODE 0: x = H @ few^T (MFMA, writes fp32 x). MODE 1: combine prev layer into x.
template<int MODE>
__global__ __launch_bounds__(128) void gatmm_mfma(
    float* __restrict__ x, const float* __restrict__ H, const short* __restrict__ fewb,
    const ushortT* __restrict__ hp1p, const ushortT* __restrict__ hp2p, int JC,
    const float* __restrict__ g1, const float* __restrict__ g2w, const float* __restrict__ g2b,
    const short* __restrict__ Wb, const short* __restrict__ Atb,
    short* __restrict__ hb16, short* __restrict__ hAb16, short* __restrict__ hT)
{
  const int tid = threadIdx.x;
  const int w = tid >> 6, lane = tid & 63;
  const int lr = lane & 15, kg = lane >> 4;
  const int r0 = blockIdx.x * 32;
  const int b = r0 >> 10, n0 = r0 & (N_ - 1);

  __shared__ __align__(16) short sxb[32][104];
  __shared__ __align__(16) short shl[32][104];

  for (int i = tid; i < 320; i += 128) {
    const int r = i / 10, c = i - (i / 10) * 10;
    *(uint2*)&sxb[r][64 + c * 4] = (uint2){0, 0};
    *(uint2*)&shl[r][64 + c * 4] = (uint2){0, 0};
  }

  if (MODE == 0) {
    // stage H rows bf16 (56 cols padded to 64) into shl
    for (int i = tid; i < 32 * 64; i += 128) {
      const int r = i >> 6, c = i & 63;
      shl[r][c] = f2bf((c < F0_) ? H[(size_t)(r0 + r) * F0_ + c] : 0.f);
    }
    __syncthreads();
    bf16x8 hf[2];
#pragma unroll
    for (int ks = 0; ks < 2; ks++)
      hf[ks] = *(const bf16x8*)&shl[w * 16 + lr][ks * 32 + kg * 8];
    f32x4 accf[5];
#pragma unroll
    for (int nt = 0; nt < 5; nt++) accf[nt] = (f32x4){0.f, 0.f, 0.f, 0.f};
#pragma unroll
    for (int nt = 0; nt < 5; nt++) {
#pragma unroll
      for (int ks = 0; ks < 2; ks++) {
        bf16x8 bw = *(const bf16x8*)(fewb + (size_t)(nt * 16 + lr) * 64 + ks * 32 + kg * 8);
        accf[nt] = __builtin_amdgcn_mfma_f32_16x16x32_bf16(hf[ks], bw, accf[nt], 0, 0, 0);
      }
    }
#pragma unroll
    for (int nt = 0; nt < 5; nt++)
#pragma unroll
      for (int r = 0; r < 4; r++) {
        const int i = w * 16 + kg * 4 + r, d = nt * 16 + lr;
        const float v = accf[nt][r];
        if (d < D_) x[(size_t)(r0 + i) * D_ + d] = v;
        sxb[i][d] = f2bf(v);
      }
  } else {
    const int lt = tid & 15, gg = tid >> 4;
#pragma unroll
    for (int rg = 0; rg < 4; rg++) {
      const int row = gg * 4 + rg;
      const int grow = r0 + row;
      float s1[5], s2[5], xv[5];
#pragma unroll
      for (int q = 0; q < 5; q++) { s1[q] = 0.f; s2[q] = 0.f; xv[q] = 0.f; }
      for (int jc = 0; jc < JC; jc++) {
        const size_t bp = ((size_t)jc * (B_ * N_) + grow) * 80 + lt;
#pragma unroll
        for (int q = 0; q < 5; q++) {
          s1[q] += bfdec(hp1p[bp + 16 * q]);
          s2[q] += bfdec(hp2p[bp + 16 * q]);
        }
      }
      float d1 = 0.f, d2 = 0.f, d3 = 0.f;
#pragma unroll
      for (int q = 0; q < 5; q++) {
        const int d = lt + 16 * q;
        if (d < D_) {
          s1[q] = fmaxf(s1[q], 0.f); s2[q] = fmaxf(s2[q], 0.f);
          xv[q] = x[(size_t)grow * D_ + d];
          d1 += xv[q] * g1[d]; d2 += s1[q] * g2w[d]; d3 += s2[q] * g2w[d];
        }
      }
#pragma unroll
      for (int off = 1; off < 16; off <<= 1) {
        d1 += __shfl_xor(d1, off); d2 += __shfl_xor(d2, off); d3 += __shfl_xor(d3, off);
      }
      const float bb = g2b[0];
      const float c1 = 1.f / (1.f + __expf(-(d1 + d2 + bb)));
      const float c2 = 1.f / (1.f + __expf(-(d1 + d3 + bb)));
#pragma unroll
      for (int q = 0; q < 5; q++) {
        const int d = lt + 16 * q;
        if (d < D_) {
          const float xn = (c1 * xv[q] + (1.f - c1) * s1[q]) - (c2 * xv[q] + (1.f - c2) * s2[q]);
          x[(size_t)grow * D_ + d] = xn;
          sxb[row][d] = f2bf(xn);
        }
      }
    }
  }
  __syncthreads();

  // GEMM1: h = x @ W^T
  bf16x8 af[3];
#pragma unroll
  for (int ks = 0; ks < 3; ks++)
    af[ks] = *(const bf16x8*)&sxb[w * 16 + lr][ks * 32 + kg * 8];
  f32x4 acc[5];
#pragma unroll
  for (int nt = 0; nt < 5; nt++) acc[nt] = (f32x4){0.f, 0.f, 0.f, 0.f};
#pragma unroll
  for (int nt = 0; nt < 5; nt++) {
#pragma unroll
    for (int ks = 0; ks < 3; ks++) {
      bf16x8 bw = *(const bf16x8*)(Wb + (size_t)(nt * 16 + lr) * 96 + ks * 32 + kg * 8);
      acc[nt] = __builtin_amdgcn_mfma_f32_16x16x32_bf16(af[ks], bw, acc[nt], 0, 0, 0);
    }
  }
  __syncthreads();  // MODE 0: shl H-frags consumed; safe to overwrite
#pragma unroll
  for (int nt = 0; nt < 5; nt++)
#pragma unroll
    for (int r = 0; r < 4; r++)
      shl[w * 16 + kg * 4 + r][nt * 16 + lr] = f2bf(acc[nt][r]);
  __syncthreads();

  for (int i = tid; i < 32 * 12; i += 128) {
    const int r = i / 12, seg = i - (i / 12) * 12;
    *(bf16x8*)(hb16 + (size_t)(r0 + r) * DK_ + seg * 8) = *(const bf16x8*)&shl[r][seg * 8];
  }
  for (int i = tid; i < 80 * 4; i += 128) {
    const int d = i >> 2, ng = i & 3;
    short tmp[8];
#pragma unroll
    for (int k = 0; k < 8; k++) tmp[k] = shl[ng * 8 + k][d];
    *(bf16x8*)(hT + ((size_t)(b * 96 + d)) * N_ + n0 + ng * 8) = *(bf16x8*)tmp;
  }

  // GEMM2: hA = h @ A
  bf16x8 ah[3];
#pragma unroll
  for (int ks = 0; ks < 3; ks++)
    ah[ks] = *(const bf16x8*)&shl[w * 16 + lr][ks * 32 + kg * 8];
  f32x4 acc2[5];
#pragma unroll
  for (int nt = 0; nt < 5; nt++) acc2[nt] = (f32x4){0.f, 0.f, 0.f, 0.f};
#pragma unroll
  for (int nt = 0; nt < 5; nt++) {
#pragma unroll
    for (int ks = 0; ks < 3; ks++) {
      bf16x8 bw = *(const bf16x8*)(Atb + (size_t)(nt * 16 + lr) * 96 + ks * 32 + kg * 8);
      acc2[nt] = __builtin_amdgcn_mfma_f32_16x16x32_bf16(ah[ks], bw, acc2[nt], 0, 0, 0);
    }
  }
#pragma unroll
  for (int nt = 0; nt < 5; nt++)
#pragma unroll
    for (int r = 0; r < 4; r++)
      sxb[w * 16 + kg * 4 + r][nt * 16 + lr] = f2bf(acc2[nt][r]);
  __syncthreads();
  for (int i = tid; i < 32 * 12; i += 128) {
    const int r = i / 12, seg = i - (i / 12) * 12;
    *(bf16x8*)(hAb16 + (size_t)(r0 + r) * DK_ + seg * 8) = *(const bf16x8*)&sxb[r][seg * 8];
  }
}

// ---------------- passE: E tiles (stored fp16, tiled) + masked softmax stats
__global__ __launch_bounds__(256) void passE_mfma(
    const unsigned* __restrict__ m1b, const unsigned* __restrict__ m2b,
    const short* __restrict__ hb16, const short* __restrict__ hAb16,
    ushortT* __restrict__ Et,
    float* __restrict__ M1p, float* __restrict__ S1p,
    float* __restrict__ M2p, float* __restrict__ S2p)
{
  const int jt = blockIdx.x, ic = blockIdx.y, b = blockIdx.z;
  const int tid = threadIdx.x, w = tid >> 6, lane = tid & 63;
  const int lr = lane & 15, kg = lane >> 4;
  const int ih = w >> 1, jh = w & 1;
  const int j0 = jt * 32;
  const short* hb  = hb16  + (size_t)b * N_ * DK_;
  const short* hAb = hAb16 + (size_t)b * N_ * DK_;

  bf16x8 b_h[3], b_hA[3];
  {
    const short* p = hb  + (size_t)(j0 + jh * 16 + lr) * DK_ + kg * 8;
    const short* q = hAb + (size_t)(j0 + jh * 16 + lr) * DK_ + kg * 8;
#pragma unroll
    for (int ks = 0; ks < 3; ks++) {
      b_h[ks]  = *(const bf16x8*)(p + ks * 32);
      b_hA[ks] = *(const bf16x8*)(q + ks * 32);
    }
  }
  const int bitp = jh * 16 + lr;
  const int i0base = ic * 128;
  float Ev[16];
  unsigned g1m = 0, g2m = 0;

#pragma unroll
  for (int iter = 0; iter < 4; iter++) {
    const int i0 = i0base + iter * 32 + ih * 16;
    const short* pa = hAb + (size_t)(i0 + lr) * DK_ + kg * 8;
    const short* ph = hb  + (size_t)(i0 + lr) * DK_ + kg * 8;
    bf16x8 a_hA[3], a_h[3];
#pragma unroll
    for (int ks = 0; ks < 3; ks++) {
      a_hA[ks] = *(const bf16x8*)(pa + ks * 32);
      a_h[ks]  = *(const bf16x8*)(ph + ks * 32);
    }
    const unsigned* W1p = m1b + ((size_t)b * N_ + i0 + kg * 4) * 32 + jt;
    const unsigned* W2p = m2b + ((size_t)b * N_ + i0 + kg * 4) * 32 + jt;
    unsigned mw1[4], mw2[4];
#pragma unroll
    for (int r = 0; r < 4; r++) { mw1[r] = W1p[(size_t)r * 32]; mw2[r] = W2p[(size_t)r * 32]; }
    f32x4 E = {0.f, 0.f, 0.f, 0.f};
#pragma unroll
    for (int ks = 0; ks < 3; ks++)
      E = __builtin_amdgcn_mfma_f32_16x16x32_bf16(a_hA[ks], b_h[ks], E, 0, 0, 0);
#pragma unroll
    for (int ks = 0; ks < 3; ks++)
      E = __builtin_amdgcn_mfma_f32_16x16x32_bf16(a_h[ks], b_hA[ks], E, 0, 0, 0);
    ushortT ev16[4];
#pragma unroll
    for (int r = 0; r < 4; r++) ev16[r] = f2h(E[r]);
    {
      const int itg = ic * 4 + iter;
      const unsigned lo = (unsigned)ev16[0] | ((unsigned)ev16[1] << 16);
      const unsigned hi = (unsigned)ev16[2] | ((unsigned)ev16[3] << 16);
      ushortT* dst = Et + ((size_t)(b * 32 + jt) * 32 + itg) * 1024 +
                     (jh * 16 + lr) * 32 + (ih * 16 + kg * 4);
      *(uint2*)dst = (uint2){lo, hi};
    }
#pragma unroll
    for (int r = 0; r < 4; r++) {
      Ev[iter * 4 + r] = h2f(ev16[r]);
      g1m |= ((mw1[r] >> bitp) & 1u) << (iter * 4 + r);
      g2m |= ((mw2[r] >> bitp) & 1u) << (iter * 4 + r);
    }
  }
  float M1r = -3.0e38f, M2r = -3.0e38f;
#pragma unroll
  for (int k = 0; k < 16; k++) {
    M1r = ((g1m >> k) & 1u) ? fmaxf(M1r, Ev[k]) : M1r;
    M2r = ((g2m >> k) & 1u) ? fmaxf(M2r, Ev[k]) : M2r;
  }
  float S1r = 0.f, S2r = 0.f;
#pragma unroll
  for (int k = 0; k < 16; k++) {
    S1r += ((g1m >> k) & 1u) ? __expf(Ev[k] - M1r) : 0.f;
    S2r += ((g2m >> k) & 1u) ? __expf(Ev[k] - M2r) : 0.f;
  }
#pragma unroll
  for (int off = 16; off <= 32; off <<= 1) {
    float Mo = __shfl_xor(M1r, off), So = __shfl_xor(S1r, off);
    float nM = fmaxf(M1r, Mo);
    S1r = S1r * __expf(M1r - nM) + So * __expf(Mo - nM); M1r = nM;
    Mo = __shfl_xor(M2r, off); So = __shfl_xor(S2r, off);
    nM = fmaxf(M2r, Mo);
    S2r = S2r * __expf(M2r - nM) + So * __expf(Mo - nM); M2r = nM;
  }
  __shared__ float sM[2][4][16], sS[2][4][16];
  if (lane < 16) {
    sM[0][w][lr] = M1r; sS[0][w][lr] = S1r;
    sM[1][w][lr] = M2r; sS[1][w][lr] = S2r;
  }
  __syncthreads();
  if (tid < 32) {
    const int jhh = tid >> 4, l2 = tid & 15;
    const size_t o = ((size_t)b * 8 + ic) * N_ + j0 + jhh * 16 + l2;
    {
      float Ma = sM[0][jhh][l2], Sa = sS[0][jhh][l2];
      float Mb = sM[0][2 + jhh][l2], Sb = sS[0][2 + jhh][l2];
      float nM = fmaxf(Ma, Mb);
      M1p[o] = nM; S1p[o] = Sa * __expf(Ma - nM) + Sb * __expf(Mb - nM);
    }
    {
      float Ma = sM[1][jhh][l2], Sa = sS[1][jhh][l2];
      float Mb = sM[1][2 + jhh][l2], Sb = sS[1][2 + jhh][l2];
      float nM = fmaxf(Ma, Mb);
      M2p[o] = nM; S2p[o] = Sa * __expf(Ma - nM) + Sb * __expf(Mb - nM);
    }
  }
}

// --------------------- passPV: read E + adj tiles, weights, PV MFMA
__global__ __launch_bounds__(256) void passPV_mfma(
    const ushortT* __restrict__ adj_t, const ushortT* __restrict__ Et,
    const short* __restrict__ hT16,
    const float* __restrict__ M1p, const float* __restrict__ S1p,
    const float* __restrict__ M2p, const float* __restrict__ S2p,
    ushortT* __restrict__ hp1p, ushortT* __restrict__ hp2p, int njt)
{
  const int it = blockIdx.x, jc = blockIdx.y, b = blockIdx.z;
  const int tid = threadIdx.x, w = tid >> 6, lane = tid & 63;
  const int lr = lane & 15, kg = lane >> 4;
  const int ih = w >> 1, jh = w & 1;
  const int dbase = (w & 1) * 3;
  const int jbase = jc * njt * 32;

  __shared__ float sMS[4][256];
  for (int idx = tid; idx < njt * 32; idx += 256) {
    const int col = jbase + idx;
    float M = -3.0e38f, S = 0.f;
#pragma unroll
    for (int q = 0; q < 8; q++) {
      const float m = M1p[((size_t)b * 8 + q) * N_ + col];
      const float s = S1p[((size_t)b * 8 + q) * N_ + col];
      const float nM = fmaxf(M, m);
      S = S * __expf(M - nM) + s * __expf(m - nM); M = nM;
    }
    sMS[0][idx] = M; sMS[1][idx] = 1.0f / S;
    M = -3.0e38f; S = 0.f;
#pragma unroll
    for (int q = 0; q < 8; q++) {
      const float m = M2p[((size_t)b * 8 + q) * N_ + col];
      const float s = S2p[((size_t)b * 8 + q) * N_ + col];
      const float nM = fmaxf(M, m);
      S = S * __expf(M - nM) + s * __expf(m - nM); M = nM;
    }
    sMS[2][idx] = M; sMS[3][idx] = 1.0f / S;
  }

  const short* hTb = hT16 + (size_t)b * DK_ * N_;
  f32x4 acc[2][3];
#pragma unroll
  for (int m = 0; m < 2; m++)
#pragma unroll
    for (int q = 0; q < 3; q++) acc[m][q] = (f32x4){0.f, 0.f, 0.f, 0.f};

  __shared__ short wlds[2][2][32][40];
  __syncthreads();

  for (int t = 0; t < njt; ++t) {
    const int j0 = jbase + t * 32;
    const int jtg = (jbase >> 5) + t;
    const int par = t & 1;
    const size_t tb = ((size_t)(b * 32 + jtg) * 32 + it) * 1024 +
                      (jh * 16 + lr) * 32 + (ih * 16 + kg * 4);
    const uint2 eraw = *(const uint2*)(Et + tb);
    const uint2 araw = *(const uint2*)(adj_t + tb);
    bf16x8 bt[3];
#pragma unroll
    for (int q = 0; q < 3; q++)
      bt[q] = *(const bf16x8*)(hTb + (size_t)((dbase + q) * 16 + lr) * N_ + j0 + kg * 8);

    const ushortT ev[4] = {(ushortT)(eraw.x & 0xFFFF), (ushortT)(eraw.x >> 16),
                           (ushortT)(eraw.y & 0xFFFF), (ushortT)(eraw.y >> 16)};
    const ushortT uu[4] = {(ushortT)(araw.x & 0xFFFF), (ushortT)(araw.x >> 16),
                           (ushortT)(araw.y & 0xFFFF), (ushortT)(araw.y >> 16)};
    const int jrel = t * 32 + jh * 16 + lr;
    const float M1j = sMS[0][jrel], is1 = sMS[1][jrel];
    const float M2j = sMS[2][jrel], is2 = sMS[3][jrel];

    short w1v[4], w2v[4];
#pragma unroll
    for (int r = 0; r < 4; r++) {
      const float e = h2f(ev[r]);
      const float adj1v = bfdec(uu[r] & 0xFFFEu);
      const bool gon1 = (uu[r] & 0xFFFEu) != 0, gon2 = (uu[r] & 1u) != 0;
      w1v[r] = f2bf(gon1 ? __expf(e - M1j) * adj1v * is1 : 0.f);
      w2v[r] = f2bf(gon2 ? __expf(e - M2j) * is2 : 0.f);
    }
#pragma unroll
    for (int r = 0; r < 4; r++) {
      wlds[par][0][ih * 16 + kg * 4 + r][jh * 16 + lr] = w1v[r];
      wlds[par][1][ih * 16 + kg * 4 + r][jh * 16 + lr] = w2v[r];
    }
    __syncthreads();
#pragma unroll
    for (int m = 0; m < 2; m++) {
      bf16x8 af = *(const bf16x8*)&wlds[par][m][ih * 16 + lr][kg * 8];
#pragma unroll
      for (int q = 0; q < 3; q++)
        acc[m][q] = __builtin_amdgcn_mfma_f32_16x16x32_bf16(af, bt[q], acc[m][q], 0, 0, 0);
    }
  }
  const int i0 = it * 32;
#pragma unroll
  for (int m = 0; m < 2; m++) {
#pragma unroll
    for (int q = 0; q < 3; q++) {
      const int dt = dbase + q;
      if (dt < 5) {
        ushortT* dst = (m ? hp2p : hp1p) +
            (((size_t)jc * B_ + b) * N_ + i0 + ih * 16 + kg * 4) * 80 + dt * 16 + lr;
#pragma unroll
        for (int r = 0; r < 4; r++) dst[(size_t)r * 80] = (ushortT)f2bf(acc[m][q][r]);
      }
    }
  }
}

// ------------- final-layer combine fused with masked pool (atomic into pooled)
__global__ __launch_bounds__(256) void combine_pool(
    const float* __restrict__ x,
    const ushortT* __restrict__ hp1p, const ushortT* __restrict__ hp2p, int JC,
    const float* __restrict__ g1, const float* __restrict__ g2w,
    const float* __restrict__ g2b,
    const float* __restrict__ V, float* __restrict__ pooled)
{
  const int r = blockIdx.x * 4 + (threadIdx.x >> 6);
  const int t = threadIdx.x & 63;
  __shared__ float sAcc[D_];
  if (threadIdx.x < D_) sAcc[threadIdx.x] = 0.f;
  __syncthreads();
  float s1a = 0.f, s2a = 0.f, s1b = 0.f, s2b = 0.f;
  for (int q = 0; q < JC; q++) {
    const size_t base = ((size_t)q * (B_ * N_) + r) * 80;
    s1a += bfdec(hp1p[base + t]);
    s2a += bfdec(hp2p[base + t]);
    if (t < D_ - 64) {
      s1b += bfdec(hp1p[base + 64 + t]);
      s2b += bfdec(hp2p[base + 64 + t]);
    }
  }
  const float a0 = fmaxf(s1a, 0.f), b0 = fmaxf(s2a, 0.f);
  const float a1v = fmaxf(s1b, 0.f), b1v = fmaxf(s2b, 0.f);
  const float* xr = x + (size_t)r * D_;
  const float x0 = xr[t];
  float d1 = x0 * g1[t], d2 = a0 * g2w[t], d3 = b0 * g2w[t];
  float x1 = 0.f;
  if (t < D_ - 64) {
    x1 = xr[64 + t];
    d1 += x1 * g1[64 + t]; d2 += a1v * g2w[64 + t]; d3 += b1v * g2w[64 + t];
  }
#pragma unroll
  for (int off = 1; off < 64; off <<= 1) {
    d1 += __shfl_xor(d1, off);
    d2 += __shfl_xor(d2, off);
    d3 += __shfl_xor(d3, off);
  }
  const float bb = g2b[0];
  const float c1 = 1.f / (1.f + __expf(-(d1 + d2 + bb)));
  const float c2 = 1.f / (1.f + __expf(-(d1 + d3 + bb)));
  const float Vr = V[r];
  const float o0 = (c1 * x0 + (1.f - c1) * a0) - (c2 * x0 + (1.f - c2) * b0);
  atomicAdd(&sAcc[t], o0 * Vr);
  if (t < D_ - 64) {
    const float o1 = (c1 * x1 + (1.f - c1) * a1v) - (c2 * x1 + (1.f - c2) * b1v);
    atomicAdd(&sAcc[64 + t], o1 * Vr);
  }
  __syncthreads();
  if (threadIdx.x < D_) {
    const int b = blockIdx.x >> 8;
    atomicAdd(&pooled[b * D_ + threadIdx.x], sAcc[threadIdx.x]);
  }
}

// ------------------------------------------- MLP head (single block, 1024 thr)
__global__ __launch_bounds__(1024) void fc_kernel(
    const float* __restrict__ pooled,
    const float* __restrict__ w0, const float* __restrict__ b0,
    const float* __restrict__ w1, const float* __restrict__ b1,
    const float* __restrict__ w2, const float* __restrict__ b2,
    const float* __restrict__ w3, const float* __restrict__ b3,
    float* __restrict__ out)
{
  __shared__ float pin[B_][D_];
  __shared__ float bufA[B_][DFC_], bufB[B_][DFC_];
  const int t = threadIdx.x;
  if (t < B_ * D_) pin[t / D_][t % D_] = pooled[t];
  __syncthreads();
  const int r = t >> 7, o = t & 127;
  {
    float a = b0[o];
    const float2* wr = (const float2*)(w0 + o * D_);
#pragma unroll
    for (int m2 = 0; m2 < D_ / 2; m2++) {
      const float2 wv = wr[m2];
      a += pin[r][m2 * 2] * wv.x + pin[r][m2 * 2 + 1] * wv.y;
    }
    bufA[r][o] = fmaxf(a, 0.f);
  }
  __syncthreads();
  {
    float a = b1[o];
    const float4* wr = (const float4*)(w1 + o * DFC_);
    const float4* br = (const float4*)&bufA[r][0];
#pragma unroll
    for (int m4 = 0; m4 < DFC_ / 4; m4++) a += dot4(br[m4], wr[m4]);
    bufB[r][o] = fmaxf(a, 0.f);
  }
  __syncthreads();
  {
    float a = b2[o];
    const float4* wr = (const float4*)(w2 + o * DFC_);
    const float4* br = (const float4*)&bufB[r][0];
#pragma unroll
    for (int m4 = 0; m4 < DFC_ / 4; m4++) a += dot4(br[m4], wr[m4]);
    bufA[r][o] = fmaxf(a, 0.f);
  }
  __syncthreads();
  if (t < 64) {
    const int rr = t >> 3, l8 = t & 7;
    const float4* wr = (const float4*)(w3 + l8 * 16);
    const float4* br = (const float4*)&bufA[rr][l8 * 16];
    float a = 0.f;
#pragma unroll
    for (int m4 = 0; m4 < 4; m4++) a += dot4(br[m4], wr[m4]);
    a += __shfl_xor(a, 1); a += __shfl_xor(a, 2); a += __shfl_xor(a, 4);
    if (l8 == 0) out[rr] = 1.f / (1.f + __expf(-(a + b3[0])));
  }
}

// ----------------------------------------------------------------------
extern "C" void kernel_launch(void* const* d_in, const int* in_sizes, int n_in,
                              void* d_out, int out_size, void* d_ws, size_t ws_size,
                              hipStream_t stream)
{
  const float* H     = (const float*)d_in[0];
  const float* A1    = (const float*)d_in[1];
  const float* A2    = (const float*)d_in[2];
  const float* V     = (const float*)d_in[3];
  const float* few   = (const float*)d_in[4];
  const float* mup   = (const float*)d_in[5];
  const float* devp  = (const float*)d_in[6];
  const float* gW    = (const float*)d_in[7];
  const float* gA    = (const float*)d_in[8];
  const float* g1    = (const float*)d_in[9];
  const float* g2w   = (const float*)d_in[10];
  const float* g2b   = (const float*)d_in[11];
  const float* w0 = (const float*)d_in[12]; const float* b0 = (const float*)d_in[13];
  const float* w1 = (const float*)d_in[14]; const float* b1 = (const float*)d_in[15];
  const float* w2 = (const float*)d_in[16]; const float* b2 = (const float*)d_in[17];
  const float* w3 = (const float*)d_in[18]; const float* b3 = (const float*)d_in[19];
  float* outp = (float*)d_out;

  float* ws = (float*)d_ws;
  // fixed layout (float offsets)
  float*   x      = ws;                         // 573440
  short*   hb16   = (short*)(ws + 573440);
  short*   hAb16  = (short*)(ws + 966656);
  short*   hT16   = (short*)(ws + 1359872);
  short*   Wb16   = (short*)(ws + 1753088);
  short*   Atb16  = (short*)(ws + 1768448);
  short*   fewb16 = (short*)(ws + 1783808);     // 80*64 bf16 -> 1786368
  float*   M1p    = ws + 1786368;               // 8*B*N each
  float*   S1p    = ws + 1851904;
  float*   M2p    = ws + 1917440;
  float*   S2p    = ws + 1982976;
  float*   pooled = ws + 2048512;               // -> 2049088
  ushortT* adj_t  = (ushortT*)(ws + 2049088);   // 8M u16 -> 6243392
  unsigned* m1b   = (unsigned*)(ws + 6243392);  // -> 6505536
  unsigned* m2b   = (unsigned*)(ws + 6505536);  // -> 6767680
  ushortT* Et     = (ushortT*)(ws + 6767680);   // 8M u16 -> 10961984
  const int JC = 4;
  ushortT* hp1p   = (ushortT*)(ws + 10961984);
  ushortT* hp2p   = hp1p + (size_t)JC * 655360u;
  const size_t need = (size_t)(10961984u + (size_t)JC * 655360u) * 4u;
  if (ws_size < need) return;
  const int njt = (N_ / 32) / JC;
  const int ROWS = B_ * N_;

  prep_all<<<32 * 32 * B_ + 17, 256, 0, stream>>>(A1, A2, mup, devp, gW, gA, few,
      adj_t, m1b, m2b, Wb16, Atb16, fewb16, hT16, pooled);

  for (int k = 0; k < 4; k++) {
    const short* Wk  = Wb16  + (size_t)k * 80 * 96;
    const short* Atk = Atb16 + (size_t)k * 80 * 96;
    if (k == 0)
      gatmm_mfma<0><<<ROWS / 32, 128, 0, stream>>>(
          x, H, fewb16, nullptr, nullptr, 0, nullptr, nullptr, nullptr,
          Wk, Atk, hb16, hAb16, hT16);
    else
      gatmm_mfma<1><<<ROWS / 32, 128, 0, stream>>>(
          x, nullptr, nullptr, hp1p, hp2p, JC,
          g1 + (size_t)(k - 1) * D_, g2w + (size_t)(k - 1) * D_, g2b + (k - 1),
          Wk, Atk, hb16, hAb16, hT16);
    passE_mfma<<<dim3(32, 8, B_), 256, 0, stream>>>(m1b, m2b, hb16, hAb16, Et,
                                                    M1p, S1p, M2p, S2p);
    passPV_mfma<<<dim3(32, JC, B_), 256, 0, stream>>>(adj_t, Et, hT16,
        M1p, S1p, M2p, S2p, hp1p, hp2p, njt);
  }
  combine_pool<<<ROWS / 4, 256, 0, stream>>>(x, hp1p, hp2p, JC,
      g1 + 3 * D_, g2w + 3 * D_, g2b + 3, V, pooled);
  fc_kernel<<<1, 1024, 0, stream>>>(pooled, w0, b0, w1, b1, w2, b2, w3, b3, outp);
}

// Round 10
// 308.394 us; speedup vs baseline: 1.3239x; 1.0123x over previous
//
#include <hip/hip_runtime.h>

#define B_   8
#define N_   1024
#define F0_  56
#define D_   70
#define DK_  96      // bf16 K-padded row stride (3 x 32)
#define DFC_ 128

typedef __attribute__((ext_vector_type(8))) short bf16x8;
typedef __attribute__((ext_vector_type(4))) float f32x4;
typedef unsigned short ushortT;
typedef _Float16 f16T;

__device__ __forceinline__ short f2bf(float x) {
  unsigned u = __builtin_bit_cast(unsigned, x);
  u += 0x7FFF + ((u >> 16) & 1);
  return (short)(u >> 16);
}
__device__ __forceinline__ float bfdec(unsigned u16bits) {
  unsigned v = u16bits << 16;
  return __builtin_bit_cast(float, v);
}
__device__ __forceinline__ ushortT f2h(float x) {
  f16T h = (f16T)x; return __builtin_bit_cast(ushortT, h);
}
__device__ __forceinline__ float h2f(ushortT u) {
  return (float)__builtin_bit_cast(f16T, u);
}
__device__ __forceinline__ float dot4(float4 a, float4 b) {
  return a.x * b.x + a.y * b.y + a.z * b.z + a.w * b.w;
}

// ---- prep_all: adj tiles+masks (8192 blocks) | weights | hT pad | few | pooled=0
__global__ __launch_bounds__(256) void prep_all(
    const float* __restrict__ A1, const float* __restrict__ A2,
    const float* __restrict__ mup, const float* __restrict__ devp,
    const float* __restrict__ gW, const float* __restrict__ gA,
    const float* __restrict__ few,
    ushortT* __restrict__ adj_t, unsigned* __restrict__ m1b, unsigned* __restrict__ m2b,
    short* __restrict__ Wb16, short* __restrict__ Atb16, short* __restrict__ fewb16,
    short* __restrict__ hT, float* __restrict__ pooled)
{
  const int bid = blockIdx.x;
  const int tid = threadIdx.x;
  if (bid >= 32 * 32 * B_) {
    const int e = bid - 32 * 32 * B_;
    if (e < 8) {
      const int k = e & 3;
      const bool isW = e < 4;
      short* dst = (isW ? Wb16 : Atb16) + (size_t)k * 80 * 96;
      const float* src = (isW ? gW : gA) + (size_t)k * D_ * D_;
      for (int i = tid; i < 80 * 96; i += 256) {
        const int d = i / 96, m = i - (i / 96) * 96;
        float v = 0.f;
        if (d < D_ && m < D_) v = isW ? src[d * D_ + m] : src[m * D_ + d];
        dst[i] = f2bf(v);
      }
    } else if (e < 16) {
      const int b = e - 8;
      uint2* p = (uint2*)(hT + ((size_t)(b * 96 + 80)) * N_);
      for (int i = tid; i < 16 * N_ / 4; i += 256) p[i] = (uint2){0, 0};
    } else {
      for (int i = tid; i < 80 * 64; i += 256) {
        const int d = i >> 6, m = i & 63;
        fewb16[i] = f2bf((d < D_ && m < F0_) ? few[d * F0_ + m] : 0.f);
      }
      for (int i = tid; i < B_ * D_; i += 256) pooled[i] = 0.f;
    }
    return;
  }
  const int it = bid & 31, jt = (bid >> 5) & 31, b = bid >> 10;
  const int i0 = it * 32, j0 = jt * 32;
  const int jrel = tid >> 3, iq = tid & 7;
  __shared__ unsigned m1s[32], m2s[32];
  if (tid < 32) { m1s[tid] = 0; m2s[tid] = 0; }
  __syncthreads();
  const float mu = mup[0], idev = 1.0f / devp[0];
  const size_t base = ((size_t)b * N_ + j0 + jrel) * N_ + i0 + iq * 4;
  const float4 a1 = *(const float4*)(A1 + base);
  const float4 a2 = *(const float4*)(A2 + base);
  const float a1v[4] = {a1.x, a1.y, a1.z, a1.w};
  const float a2v[4] = {a2.x, a2.y, a2.z, a2.w};
  ushortT o[4];
#pragma unroll
  for (int k = 0; k < 4; k++) {
    const float rbf = (a2v[k] <= 10.f) ? __expf(-(a2v[k] - mu) * (a2v[k] - mu) * idev) : 0.f;
    const float adj1 = rbf + a1v[k];
    ushortT u = ((ushortT)f2bf(adj1)) & 0xFFFE;
    if (a1v[k] > 0.f) u |= 1;
    o[k] = u;
  }
  *(uint2*)(adj_t + ((size_t)(b * 32 + jt) * 32 + it) * 1024 + jrel * 32 + iq * 4) =
      *(uint2*)o;
  const unsigned bit = 1u << jrel;
#pragma unroll
  for (int k = 0; k < 4; k++) {
    if (o[k] & 0xFFFEu) atomicOr(&m1s[iq * 4 + k], bit);
    if (o[k] & 1u)      atomicOr(&m2s[iq * 4 + k], bit);
  }
  __syncthreads();
  if (tid < 32) {
    m1b[((size_t)b * N_ + i0 + tid) * 32 + jt] = m1s[tid];
    m2b[((size_t)b * N_ + i0 + tid) * 32 + jt] = m2s[tid];
  }
}

// -- fused [featem|combine] + h + hA + hT via MFMA (16 rows, 2 waves, nt-split)
#define GR 16
template<int MODE>
__global__ __launch_bounds__(128) void gatmm_mfma(
    float* __restrict__ x, const float* __restrict__ H, const short* __restrict__ fewb,
    const ushortT* __restrict__ hp1p, const ushortT* __restrict__ hp2p, int JC,
    const float* __restrict__ g1, const float* __restrict__ g2w, const float* __restrict__ g2b,
    const short* __restrict__ Wb, const short* __restrict__ Atb,
    short* __restrict__ hb16, short* __restrict__ hAb16, short* __restrict__ hT)
{
  const int tid = threadIdx.x;
  const int w = tid >> 6, lane = tid & 63;
  const int lr = lane & 15, kg = lane >> 4;
  const int r0 = blockIdx.x * GR;
  const int b = r0 >> 10, n0 = r0 & (N_ - 1);

  __shared__ __align__(16) short sxb[GR][104];
  __shared__ __align__(16) short shl[GR][104];

  for (int i = tid; i < 160; i += 128) {
    const int r = i / 10, c = i - (i / 10) * 10;
    *(uint2*)&sxb[r][64 + c * 4] = (uint2){0, 0};
    *(uint2*)&shl[r][64 + c * 4] = (uint2){0, 0};
  }

  if (MODE == 0) {
    // stage H rows bf16 (56 cols padded to 64) into shl
    for (int i = tid; i < GR * 64; i += 128) {
      const int r = i >> 6, c = i & 63;
      shl[r][c] = f2bf((c < F0_) ? H[(size_t)(r0 + r) * F0_ + c] : 0.f);
    }
    __syncthreads();
    bf16x8 hf[2];
#pragma unroll
    for (int ks = 0; ks < 2; ks++)
      hf[ks] = *(const bf16x8*)&shl[lr][ks * 32 + kg * 8];
    for (int nt = w; nt < 5; nt += 2) {
      f32x4 accf = (f32x4){0.f, 0.f, 0.f, 0.f};
#pragma unroll
      for (int ks = 0; ks < 2; ks++) {
        bf16x8 bw = *(const bf16x8*)(fewb + (size_t)(nt * 16 + lr) * 64 + ks * 32 + kg * 8);
        accf = __builtin_amdgcn_mfma_f32_16x16x32_bf16(hf[ks], bw, accf, 0, 0, 0);
      }
#pragma unroll
      for (int r = 0; r < 4; r++) {
        const int i = kg * 4 + r, d = nt * 16 + lr;
        if (d < D_) x[(size_t)(r0 + i) * D_ + d] = accf[r];
        sxb[i][d] = f2bf(accf[r]);
      }
    }
  } else {
    const int lt = tid & 15, gg = tid >> 4;   // 8 groups x 16 lanes, 2 rows each
#pragma unroll
    for (int rg = 0; rg < 2; rg++) {
      const int row = gg * 2 + rg;
      const int grow = r0 + row;
      float s1[5], s2[5], xv[5];
#pragma unroll
      for (int q = 0; q < 5; q++) { s1[q] = 0.f; s2[q] = 0.f; xv[q] = 0.f; }
      for (int jc = 0; jc < JC; jc++) {
        const size_t bp = ((size_t)jc * (B_ * N_) + grow) * 80 + lt;
#pragma unroll
        for (int q = 0; q < 5; q++) {
          s1[q] += bfdec(hp1p[bp + 16 * q]);
          s2[q] += bfdec(hp2p[bp + 16 * q]);
        }
      }
      float d1 = 0.f, d2 = 0.f, d3 = 0.f;
#pragma unroll
      for (int q = 0; q < 5; q++) {
        const int d = lt + 16 * q;
        if (d < D_) {
          s1[q] = fmaxf(s1[q], 0.f); s2[q] = fmaxf(s2[q], 0.f);
          xv[q] = x[(size_t)grow * D_ + d];
          d1 += xv[q] * g1[d]; d2 += s1[q] * g2w[d]; d3 += s2[q] * g2w[d];
        }
      }
#pragma unroll
      for (int off = 1; off < 16; off <<= 1) {
        d1 += __shfl_xor(d1, off); d2 += __shfl_xor(d2, off); d3 += __shfl_xor(d3, off);
      }
      const float bb = g2b[0];
      const float c1 = 1.f / (1.f + __expf(-(d1 + d2 + bb)));
      const float c2 = 1.f / (1.f + __expf(-(d1 + d3 + bb)));
#pragma unroll
      for (int q = 0; q < 5; q++) {
        const int d = lt + 16 * q;
        if (d < D_) {
          const float xn = (c1 * xv[q] + (1.f - c1) * s1[q]) - (c2 * xv[q] + (1.f - c2) * s2[q]);
          x[(size_t)grow * D_ + d] = xn;
          sxb[row][d] = f2bf(xn);
        }
      }
    }
  }
  __syncthreads();

  // GEMM1: h = x @ W^T   (nt tiles split across 2 waves)
  bf16x8 af[3];
#pragma unroll
  for (int ks = 0; ks < 3; ks++)
    af[ks] = *(const bf16x8*)&sxb[lr][ks * 32 + kg * 8];
  for (int nt = w; nt < 5; nt += 2) {
    f32x4 acc = (f32x4){0.f, 0.f, 0.f, 0.f};
#pragma unroll
    for (int ks = 0; ks < 3; ks++) {
      bf16x8 bw = *(const bf16x8*)(Wb + (size_t)(nt * 16 + lr) * 96 + ks * 32 + kg * 8);
      acc = __builtin_amdgcn_mfma_f32_16x16x32_bf16(af[ks], bw, acc, 0, 0, 0);
    }
#pragma unroll
    for (int r = 0; r < 4; r++)
      shl[kg * 4 + r][nt * 16 + lr] = f2bf(acc[r]);
  }
  __syncthreads();

  for (int i = tid; i < GR * 12; i += 128) {
    const int r = i / 12, seg = i - (i / 12) * 12;
    *(bf16x8*)(hb16 + (size_t)(r0 + r) * DK_ + seg * 8) = *(const bf16x8*)&shl[r][seg * 8];
  }
  for (int i = tid; i < 160; i += 128) {
    const int d = i >> 1, ng = i & 1;
    short tmp[8];
#pragma unroll
    for (int k = 0; k < 8; k++) tmp[k] = shl[ng * 8 + k][d];
    *(bf16x8*)(hT + ((size_t)(b * 96 + d)) * N_ + n0 + ng * 8) = *(bf16x8*)tmp;
  }

  // GEMM2: hA = h @ A
  bf16x8 ah[3];
#pragma unroll
  for (int ks = 0; ks < 3; ks++)
    ah[ks] = *(const bf16x8*)&shl[lr][ks * 32 + kg * 8];
  for (int nt = w; nt < 5; nt += 2) {
    f32x4 acc2 = (f32x4){0.f, 0.f, 0.f, 0.f};
#pragma unroll
    for (int ks = 0; ks < 3; ks++) {
      bf16x8 bw = *(const bf16x8*)(Atb + (size_t)(nt * 16 + lr) * 96 + ks * 32 + kg * 8);
      acc2 = __builtin_amdgcn_mfma_f32_16x16x32_bf16(ah[ks], bw, acc2, 0, 0, 0);
    }
#pragma unroll
    for (int r = 0; r < 4; r++)
      sxb[kg * 4 + r][nt * 16 + lr] = f2bf(acc2[r]);
  }
  __syncthreads();
  for (int i = tid; i < GR * 12; i += 128) {
    const int r = i / 12, seg = i - (i / 12) * 12;
    *(bf16x8*)(hAb16 + (size_t)(r0 + r) * DK_ + seg * 8) = *(const bf16x8*)&sxb[r][seg * 8];
  }
}

// ---------------- passE: E tiles (stored fp16, tiled) + masked softmax stats
__global__ __launch_bounds__(256) void passE_mfma(
    const unsigned* __restrict__ m1b, const unsigned* __restrict__ m2b,
    const short* __restrict__ hb16, const short* __restrict__ hAb16,
    ushortT* __restrict__ Et,
    float* __restrict__ M1p, float* __restrict__ S1p,
    float* __restrict__ M2p, float* __restrict__ S2p)
{
  const int jt = blockIdx.x, ic = blockIdx.y, b = blockIdx.z;
  const int tid = threadIdx.x, w = tid >> 6, lane = tid & 63;
  const int lr = lane & 15, kg = lane >> 4;
  const int ih = w >> 1, jh = w & 1;
  const int j0 = jt * 32;
  const short* hb  = hb16  + (size_t)b * N_ * DK_;
  const short* hAb = hAb16 + (size_t)b * N_ * DK_;

  bf16x8 b_h[3], b_hA[3];
  {
    const short* p = hb  + (size_t)(j0 + jh * 16 + lr) * DK_ + kg * 8;
    const short* q = hAb + (size_t)(j0 + jh * 16 + lr) * DK_ + kg * 8;
#pragma unroll
    for (int ks = 0; ks < 3; ks++) {
      b_h[ks]  = *(const bf16x8*)(p + ks * 32);
      b_hA[ks] = *(const bf16x8*)(q + ks * 32);
    }
  }
  const int bitp = jh * 16 + lr;
  const int i0base = ic * 128;
  float Ev[16];
  unsigned g1m = 0, g2m = 0;

#pragma unroll
  for (int iter = 0; iter < 4; iter++) {
    const int i0 = i0base + iter * 32 + ih * 16;
    const short* pa = hAb + (size_t)(i0 + lr) * DK_ + kg * 8;
    const short* ph = hb  + (size_t)(i0 + lr) * DK_ + kg * 8;
    bf16x8 a_hA[3], a_h[3];
#pragma unroll
    for (int ks = 0; ks < 3; ks++) {
      a_hA[ks] = *(const bf16x8*)(pa + ks * 32);
      a_h[ks]  = *(const bf16x8*)(ph + ks * 32);
    }
    const unsigned* W1p = m1b + ((size_t)b * N_ + i0 + kg * 4) * 32 + jt;
    const unsigned* W2p = m2b + ((size_t)b * N_ + i0 + kg * 4) * 32 + jt;
    unsigned mw1[4], mw2[4];
#pragma unroll
    for (int r = 0; r < 4; r++) { mw1[r] = W1p[(size_t)r * 32]; mw2[r] = W2p[(size_t)r * 32]; }
    f32x4 E = {0.f, 0.f, 0.f, 0.f};
#pragma unroll
    for (int ks = 0; ks < 3; ks++)
      E = __builtin_amdgcn_mfma_f32_16x16x32_bf16(a_hA[ks], b_h[ks], E, 0, 0, 0);
#pragma unroll
    for (int ks = 0; ks < 3; ks++)
      E = __builtin_amdgcn_mfma_f32_16x16x32_bf16(a_h[ks], b_hA[ks], E, 0, 0, 0);
    ushortT ev16[4];
#pragma unroll
    for (int r = 0; r < 4; r++) ev16[r] = f2h(E[r]);
    {
      const int itg = ic * 4 + iter;
      const unsigned lo = (unsigned)ev16[0] | ((unsigned)ev16[1] << 16);
      const unsigned hi = (unsigned)ev16[2] | ((unsigned)ev16[3] << 16);
      ushortT* dst = Et + ((size_t)(b * 32 + jt) * 32 + itg) * 1024 +
                     (jh * 16 + lr) * 32 + (ih * 16 + kg * 4);
      *(uint2*)dst = (uint2){lo, hi};
    }
#pragma unroll
    for (int r = 0; r < 4; r++) {
      Ev[iter * 4 + r] = h2f(ev16[r]);
      g1m |= ((mw1[r] >> bitp) & 1u) << (iter * 4 + r);
      g2m |= ((mw2[r] >> bitp) & 1u) << (iter * 4 + r);
    }
  }
  float M1r = -3.0e38f, M2r = -3.0e38f;
#pragma unroll
  for (int k = 0; k < 16; k++) {
    M1r = ((g1m >> k) & 1u) ? fmaxf(M1r, Ev[k]) : M1r;
    M2r = ((g2m >> k) & 1u) ? fmaxf(M2r, Ev[k]) : M2r;
  }
  float S1r = 0.f, S2r = 0.f;
#pragma unroll
  for (int k = 0; k < 16; k++) {
    S1r += ((g1m >> k) & 1u) ? __expf(Ev[k] - M1r) : 0.f;
    S2r += ((g2m >> k) & 1u) ? __expf(Ev[k] - M2r) : 0.f;
  }
#pragma unroll
  for (int off = 16; off <= 32; off <<= 1) {
    float Mo = __shfl_xor(M1r, off), So = __shfl_xor(S1r, off);
    float nM = fmaxf(M1r, Mo);
    S1r = S1r * __expf(M1r - nM) + So * __expf(Mo - nM); M1r = nM;
    Mo = __shfl_xor(M2r, off); So = __shfl_xor(S2r, off);
    nM = fmaxf(M2r, Mo);
    S2r = S2r * __expf(M2r - nM) + So * __expf(Mo - nM); M2r = nM;
  }
  __shared__ float sM[2][4][16], sS[2][4][16];
  if (lane < 16) {
    sM[0][w][lr] = M1r; sS[0][w][lr] = S1r;
    sM[1][w][lr] = M2r; sS[1][w][lr] = S2r;
  }
  __syncthreads();
  if (tid < 32) {
    const int jhh = tid >> 4, l2 = tid & 15;
    const size_t o = ((size_t)b * 8 + ic) * N_ + j0 + jhh * 16 + l2;
    {
      float Ma = sM[0][jhh][l2], Sa = sS[0][jhh][l2];
      float Mb = sM[0][2 + jhh][l2], Sb = sS[0][2 + jhh][l2];
      float nM = fmaxf(Ma, Mb);
      M1p[o] = nM; S1p[o] = Sa * __expf(Ma - nM) + Sb * __expf(Mb - nM);
    }
    {
      float Ma = sM[1][jhh][l2], Sa = sS[1][jhh][l2];
      float Mb = sM[1][2 + jhh][l2], Sb = sS[1][2 + jhh][l2];
      float nM = fmaxf(Ma, Mb);
      M2p[o] = nM; S2p[o] = Sa * __expf(Ma - nM) + Sb * __expf(Mb - nM);
    }
  }
}

// --------------------- passPV: prefetched E/adj tiles, weights, PV MFMA
#define NJT 4
__global__ __launch_bounds__(256) void passPV_mfma(
    const ushortT* __restrict__ adj_t, const ushortT* __restrict__ Et,
    const short* __restrict__ hT16,
    const float* __restrict__ M1p, const float* __restrict__ S1p,
    const float* __restrict__ M2p, const float* __restrict__ S2p,
    ushortT* __restrict__ hp1p, ushortT* __restrict__ hp2p)
{
  const int it = blockIdx.x, jc = blockIdx.y, b = blockIdx.z;
  const int tid = threadIdx.x, w = tid >> 6, lane = tid & 63;
  const int lr = lane & 15, kg = lane >> 4;
  const int ih = w >> 1, jh = w & 1;
  const int dbase = (w & 1) * 3;
  const int jbase = jc * NJT * 32;
  const int lofs = (jh * 16 + lr) * 32 + (ih * 16 + kg * 4);

  __shared__ float sMS[4][NJT * 32];
  for (int idx = tid; idx < NJT * 32; idx += 256) {
    const int col = jbase + idx;
    float M = -3.0e38f, S = 0.f;
#pragma unroll
    for (int q = 0; q < 8; q++) {
      const float m = M1p[((size_t)b * 8 + q) * N_ + col];
      const float s = S1p[((size_t)b * 8 + q) * N_ + col];
      const float nM = fmaxf(M, m);
      S = S * __expf(M - nM) + s * __expf(m - nM); M = nM;
    }
    sMS[0][idx] = M; sMS[1][idx] = 1.0f / S;
    M = -3.0e38f; S = 0.f;
#pragma unroll
    for (int q = 0; q < 8; q++) {
      const float m = M2p[((size_t)b * 8 + q) * N_ + col];
      const float s = S2p[((size_t)b * 8 + q) * N_ + col];
      const float nM = fmaxf(M, m);
      S = S * __expf(M - nM) + s * __expf(m - nM); M = nM;
    }
    sMS[2][idx] = M; sMS[3][idx] = 1.0f / S;
  }

  const short* hTb = hT16 + (size_t)b * DK_ * N_;
  f32x4 acc[2][3];
#pragma unroll
  for (int m = 0; m < 2; m++)
#pragma unroll
    for (int q = 0; q < 3; q++) acc[m][q] = (f32x4){0.f, 0.f, 0.f, 0.f};

  __shared__ short wlds[2][2][32][40];
  __syncthreads();

  // prefetch iteration 0
  size_t tb = ((size_t)(b * 32 + jc * NJT) * 32 + it) * 1024 + lofs;
  uint2 eraw = *(const uint2*)(Et + tb);
  uint2 araw = *(const uint2*)(adj_t + tb);

#pragma unroll
  for (int t = 0; t < NJT; ++t) {
    const int j0 = jbase + t * 32;
    const int par = t & 1;
    bf16x8 bt[3];
#pragma unroll
    for (int q = 0; q < 3; q++)
      bt[q] = *(const bf16x8*)(hTb + (size_t)((dbase + q) * 16 + lr) * N_ + j0 + kg * 8);
    // issue next-iteration tile loads before the compute/barrier section
    uint2 eN, aN;
    if (t + 1 < NJT) {
      const size_t tbn = ((size_t)(b * 32 + jc * NJT + t + 1) * 32 + it) * 1024 + lofs;
      eN = *(const uint2*)(Et + tbn);
      aN = *(const uint2*)(adj_t + tbn);
    }

    const ushortT ev[4] = {(ushortT)(eraw.x & 0xFFFF), (ushortT)(eraw.x >> 16),
                           (ushortT)(eraw.y & 0xFFFF), (ushortT)(eraw.y >> 16)};
    const ushortT uu[4] = {(ushortT)(araw.x & 0xFFFF), (ushortT)(araw.x >> 16),
                           (ushortT)(araw.y & 0xFFFF), (ushortT)(araw.y >> 16)};
    const int jrel = t * 32 + jh * 16 + lr;
    const float M1j = sMS[0][jrel], is1 = sMS[1][jrel];
    const float M2j = sMS[2][jrel], is2 = sMS[3][jrel];

    short w1v[4], w2v[4];
#pragma unroll
    for (int r = 0; r < 4; r++) {
      const float e = h2f(ev[r]);
      const float adj1v = bfdec(uu[r] & 0xFFFEu);
      const bool gon1 = (uu[r] & 0xFFFEu) != 0, gon2 = (uu[r] & 1u) != 0;
      w1v[r] = f2bf(gon1 ? __expf(e - M1j) * adj1v * is1 : 0.f);
      w2v[r] = f2bf(gon2 ? __expf(e - M2j) * is2 : 0.f);
    }
#pragma unroll
    for (int r = 0; r < 4; r++) {
      wlds[par][0][ih * 16 + kg * 4 + r][jh * 16 + lr] = w1v[r];
      wlds[par][1][ih * 16 + kg * 4 + r][jh * 16 + lr] = w2v[r];
    }
    __syncthreads();
#pragma unroll
    for (int m = 0; m < 2; m++) {
      bf16x8 af = *(const bf16x8*)&wlds[par][m][ih * 16 + lr][kg * 8];
#pragma unroll
      for (int q = 0; q < 3; q++)
        acc[m][q] = __builtin_amdgcn_mfma_f32_16x16x32_bf16(af, bt[q], acc[m][q], 0, 0, 0);
    }
    eraw = eN; araw = aN;
  }
  const int i0 = it * 32;
#pragma unroll
  for (int m = 0; m < 2; m++) {
#pragma unroll
    for (int q = 0; q < 3; q++) {
      const int dt = dbase + q;
      if (dt < 5) {
        ushortT* dst = (m ? hp2p : hp1p) +
            (((size_t)jc * B_ + b) * N_ + i0 + ih * 16 + kg * 4) * 80 + dt * 16 + lr;
#pragma unroll
        for (int r = 0; r < 4; r++) dst[(size_t)r * 80] = (ushortT)f2bf(acc[m][q][r]);
      }
    }
  }
}

// ------------- final-layer combine fused with masked pool (atomic into pooled)
__global__ __launch_bounds__(256) void combine_pool(
    const float* __restrict__ x,
    const ushortT* __restrict__ hp1p, const ushortT* __restrict__ hp2p, int JC,
    const float* __restrict__ g1, const float* __restrict__ g2w,
    const float* __restrict__ g2b,
    const float* __restrict__ V, float* __restrict__ pooled)
{
  const int r = blockIdx.x * 4 + (threadIdx.x >> 6);
  const int t = threadIdx.x & 63;
  __shared__ float sAcc[D_];
  if (threadIdx.x < D_) sAcc[threadIdx.x] = 0.f;
  __syncthreads();
  float s1a = 0.f, s2a = 0.f, s1b = 0.f, s2b = 0.f;
  for (int q = 0; q < JC; q++) {
    const size_t base = ((size_t)q * (B_ * N_) + r) * 80;
    s1a += bfdec(hp1p[base + t]);
    s2a += bfdec(hp2p[base + t]);
    if (t < D_ - 64) {
      s1b += bfdec(hp1p[base + 64 + t]);
      s2b += bfdec(hp2p[base + 64 + t]);
    }
  }
  const float a0 = fmaxf(s1a, 0.f), b0 = fmaxf(s2a, 0.f);
  const float a1v = fmaxf(s1b, 0.f), b1v = fmaxf(s2b, 0.f);
  const float* xr = x + (size_t)r * D_;
  const float x0 = xr[t];
  float d1 = x0 * g1[t], d2 = a0 * g2w[t], d3 = b0 * g2w[t];
  float x1 = 0.f;
  if (t < D_ - 64) {
    x1 = xr[64 + t];
    d1 += x1 * g1[64 + t]; d2 += a1v * g2w[64 + t]; d3 += b1v * g2w[64 + t];
  }
#pragma unroll
  for (int off = 1; off < 64; off <<= 1) {
    d1 += __shfl_xor(d1, off);
    d2 += __shfl_xor(d2, off);
    d3 += __shfl_xor(d3, off);
  }
  const float bb = g2b[0];
  const float c1 = 1.f / (1.f + __expf(-(d1 + d2 + bb)));
  const float c2 = 1.f / (1.f + __expf(-(d1 + d3 + bb)));
  const float Vr = V[r];
  const float o0 = (c1 * x0 + (1.f - c1) * a0) - (c2 * x0 + (1.f - c2) * b0);
  atomicAdd(&sAcc[t], o0 * Vr);
  if (t < D_ - 64) {
    const float o1 = (c1 * x1 + (1.f - c1) * a1v) - (c2 * x1 + (1.f - c2) * b1v);
    atomicAdd(&sAcc[64 + t], o1 * Vr);
  }
  __syncthreads();
  if (threadIdx.x < D_) {
    const int b = blockIdx.x >> 8;
    atomicAdd(&pooled[b * D_ + threadIdx.x], sAcc[threadIdx.x]);
  }
}

// ------------------------------------------- MLP head (single block, 1024 thr)
__global__ __launch_bounds__(1024) void fc_kernel(
    const float* __restrict__ pooled,
    const float* __restrict__ w0, const float* __restrict__ b0,
    const float* __restrict__ w1, const float* __restrict__ b1,
    const float* __restrict__ w2, const float* __restrict__ b2,
    const float* __restrict__ w3, const float* __restrict__ b3,
    float* __restrict__ out)
{
  __shared__ float pin[B_][D_];
  __shared__ float bufA[B_][DFC_], bufB[B_][DFC_];
  const int t = threadIdx.x;
  if (t < B_ * D_) pin[t / D_][t % D_] = pooled[t];
  __syncthreads();
  const int r = t >> 7, o = t & 127;
  {
    float a = b0[o];
    const float2* wr = (const float2*)(w0 + o * D_);
#pragma unroll
    for (int m2 = 0; m2 < D_ / 2; m2++) {
      const float2 wv = wr[m2];
      a += pin[r][m2 * 2] * wv.x + pin[r][m2 * 2 + 1] * wv.y;
    }
    bufA[r][o] = fmaxf(a, 0.f);
  }
  __syncthreads();
  {
    float a = b1[o];
    const float4* wr = (const float4*)(w1 + o * DFC_);
    const float4* br = (const float4*)&bufA[r][0];
#pragma unroll
    for (int m4 = 0; m4 < DFC_ / 4; m4++) a += dot4(br[m4], wr[m4]);
    bufB[r][o] = fmaxf(a, 0.f);
  }
  __syncthreads();
  {
    float a = b2[o];
    const float4* wr = (const float4*)(w2 + o * DFC_);
    const float4* br = (const float4*)&bufB[r][0];
#pragma unroll
    for (int m4 = 0; m4 < DFC_ / 4; m4++) a += dot4(br[m4], wr[m4]);
    bufA[r][o] = fmaxf(a, 0.f);
  }
  __syncthreads();
  if (t < 64) {
    const int rr = t >> 3, l8 = t & 7;
    const float4* wr = (const float4*)(w3 + l8 * 16);
    const float4* br = (const float4*)&bufA[rr][l8 * 16];
    float a = 0.f;
#pragma unroll
    for (int m4 = 0; m4 < 4; m4++) a += dot4(br[m4], wr[m4]);
    a += __shfl_xor(a, 1); a += __shfl_xor(a, 2); a += __shfl_xor(a, 4);
    if (l8 == 0) out[rr] = 1.f / (1.f + __expf(-(a + b3[0])));
  }
}

// ----------------------------------------------------------------------
extern "C" void kernel_launch(void* const* d_in, const int* in_sizes, int n_in,
                              void* d_out, int out_size, void* d_ws, size_t ws_size,
                              hipStream_t stream)
{
  const float* H     = (const float*)d_in[0];
  const float* A1    = (const float*)d_in[1];
  const float* A2    = (const float*)d_in[2];
  const float* V     = (const float*)d_in[3];
  const float* few   = (const float*)d_in[4];
  const float* mup   = (const float*)d_in[5];
  const float* devp  = (const float*)d_in[6];
  const float* gW    = (const float*)d_in[7];
  const float* gA    = (const float*)d_in[8];
  const float* g1    = (const float*)d_in[9];
  const float* g2w   = (const float*)d_in[10];
  const float* g2b   = (const float*)d_in[11];
  const float* w0 = (const float*)d_in[12]; const float* b0 = (const float*)d_in[13];
  const float* w1 = (const float*)d_in[14]; const float* b1 = (const float*)d_in[15];
  const float* w2 = (const float*)d_in[16]; const float* b2 = (const float*)d_in[17];
  const float* w3 = (const float*)d_in[18]; const float* b3 = (const float*)d_in[19];
  float* outp = (float*)d_out;

  float* ws = (float*)d_ws;
  // fixed layout (float offsets)
  float*   x      = ws;                         // 573440
  short*   hb16   = (short*)(ws + 573440);
  short*   hAb16  = (short*)(ws + 966656);
  short*   hT16   = (short*)(ws + 1359872);
  short*   Wb16   = (short*)(ws + 1753088);
  short*   Atb16  = (short*)(ws + 1768448);
  short*   fewb16 = (short*)(ws + 1783808);     // 80*64 bf16 -> 1786368
  float*   M1p    = ws + 1786368;               // 8*B*N each
  float*   S1p    = ws + 1851904;
  float*   M2p    = ws + 1917440;
  float*   S2p    = ws + 1982976;
  float*   pooled = ws + 2048512;               // -> 2049088
  ushortT* adj_t  = (ushortT*)(ws + 2049088);   // 8M u16 -> 6243392
  unsigned* m1b   = (unsigned*)(ws + 6243392);  // -> 6505536
  unsigned* m2b   = (unsigned*)(ws + 6505536);  // -> 6767680
  ushortT* Et     = (ushortT*)(ws + 6767680);   // 8M u16 -> 10961984
  const int JC = 8;                              // = 32 / NJT
  ushortT* hp1p   = (ushortT*)(ws + 10961984);
  ushortT* hp2p   = hp1p + (size_t)JC * 655360u;
  const size_t need = (size_t)10961984u * 4u + (size_t)JC * 655360u * 4u;
  if (ws_size < need) return;
  const int ROWS = B_ * N_;

  prep_all<<<32 * 32 * B_ + 17, 256, 0, stream>>>(A1, A2, mup, devp, gW, gA, few,
      adj_t, m1b, m2b, Wb16, Atb16, fewb16, hT16, pooled);

  for (int k = 0; k < 4; k++) {
    const short* Wk  = Wb16  + (size_t)k * 80 * 96;
    const short* Atk = Atb16 + (size_t)k * 80 * 96;
    if (k == 0)
      gatmm_mfma<0><<<ROWS / GR, 128, 0, stream>>>(
          x, H, fewb16, nullptr, nullptr, 0, nullptr, nullptr, nullptr,
          Wk, Atk, hb16, hAb16, hT16);
    else
      gatmm_mfma<1><<<ROWS / GR, 128, 0, stream>>>(
          x, nullptr, nullptr, hp1p, hp2p, JC,
          g1 + (size_t)(k - 1) * D_, g2w + (size_t)(k - 1) * D_, g2b + (k - 1),
          Wk, Atk, hb16, hAb16, hT16);
    passE_mfma<<<dim3(32, 8, B_), 256, 0, stream>>>(m1b, m2b, hb16, hAb16, Et,
                                                    M1p, S1p, M2p, S2p);
    passPV_mfma<<<dim3(32, JC, B_), 256, 0, stream>>>(adj_t, Et, hT16,
        M1p, S1p, M2p, S2p, hp1p, hp2p);
  }
  combine_pool<<<ROWS / 4, 256, 0, stream>>>(x, hp1p, hp2p, JC,
      g1 + 3 * D_, g2w + 3 * D_, g2b + 3, V, pooled);
  fc_kernel<<<1, 1024, 0, stream>>>(pooled, w0, b0, w1, b1, w2, b2, w3, b3, outp);
}